// Round 1
// baseline (1908.609 us; speedup 1.0000x reference)
//
#include <hip/hip_runtime.h>
#include <math.h>

#define H 256
#define NHEAD 4
#define HD 64
#define NEXP 8
#define SEQL 200
#define BATCH 128
#define NF (BATCH*SEQL)

// ---------------- helpers ----------------
__device__ __forceinline__ float blk_sum256(float v, float* s4) {
    #pragma unroll
    for (int o = 32; o > 0; o >>= 1) v += __shfl_xor(v, o, 64);
    __syncthreads();
    if ((threadIdx.x & 63) == 0) s4[threadIdx.x >> 6] = v;
    __syncthreads();
    return s4[0] + s4[1] + s4[2] + s4[3];
}

// ---------------- embedding ----------------
__global__ __launch_bounds__(256) void embed_kernel(
    const int* __restrict__ seqs, const float* __restrict__ item_emb,
    const float* __restrict__ pos_emb, float* __restrict__ x)
{
    int n = blockIdx.x, t = threadIdx.x;
    int id = seqs[n];
    int pos = (id != 0) ? (n % SEQL) + 1 : 0;
    x[(size_t)n*H + t] = item_emb[(size_t)id*H + t] * 16.0f + pos_emb[(size_t)pos*H + t];
}

// ---------------- layernorm (gather + optional residual) ----------------
// out[r] = LN(in[base + r*step] (+ res[r])) ; res (if set) and out are compact.
__global__ __launch_bounds__(256) void ln_kernel(
    const float* __restrict__ in, const float* __restrict__ res,
    float* __restrict__ out, const float* __restrict__ w, const float* __restrict__ b,
    float eps, int base, int step)
{
    __shared__ float s4[4];
    int r = blockIdx.x, t = threadIdx.x;
    float v = in[(size_t)(base + r*step)*H + t];
    if (res) v += res[(size_t)r*H + t];
    float mean = blk_sum256(v, s4) * (1.f/H);
    float d = v - mean;
    float var = blk_sum256(d*d, s4) * (1.f/H);
    out[(size_t)r*H + t] = d * rsqrtf(var + eps) * w[t] + b[t];
}

// ---------------- GEMM: out[r][o] = sum_h A[r][h]*W[o][h] + bias[o] ----------------
__global__ __launch_bounds__(256) void gemm_nt(
    const float* __restrict__ A, const float* __restrict__ W,
    const float* __restrict__ bias, float* __restrict__ out, int nrows)
{
    __shared__ float As[16][68];
    __shared__ float Ws[16][68];
    int r0 = blockIdx.x * 64;
    if (r0 >= nrows) return;
    int c0 = blockIdx.y * 64;
    int tid = threadIdx.x;
    int tx = tid & 15, ty = tid >> 4;
    int lrow = tid >> 2, lkg = (tid & 3) << 2;
    float acc[4][4] = {};
    for (int kk = 0; kk < H; kk += 16) {
        float4 av = make_float4(0.f,0.f,0.f,0.f);
        int gr = r0 + lrow;
        if (gr < nrows) av = *(const float4*)(A + (size_t)gr*H + kk + lkg);
        As[lkg+0][lrow]=av.x; As[lkg+1][lrow]=av.y; As[lkg+2][lrow]=av.z; As[lkg+3][lrow]=av.w;
        float4 wv = *(const float4*)(W + (size_t)(c0+lrow)*H + kk + lkg);
        Ws[lkg+0][lrow]=wv.x; Ws[lkg+1][lrow]=wv.y; Ws[lkg+2][lrow]=wv.z; Ws[lkg+3][lrow]=wv.w;
        __syncthreads();
        #pragma unroll
        for (int k = 0; k < 16; ++k) {
            float4 a = *(const float4*)&As[k][ty<<2];
            float4 bv = *(const float4*)&Ws[k][tx<<2];
            float aa[4] = {a.x,a.y,a.z,a.w};
            float bb[4] = {bv.x,bv.y,bv.z,bv.w};
            #pragma unroll
            for (int ii = 0; ii < 4; ++ii)
                #pragma unroll
                for (int jj = 0; jj < 4; ++jj)
                    acc[ii][jj] += aa[ii] * bb[jj];
        }
        __syncthreads();
    }
    #pragma unroll
    for (int ii = 0; ii < 4; ++ii) {
        int gr = r0 + (ty<<2) + ii;
        if (gr < nrows) {
            #pragma unroll
            for (int jj = 0; jj < 4; ++jj) {
                int gc = c0 + (tx<<2) + jj;
                out[(size_t)gr*H + gc] = acc[ii][jj] + bias[gc];
            }
        }
    }
}

// ---------------- fused attention: one block per (batch, head) ----------------
// q has nq rows per batch (compact); K/V are full [B*L, H]. qpos = qi + (L - nq).
__global__ __launch_bounds__(256) void attn_kernel(
    const float* __restrict__ qbuf, const float* __restrict__ kbuf,
    const float* __restrict__ vbuf, float* __restrict__ ctx, int nq)
{
    __shared__ float Vs[SEQL][HD];
    __shared__ float qs[4][HD];
    __shared__ float ps[4][SEQL];
    int b = blockIdx.x, h = blockIdx.y;
    int tid = threadIdx.x;
    for (int idx = tid; idx < SEQL*HD; idx += 256) {
        int key = idx >> 6, j = idx & 63;
        Vs[key][j] = vbuf[(size_t)(b*SEQL + key)*H + h*HD + j];
    }
    __syncthreads();
    int w = tid >> 6, lane = tid & 63;
    int iters = (nq + 3) >> 2;
    for (int it = 0; it < iters; ++it) {
        int qi = it*4 + w;
        bool active = qi < nq;
        int qpos = qi + (SEQL - nq);
        int nkey = active ? (qpos + 1) : 0;
        if (active) qs[w][lane] = qbuf[(size_t)(b*nq + qi)*H + h*HD + lane];
        float sc[4]; float m = -1e30f;
        #pragma unroll
        for (int c = 0; c < 4; ++c) {
            int key = lane + (c<<6);
            float s = -1e30f;
            if (key < nkey) {
                const float* kr = kbuf + (size_t)(b*SEQL + key)*H + h*HD;
                float acc = 0.f;
                for (int j = 0; j < HD; ++j) acc += qs[w][j] * kr[j];
                s = acc * 0.125f;
            }
            sc[c] = s; m = fmaxf(m, s);
        }
        #pragma unroll
        for (int o = 32; o > 0; o >>= 1) m = fmaxf(m, __shfl_xor(m, o, 64));
        float sum = 0.f;
        #pragma unroll
        for (int c = 0; c < 4; ++c) {
            float ev = (sc[c] > -1e29f) ? expf(sc[c] - m) : 0.f;
            sc[c] = ev; sum += ev;
        }
        #pragma unroll
        for (int o = 32; o > 0; o >>= 1) sum += __shfl_xor(sum, o, 64);
        float inv = 1.f / sum;
        #pragma unroll
        for (int c = 0; c < 4; ++c) {
            int key = lane + (c<<6);
            if (key < nkey) ps[w][key] = sc[c] * inv;
        }
        float acc = 0.f;
        for (int key = 0; key < nkey; ++key) acc += ps[w][key] * Vs[key][lane];
        if (active) ctx[(size_t)(b*nq + qi)*H + h*HD + lane] = acc;
    }
}

// ---------------- gate: logits, top-2, softmax weights, counts ----------------
__global__ __launch_bounds__(256) void gate_kernel(
    const float* __restrict__ X, const float* __restrict__ gw, const float* __restrict__ gb,
    int* __restrict__ top_idx, float* __restrict__ top_w, int* __restrict__ counts, int nrows)
{
    __shared__ float gl[NEXP];
    int n = blockIdx.x;
    int tid = threadIdx.x;
    int wv = tid >> 6, lane = tid & 63;
    float xv[4];
    #pragma unroll
    for (int c = 0; c < 4; ++c) xv[c] = X[(size_t)n*H + lane + (c<<6)];
    #pragma unroll
    for (int s = 0; s < 2; ++s) {
        int e = wv*2 + s;
        float acc = 0.f;
        #pragma unroll
        for (int c = 0; c < 4; ++c) acc += xv[c] * gw[(size_t)e*H + lane + (c<<6)];
        #pragma unroll
        for (int o = 32; o > 0; o >>= 1) acc += __shfl_xor(acc, o, 64);
        if (lane == 0) gl[e] = acc + gb[e];
    }
    __syncthreads();
    if (tid == 0) {
        int i0 = 0;
        for (int e = 1; e < NEXP; ++e) if (gl[e] > gl[i0]) i0 = e;
        int i1 = -1;
        for (int e = 0; e < NEXP; ++e) { if (e == i0) continue; if (i1 < 0 || gl[e] > gl[i1]) i1 = e; }
        float e1 = expf(gl[i1] - gl[i0]);
        float w0 = 1.f / (1.f + e1);
        top_idx[n*2+0] = i0; top_idx[n*2+1] = i1;
        top_w[n*2+0] = w0;  top_w[n*2+1] = 1.f - w0;
        atomicAdd(&counts[i0], 1);
        atomicAdd(&counts[i1], 1);
    }
}

__global__ void scan_kernel(const int* __restrict__ counts, int* __restrict__ offsets,
                            int* __restrict__ cursor)
{
    int s = 0;
    for (int e = 0; e < NEXP; ++e) { offsets[e] = s; cursor[e] = s; s += counts[e]; }
}

__global__ void scatter_kernel(const int* __restrict__ top_idx, const float* __restrict__ top_w,
    int* __restrict__ cursor, int* __restrict__ pair_tok, float* __restrict__ pair_w, int nrows)
{
    int n = blockIdx.x * 256 + threadIdx.x;
    if (n >= nrows) return;
    #pragma unroll
    for (int s = 0; s < 2; ++s) {
        int e = top_idx[n*2+s];
        int p = atomicAdd(&cursor[e], 1);
        pair_tok[p] = n;
        pair_w[p] = top_w[n*2+s];
    }
}

// ---------------- grouped MoE GEMM 1: h = relu(X[tok] @ W1[e] + b1[e]) ----------------
__global__ __launch_bounds__(256) void moe_gemm1(
    const float* __restrict__ X, const float* __restrict__ W1base,
    const float* __restrict__ b1base, const int* __restrict__ pair_tok,
    const int* __restrict__ offsets, const int* __restrict__ counts,
    float* __restrict__ hbuf)
{
    int e = blockIdx.z;
    int cnt = counts[e];
    int r0 = blockIdx.x * 64;
    if (r0 >= cnt) return;
    int off = offsets[e];
    int c0 = blockIdx.y * 64;
    const float* W = W1base + (size_t)e * H * H;
    const float* bias = b1base + (size_t)e * H;
    __shared__ float As[16][68];
    __shared__ float Bs[16][68];
    int tid = threadIdx.x, tx = tid & 15, ty = tid >> 4;
    int lrow = tid >> 2, lkg = (tid & 3) << 2;
    float acc[4][4] = {};
    for (int kk = 0; kk < H; kk += 16) {
        float4 av = make_float4(0.f,0.f,0.f,0.f);
        int pr = r0 + lrow;
        if (pr < cnt) {
            int tok = pair_tok[off + pr];
            av = *(const float4*)(X + (size_t)tok*H + kk + lkg);
        }
        As[lkg+0][lrow]=av.x; As[lkg+1][lrow]=av.y; As[lkg+2][lrow]=av.z; As[lkg+3][lrow]=av.w;
        float4 wv = *(const float4*)(W + (size_t)(kk+ty)*H + c0 + (tx<<2));
        *(float4*)&Bs[ty][tx<<2] = wv;
        __syncthreads();
        #pragma unroll
        for (int k = 0; k < 16; ++k) {
            float4 a = *(const float4*)&As[k][ty<<2];
            float4 bv = *(const float4*)&Bs[k][tx<<2];
            float aa[4] = {a.x,a.y,a.z,a.w};
            float bb[4] = {bv.x,bv.y,bv.z,bv.w};
            #pragma unroll
            for (int ii = 0; ii < 4; ++ii)
                #pragma unroll
                for (int jj = 0; jj < 4; ++jj)
                    acc[ii][jj] += aa[ii] * bb[jj];
        }
        __syncthreads();
    }
    #pragma unroll
    for (int ii = 0; ii < 4; ++ii) {
        int pr = r0 + (ty<<2) + ii;
        if (pr < cnt) {
            #pragma unroll
            for (int jj = 0; jj < 4; ++jj) {
                int gc = c0 + (tx<<2) + jj;
                hbuf[(size_t)(off+pr)*H + gc] = fmaxf(acc[ii][jj] + bias[gc], 0.f);
            }
        }
    }
}

// ---------------- grouped MoE GEMM 2: acc[tok] += w * (h @ W2[e] + b2[e]) ----------------
__global__ __launch_bounds__(256) void moe_gemm2(
    const float* __restrict__ Hbuf, const float* __restrict__ W2base,
    const float* __restrict__ b2base, const int* __restrict__ pair_tok,
    const float* __restrict__ pair_w, const int* __restrict__ offsets,
    const int* __restrict__ counts, float* __restrict__ accbuf)
{
    int e = blockIdx.z;
    int cnt = counts[e];
    int r0 = blockIdx.x * 64;
    if (r0 >= cnt) return;
    int off = offsets[e];
    int c0 = blockIdx.y * 64;
    const float* W = W2base + (size_t)e * H * H;
    const float* bias = b2base + (size_t)e * H;
    __shared__ float As[16][68];
    __shared__ float Bs[16][68];
    int tid = threadIdx.x, tx = tid & 15, ty = tid >> 4;
    int lrow = tid >> 2, lkg = (tid & 3) << 2;
    float acc[4][4] = {};
    for (int kk = 0; kk < H; kk += 16) {
        float4 av = make_float4(0.f,0.f,0.f,0.f);
        int pr = r0 + lrow;
        if (pr < cnt) av = *(const float4*)(Hbuf + (size_t)(off+pr)*H + kk + lkg);
        As[lkg+0][lrow]=av.x; As[lkg+1][lrow]=av.y; As[lkg+2][lrow]=av.z; As[lkg+3][lrow]=av.w;
        float4 wv = *(const float4*)(W + (size_t)(kk+ty)*H + c0 + (tx<<2));
        *(float4*)&Bs[ty][tx<<2] = wv;
        __syncthreads();
        #pragma unroll
        for (int k = 0; k < 16; ++k) {
            float4 a = *(const float4*)&As[k][ty<<2];
            float4 bv = *(const float4*)&Bs[k][tx<<2];
            float aa[4] = {a.x,a.y,a.z,a.w};
            float bb[4] = {bv.x,bv.y,bv.z,bv.w};
            #pragma unroll
            for (int ii = 0; ii < 4; ++ii)
                #pragma unroll
                for (int jj = 0; jj < 4; ++jj)
                    acc[ii][jj] += aa[ii] * bb[jj];
        }
        __syncthreads();
    }
    #pragma unroll
    for (int ii = 0; ii < 4; ++ii) {
        int pr = r0 + (ty<<2) + ii;
        if (pr < cnt) {
            int tok = pair_tok[off + pr];
            float pw = pair_w[off + pr];
            #pragma unroll
            for (int jj = 0; jj < 4; ++jj) {
                int gc = c0 + (tx<<2) + jj;
                atomicAdd(&accbuf[(size_t)tok*H + gc], pw * (acc[ii][jj] + bias[gc]));
            }
        }
    }
}

__global__ void zero_kernel(float* __restrict__ p, int n) {
    int i = blockIdx.x * 256 + threadIdx.x;
    if (i < n) p[i] = 0.f;
}

// ---------------- final: LN + user emb + dot(item emb) ----------------
__global__ __launch_bounds__(256) void final_kernel(
    const float* __restrict__ xf, const float* __restrict__ lnw, const float* __restrict__ lnb,
    const float* __restrict__ user_emb, const float* __restrict__ item_emb,
    const int* __restrict__ user_ids, const int* __restrict__ item_ids, float* __restrict__ out)
{
    __shared__ float s4[4];
    int bb = blockIdx.x, t = threadIdx.x;
    float v = xf[(size_t)bb*H + t];
    float mean = blk_sum256(v, s4) * (1.f/H);
    float d = v - mean;
    float var = blk_sum256(d*d, s4) * (1.f/H);
    float lnv = d * rsqrtf(var + 1e-8f) * lnw[t] + lnb[t];
    float fin = lnv + user_emb[(size_t)user_ids[bb]*H + t];
    float prod = fin * item_emb[(size_t)item_ids[bb]*H + t];
    float tot = blk_sum256(prod, s4);
    if (t == 0) out[bb] = tot;
}

// ---------------- launch ----------------
extern "C" void kernel_launch(void* const* d_in, const int* in_sizes, int n_in,
                              void* d_out, int out_size, void* d_ws, size_t ws_size,
                              hipStream_t stream)
{
    (void)in_sizes; (void)n_in; (void)out_size; (void)ws_size;
    const int*   user_ids  = (const int*)d_in[0];
    const int*   log_seqs  = (const int*)d_in[1];
    const int*   item_ids  = (const int*)d_in[2];
    const float* item_emb  = (const float*)d_in[3];
    const float* pos_emb   = (const float*)d_in[4];
    const float* user_emb  = (const float*)d_in[5];
    const float* ln1_w     = (const float*)d_in[6];
    const float* ln1_b     = (const float*)d_in[7];
    const float* inproj_w  = (const float*)d_in[8];
    const float* inproj_b  = (const float*)d_in[9];
    const float* outproj_w = (const float*)d_in[10];
    const float* outproj_b = (const float*)d_in[11];
    const float* ln2_w     = (const float*)d_in[12];
    const float* ln2_b     = (const float*)d_in[13];
    const float* gate_w    = (const float*)d_in[14];
    const float* gate_b    = (const float*)d_in[15];
    const float* e_w1      = (const float*)d_in[16];
    const float* e_b1      = (const float*)d_in[17];
    const float* e_w2      = (const float*)d_in[18];
    const float* e_b2      = (const float*)d_in[19];
    const float* moeln_w   = (const float*)d_in[20];
    const float* moeln_b   = (const float*)d_in[21];
    const float* lastln_w  = (const float*)d_in[22];
    const float* lastln_b  = (const float*)d_in[23];

    float* ws = (float*)d_ws;
    const size_t NFH = (size_t)NF * H;
    float* buf0 = ws;
    float* buf1 = buf0 + NFH;
    float* buf2 = buf1 + NFH;
    float* buf3 = buf2 + NFH;
    float* buf4 = buf3 + NFH;            // buf3+buf4 contiguous -> MoE h region (2*NF rows worst-case)
    float* s0   = buf4 + NFH;
    float* s1   = s0 + (size_t)BATCH*H;
    float* s2   = s1 + (size_t)BATCH*H;
    float* s3   = s2 + (size_t)BATCH*H;
    float* s5   = s3 + (size_t)BATCH*H;
    float* s6   = s5 + (size_t)BATCH*H;
    float* s4   = s6 + (size_t)BATCH*H;  // 2*BATCH rows
    float* top_w   = s4 + (size_t)2*BATCH*H;
    float* pair_w  = top_w + (size_t)NF*2;
    int*   top_idx = (int*)(pair_w + (size_t)NF*2);
    int*   pair_tok= top_idx + (size_t)NF*2;
    int*   counts  = pair_tok + (size_t)NF*2;
    int*   offsets = counts + NEXP;
    int*   cursor  = offsets + NEXP;

    dim3 blk(256);
    dim3 gfull((NF+63)/64, H/64);
    dim3 gsmall((BATCH+63)/64, H/64);
    dim3 mfull((NF+63)/64, H/64, NEXP);
    dim3 msmall((BATCH+63)/64, H/64, NEXP);

    embed_kernel<<<NF, blk, 0, stream>>>(log_seqs, item_emb, pos_emb, buf0);

    // ================= block 0 : full sequence =================
    {
        const int i = 0;
        const float* Wq = inproj_w + (size_t)i*3*H*H;
        const float* Wk = Wq + (size_t)H*H;
        const float* Wv = Wk + (size_t)H*H;
        const float* bq = inproj_b + (size_t)i*3*H;
        ln_kernel<<<NF, blk, 0, stream>>>(buf0, nullptr, buf1, ln1_w + i*H, ln1_b + i*H, 1e-8f, 0, 1);
        gemm_nt<<<gfull, blk, 0, stream>>>(buf1, Wq, bq,       buf2, NF);   // q
        gemm_nt<<<gfull, blk, 0, stream>>>(buf0, Wk, bq + H,   buf3, NF);   // k
        gemm_nt<<<gfull, blk, 0, stream>>>(buf0, Wv, bq + 2*H, buf4, NF);   // v
        attn_kernel<<<dim3(BATCH, NHEAD), blk, 0, stream>>>(buf2, buf3, buf4, buf0, SEQL);
        gemm_nt<<<gfull, blk, 0, stream>>>(buf0, outproj_w + (size_t)i*H*H, outproj_b + i*H, buf2, NF);
        ln_kernel<<<NF, blk, 0, stream>>>(buf1, buf2, buf0, ln2_w + i*H, ln2_b + i*H, 1e-8f, 0, 1);
        zero_kernel<<<1, 32, 0, stream>>>((float*)counts, NEXP);
        gate_kernel<<<NF, blk, 0, stream>>>(buf0, gate_w + (size_t)i*NEXP*H, gate_b + i*NEXP,
                                            top_idx, top_w, counts, NF);
        scan_kernel<<<1, 1, 0, stream>>>(counts, offsets, cursor);
        scatter_kernel<<<(NF+255)/256, blk, 0, stream>>>(top_idx, top_w, cursor, pair_tok, pair_w, NF);
        moe_gemm1<<<mfull, blk, 0, stream>>>(buf0, e_w1 + (size_t)i*NEXP*H*H, e_b1 + (size_t)i*NEXP*H,
                                             pair_tok, offsets, counts, buf3);
        zero_kernel<<<(int)((NFH+255)/256), blk, 0, stream>>>(buf2, (int)NFH);
        moe_gemm2<<<mfull, blk, 0, stream>>>(buf3, e_w2 + (size_t)i*NEXP*H*H, e_b2 + (size_t)i*NEXP*H,
                                             pair_tok, pair_w, offsets, counts, buf2);
        ln_kernel<<<NF, blk, 0, stream>>>(buf0, buf2, buf1, moeln_w + i*H, moeln_b + i*H, 1e-5f, 0, 1);
    }

    // ================= block 1 : only last position matters downstream =================
    {
        const int i = 1;
        const float* Wq = inproj_w + (size_t)i*3*H*H;
        const float* Wk = Wq + (size_t)H*H;
        const float* Wv = Wk + (size_t)H*H;
        const float* bq = inproj_b + (size_t)i*3*H;
        float* X = buf1;
        ln_kernel<<<BATCH, blk, 0, stream>>>(X, nullptr, s0, ln1_w + i*H, ln1_b + i*H, 1e-8f, SEQL-1, SEQL);
        gemm_nt<<<gsmall, blk, 0, stream>>>(s0, Wq, bq, s1, BATCH);          // q (last rows only)
        gemm_nt<<<gfull, blk, 0, stream>>>(X, Wk, bq + H,   buf3, NF);       // k (full)
        gemm_nt<<<gfull, blk, 0, stream>>>(X, Wv, bq + 2*H, buf4, NF);       // v (full)
        attn_kernel<<<dim3(BATCH, NHEAD), blk, 0, stream>>>(s1, buf3, buf4, s2, 1);
        gemm_nt<<<gsmall, blk, 0, stream>>>(s2, outproj_w + (size_t)i*H*H, outproj_b + i*H, s3, BATCH);
        ln_kernel<<<BATCH, blk, 0, stream>>>(s0, s3, s2, ln2_w + i*H, ln2_b + i*H, 1e-8f, 0, 1);
        zero_kernel<<<1, 32, 0, stream>>>((float*)counts, NEXP);
        gate_kernel<<<BATCH, blk, 0, stream>>>(s2, gate_w + (size_t)i*NEXP*H, gate_b + i*NEXP,
                                               top_idx, top_w, counts, BATCH);
        scan_kernel<<<1, 1, 0, stream>>>(counts, offsets, cursor);
        scatter_kernel<<<1, blk, 0, stream>>>(top_idx, top_w, cursor, pair_tok, pair_w, BATCH);
        moe_gemm1<<<msmall, blk, 0, stream>>>(s2, e_w1 + (size_t)i*NEXP*H*H, e_b1 + (size_t)i*NEXP*H,
                                              pair_tok, offsets, counts, s4);
        zero_kernel<<<(BATCH*H+255)/256, blk, 0, stream>>>(s5, BATCH*H);
        moe_gemm2<<<msmall, blk, 0, stream>>>(s4, e_w2 + (size_t)i*NEXP*H*H, e_b2 + (size_t)i*NEXP*H,
                                              pair_tok, pair_w, offsets, counts, s5);
        ln_kernel<<<BATCH, blk, 0, stream>>>(s2, s5, s6, moeln_w + i*H, moeln_b + i*H, 1e-5f, 0, 1);
    }

    final_kernel<<<BATCH, blk, 0, stream>>>(s6, lastln_w, lastln_b, user_emb, item_emb,
                                            user_ids, item_ids, (float*)d_out);
}

// Round 4
// 1160.107 us; speedup vs baseline: 1.6452x; 1.6452x over previous
//
#include <hip/hip_runtime.h>
#include <math.h>

#define H 256
#define NHEAD 4
#define HD 64
#define NEXP 8
#define SEQL 200
#define BATCH 128
#define NF (BATCH*SEQL)

// ---------------- helpers ----------------
__device__ __forceinline__ float blk_sum256(float v, float* s4) {
    #pragma unroll
    for (int o = 32; o > 0; o >>= 1) v += __shfl_xor(v, o, 64);
    __syncthreads();
    if ((threadIdx.x & 63) == 0) s4[threadIdx.x >> 6] = v;
    __syncthreads();
    return s4[0] + s4[1] + s4[2] + s4[3];
}

// ---------------- embedding ----------------
__global__ __launch_bounds__(256) void embed_kernel(
    const int* __restrict__ seqs, const float* __restrict__ item_emb,
    const float* __restrict__ pos_emb, float* __restrict__ x)
{
    int n = blockIdx.x, t = threadIdx.x;
    int id = seqs[n];
    int pos = (id != 0) ? (n % SEQL) + 1 : 0;
    x[(size_t)n*H + t] = item_emb[(size_t)id*H + t] * 16.0f + pos_emb[(size_t)pos*H + t];
}

// ---------------- layernorm (gather + optional residual) ----------------
__global__ __launch_bounds__(256) void ln_kernel(
    const float* __restrict__ in, const float* __restrict__ res,
    float* __restrict__ out, const float* __restrict__ w, const float* __restrict__ b,
    float eps, int base, int step)
{
    __shared__ float s4[4];
    int r = blockIdx.x, t = threadIdx.x;
    float v = in[(size_t)(base + r*step)*H + t];
    if (res) v += res[(size_t)r*H + t];
    float mean = blk_sum256(v, s4) * (1.f/H);
    float d = v - mean;
    float var = blk_sum256(d*d, s4) * (1.f/H);
    out[(size_t)r*H + t] = d * rsqrtf(var + eps) * w[t] + b[t];
}

// ---------------- GEMM: out[r][o] = sum_h A[r][h]*W[o][h] + bias[o] ----------------
__global__ __launch_bounds__(256) void gemm_nt(
    const float* __restrict__ A, const float* __restrict__ W,
    const float* __restrict__ bias, float* __restrict__ out, int nrows)
{
    __shared__ float As[16][68];
    __shared__ float Ws[16][68];
    int r0 = blockIdx.x * 64;
    if (r0 >= nrows) return;
    int c0 = blockIdx.y * 64;
    int tid = threadIdx.x;
    int tx = tid & 15, ty = tid >> 4;
    int lrow = tid >> 2, lkg = (tid & 3) << 2;
    float acc[4][4] = {};
    for (int kk = 0; kk < H; kk += 16) {
        float4 av = make_float4(0.f,0.f,0.f,0.f);
        int gr = r0 + lrow;
        if (gr < nrows) av = *(const float4*)(A + (size_t)gr*H + kk + lkg);
        As[lkg+0][lrow]=av.x; As[lkg+1][lrow]=av.y; As[lkg+2][lrow]=av.z; As[lkg+3][lrow]=av.w;
        float4 wv = *(const float4*)(W + (size_t)(c0+lrow)*H + kk + lkg);
        Ws[lkg+0][lrow]=wv.x; Ws[lkg+1][lrow]=wv.y; Ws[lkg+2][lrow]=wv.z; Ws[lkg+3][lrow]=wv.w;
        __syncthreads();
        #pragma unroll
        for (int k = 0; k < 16; ++k) {
            float4 a = *(const float4*)&As[k][ty<<2];
            float4 bv = *(const float4*)&Ws[k][tx<<2];
            float aa[4] = {a.x,a.y,a.z,a.w};
            float bb[4] = {bv.x,bv.y,bv.z,bv.w};
            #pragma unroll
            for (int ii = 0; ii < 4; ++ii)
                #pragma unroll
                for (int jj = 0; jj < 4; ++jj)
                    acc[ii][jj] += aa[ii] * bb[jj];
        }
        __syncthreads();
    }
    #pragma unroll
    for (int ii = 0; ii < 4; ++ii) {
        int gr = r0 + (ty<<2) + ii;
        if (gr < nrows) {
            #pragma unroll
            for (int jj = 0; jj < 4; ++jj) {
                int gc = c0 + (tx<<2) + jj;
                out[(size_t)gr*H + gc] = acc[ii][jj] + bias[gc];
            }
        }
    }
}

// ---------------- fused attention: one block per (batch, head) ----------------
__global__ __launch_bounds__(256) void attn_kernel(
    const float* __restrict__ qbuf, const float* __restrict__ kbuf,
    const float* __restrict__ vbuf, float* __restrict__ ctx, int nq)
{
    __shared__ float Vs[SEQL][HD];
    __shared__ float qs[4][HD];
    __shared__ float ps[4][SEQL];
    int b = blockIdx.x, h = blockIdx.y;
    int tid = threadIdx.x;
    for (int idx = tid; idx < SEQL*HD; idx += 256) {
        int key = idx >> 6, j = idx & 63;
        Vs[key][j] = vbuf[(size_t)(b*SEQL + key)*H + h*HD + j];
    }
    __syncthreads();
    int w = tid >> 6, lane = tid & 63;
    int iters = (nq + 3) >> 2;
    for (int it = 0; it < iters; ++it) {
        int qi = it*4 + w;
        bool active = qi < nq;
        int qpos = qi + (SEQL - nq);
        int nkey = active ? (qpos + 1) : 0;
        if (active) qs[w][lane] = qbuf[(size_t)(b*nq + qi)*H + h*HD + lane];
        float sc[4]; float m = -1e30f;
        #pragma unroll
        for (int c = 0; c < 4; ++c) {
            int key = lane + (c<<6);
            float s = -1e30f;
            if (key < nkey) {
                const float* kr = kbuf + (size_t)(b*SEQL + key)*H + h*HD;
                float acc = 0.f;
                for (int j = 0; j < HD; ++j) acc += qs[w][j] * kr[j];
                s = acc * 0.125f;
            }
            sc[c] = s; m = fmaxf(m, s);
        }
        #pragma unroll
        for (int o = 32; o > 0; o >>= 1) m = fmaxf(m, __shfl_xor(m, o, 64));
        float sum = 0.f;
        #pragma unroll
        for (int c = 0; c < 4; ++c) {
            float ev = (sc[c] > -1e29f) ? expf(sc[c] - m) : 0.f;
            sc[c] = ev; sum += ev;
        }
        #pragma unroll
        for (int o = 32; o > 0; o >>= 1) sum += __shfl_xor(sum, o, 64);
        float inv = 1.f / sum;
        #pragma unroll
        for (int c = 0; c < 4; ++c) {
            int key = lane + (c<<6);
            if (key < nkey) ps[w][key] = sc[c] * inv;
        }
        float acc = 0.f;
        for (int key = 0; key < nkey; ++key) acc += ps[w][key] * Vs[key][lane];
        if (active) ctx[(size_t)(b*nq + qi)*H + h*HD + lane] = acc;
    }
}

// ---------------- gate: logits + top-2 (R1 bit-exact compute; NO global atomics) --------
__global__ __launch_bounds__(256) void gate_kernel(
    const float* __restrict__ X, const float* __restrict__ gw, const float* __restrict__ gb,
    int* __restrict__ top_idx, float* __restrict__ top_w, int nrows)
{
    __shared__ float gl[NEXP];
    int n = blockIdx.x;
    int tid = threadIdx.x;
    int wv = tid >> 6, lane = tid & 63;
    float xv[4];
    #pragma unroll
    for (int c = 0; c < 4; ++c) xv[c] = X[(size_t)n*H + lane + (c<<6)];
    #pragma unroll
    for (int s = 0; s < 2; ++s) {
        int e = wv*2 + s;
        float acc = 0.f;
        #pragma unroll
        for (int c = 0; c < 4; ++c) acc += xv[c] * gw[(size_t)e*H + lane + (c<<6)];
        #pragma unroll
        for (int o = 32; o > 0; o >>= 1) acc += __shfl_xor(acc, o, 64);
        if (lane == 0) gl[e] = acc + gb[e];
    }
    __syncthreads();
    if (tid == 0) {
        int i0 = 0;
        for (int e = 1; e < NEXP; ++e) if (gl[e] > gl[i0]) i0 = e;
        int i1 = -1;
        for (int e = 0; e < NEXP; ++e) { if (e == i0) continue; if (i1 < 0 || gl[e] > gl[i1]) i1 = e; }
        float e1 = expf(gl[i1] - gl[i0]);
        float w0 = 1.f / (1.f + e1);
        top_idx[n*2+0] = i0; top_idx[n*2+1] = i1;
        top_w[n*2+0] = w0;  top_w[n*2+1] = 1.f - w0;
    }
}

// ---------------- count: LDS histogram, <=8 global atomics per 256 tokens ----------------
__global__ __launch_bounds__(256) void count_kernel(
    const int* __restrict__ top_idx, int* __restrict__ counts, int nrows)
{
    __shared__ int hist[NEXP];
    int tid = threadIdx.x;
    if (tid < NEXP) hist[tid] = 0;
    __syncthreads();
    int n = blockIdx.x * 256 + tid;
    if (n < nrows) {
        atomicAdd(&hist[top_idx[n*2+0]], 1);
        atomicAdd(&hist[top_idx[n*2+1]], 1);
    }
    __syncthreads();
    if (tid < NEXP && hist[tid] > 0) atomicAdd(&counts[tid], hist[tid]);
}

__global__ void scan_kernel(const int* __restrict__ counts, int* __restrict__ offsets,
                            int* __restrict__ cursor)
{
    int s = 0;
    for (int e = 0; e < NEXP; ++e) { offsets[e] = s; cursor[e] = s; s += counts[e]; }
}

// ---------------- block-aggregated scatter ----------------
__global__ __launch_bounds__(256) void scatter_kernel(
    const int* __restrict__ top_idx, const float* __restrict__ top_w,
    int* __restrict__ cursor, int* __restrict__ pair_tok, float* __restrict__ pair_w, int nrows)
{
    __shared__ int lcnt[NEXP];
    __shared__ int lbase[NEXP];
    int tid = threadIdx.x;
    if (tid < NEXP) lcnt[tid] = 0;
    __syncthreads();
    int n = blockIdx.x * 256 + tid;
    int e0 = 0, e1 = 0, p0 = 0, p1 = 0;
    bool act = n < nrows;
    if (act) {
        e0 = top_idx[n*2+0]; e1 = top_idx[n*2+1];
        p0 = atomicAdd(&lcnt[e0], 1);
        p1 = atomicAdd(&lcnt[e1], 1);
    }
    __syncthreads();
    if (tid < NEXP) lbase[tid] = (lcnt[tid] > 0) ? atomicAdd(&cursor[tid], lcnt[tid]) : 0;
    __syncthreads();
    if (act) {
        int q0 = lbase[e0] + p0, q1 = lbase[e1] + p1;
        pair_tok[q0] = n; pair_w[q0] = top_w[n*2+0];
        pair_tok[q1] = n; pair_w[q1] = top_w[n*2+1];
    }
}

// ---------------- grouped MoE GEMM 1: h = relu(X[tok] @ W1[e] + b1[e]) ----------------
__global__ __launch_bounds__(256) void moe_gemm1(
    const float* __restrict__ X, const float* __restrict__ W1base,
    const float* __restrict__ b1base, const int* __restrict__ pair_tok,
    const int* __restrict__ offsets, const int* __restrict__ counts,
    float* __restrict__ hbuf)
{
    int e = blockIdx.z;
    int cnt = counts[e];
    int r0 = blockIdx.x * 64;
    if (r0 >= cnt) return;
    int off = offsets[e];
    int c0 = blockIdx.y * 64;
    const float* W = W1base + (size_t)e * H * H;
    const float* bias = b1base + (size_t)e * H;
    __shared__ float As[16][68];
    __shared__ float Bs[16][68];
    int tid = threadIdx.x, tx = tid & 15, ty = tid >> 4;
    int lrow = tid >> 2, lkg = (tid & 3) << 2;
    float acc[4][4] = {};
    for (int kk = 0; kk < H; kk += 16) {
        float4 av = make_float4(0.f,0.f,0.f,0.f);
        int pr = r0 + lrow;
        if (pr < cnt) {
            int tok = pair_tok[off + pr];
            av = *(const float4*)(X + (size_t)tok*H + kk + lkg);
        }
        As[lkg+0][lrow]=av.x; As[lkg+1][lrow]=av.y; As[lkg+2][lrow]=av.z; As[lkg+3][lrow]=av.w;
        float4 wv = *(const float4*)(W + (size_t)(kk+ty)*H + c0 + (tx<<2));
        *(float4*)&Bs[ty][tx<<2] = wv;
        __syncthreads();
        #pragma unroll
        for (int k = 0; k < 16; ++k) {
            float4 a = *(const float4*)&As[k][ty<<2];
            float4 bv = *(const float4*)&Bs[k][tx<<2];
            float aa[4] = {a.x,a.y,a.z,a.w};
            float bb[4] = {bv.x,bv.y,bv.z,bv.w};
            #pragma unroll
            for (int ii = 0; ii < 4; ++ii)
                #pragma unroll
                for (int jj = 0; jj < 4; ++jj)
                    acc[ii][jj] += aa[ii] * bb[jj];
        }
        __syncthreads();
    }
    #pragma unroll
    for (int ii = 0; ii < 4; ++ii) {
        int pr = r0 + (ty<<2) + ii;
        if (pr < cnt) {
            #pragma unroll
            for (int jj = 0; jj < 4; ++jj) {
                int gc = c0 + (tx<<2) + jj;
                hbuf[(size_t)(off+pr)*H + gc] = fmaxf(acc[ii][jj] + bias[gc], 0.f);
            }
        }
    }
}

// ---------------- grouped MoE GEMM 2: acc[tok] += w * (h @ W2[e] + b2[e]) ----------------
__global__ __launch_bounds__(256) void moe_gemm2(
    const float* __restrict__ Hbuf, const float* __restrict__ W2base,
    const float* __restrict__ b2base, const int* __restrict__ pair_tok,
    const float* __restrict__ pair_w, const int* __restrict__ offsets,
    const int* __restrict__ counts, float* __restrict__ accbuf)
{
    int e = blockIdx.z;
    int cnt = counts[e];
    int r0 = blockIdx.x * 64;
    if (r0 >= cnt) return;
    int off = offsets[e];
    int c0 = blockIdx.y * 64;
    const float* W = W2base + (size_t)e * H * H;
    const float* bias = b2base + (size_t)e * H;
    __shared__ float As[16][68];
    __shared__ float Bs[16][68];
    int tid = threadIdx.x, tx = tid & 15, ty = tid >> 4;
    int lrow = tid >> 2, lkg = (tid & 3) << 2;
    float acc[4][4] = {};
    for (int kk = 0; kk < H; kk += 16) {
        float4 av = make_float4(0.f,0.f,0.f,0.f);
        int pr = r0 + lrow;
        if (pr < cnt) av = *(const float4*)(Hbuf + (size_t)(off+pr)*H + kk + lkg);
        As[lkg+0][lrow]=av.x; As[lkg+1][lrow]=av.y; As[lkg+2][lrow]=av.z; As[lkg+3][lrow]=av.w;
        float4 wv = *(const float4*)(W + (size_t)(kk+ty)*H + c0 + (tx<<2));
        *(float4*)&Bs[ty][tx<<2] = wv;
        __syncthreads();
        #pragma unroll
        for (int k = 0; k < 16; ++k) {
            float4 a = *(const float4*)&As[k][ty<<2];
            float4 bv = *(const float4*)&Bs[k][tx<<2];
            float aa[4] = {a.x,a.y,a.z,a.w};
            float bb[4] = {bv.x,bv.y,bv.z,bv.w};
            #pragma unroll
            for (int ii = 0; ii < 4; ++ii)
                #pragma unroll
                for (int jj = 0; jj < 4; ++jj)
                    acc[ii][jj] += aa[ii] * bb[jj];
        }
        __syncthreads();
    }
    #pragma unroll
    for (int ii = 0; ii < 4; ++ii) {
        int pr = r0 + (ty<<2) + ii;
        if (pr < cnt) {
            int tok = pair_tok[off + pr];
            float pw = pair_w[off + pr];
            #pragma unroll
            for (int jj = 0; jj < 4; ++jj) {
                int gc = c0 + (tx<<2) + jj;
                atomicAdd(&accbuf[(size_t)tok*H + gc], pw * (acc[ii][jj] + bias[gc]));
            }
        }
    }
}

__global__ void zero_kernel(float* __restrict__ p, int n) {
    int i = blockIdx.x * 256 + threadIdx.x;
    if (i < n) p[i] = 0.f;
}

// ---------------- final: LN + user emb + dot(item emb) ----------------
__global__ __launch_bounds__(256) void final_kernel(
    const float* __restrict__ xf, const float* __restrict__ lnw, const float* __restrict__ lnb,
    const float* __restrict__ user_emb, const float* __restrict__ item_emb,
    const int* __restrict__ user_ids, const int* __restrict__ item_ids, float* __restrict__ out)
{
    __shared__ float s4[4];
    int bb = blockIdx.x, t = threadIdx.x;
    float v = xf[(size_t)bb*H + t];
    float mean = blk_sum256(v, s4) * (1.f/H);
    float d = v - mean;
    float var = blk_sum256(d*d, s4) * (1.f/H);
    float lnv = d * rsqrtf(var + 1e-8f) * lnw[t] + lnb[t];
    float fin = lnv + user_emb[(size_t)user_ids[bb]*H + t];
    float prod = fin * item_emb[(size_t)item_ids[bb]*H + t];
    float tot = blk_sum256(prod, s4);
    if (t == 0) out[bb] = tot;
}

// ---------------- launch ----------------
extern "C" void kernel_launch(void* const* d_in, const int* in_sizes, int n_in,
                              void* d_out, int out_size, void* d_ws, size_t ws_size,
                              hipStream_t stream)
{
    (void)in_sizes; (void)n_in; (void)out_size; (void)ws_size;
    const int*   user_ids  = (const int*)d_in[0];
    const int*   log_seqs  = (const int*)d_in[1];
    const int*   item_ids  = (const int*)d_in[2];
    const float* item_emb  = (const float*)d_in[3];
    const float* pos_emb   = (const float*)d_in[4];
    const float* user_emb  = (const float*)d_in[5];
    const float* ln1_w     = (const float*)d_in[6];
    const float* ln1_b     = (const float*)d_in[7];
    const float* inproj_w  = (const float*)d_in[8];
    const float* inproj_b  = (const float*)d_in[9];
    const float* outproj_w = (const float*)d_in[10];
    const float* outproj_b = (const float*)d_in[11];
    const float* ln2_w     = (const float*)d_in[12];
    const float* ln2_b     = (const float*)d_in[13];
    const float* gate_w    = (const float*)d_in[14];
    const float* gate_b    = (const float*)d_in[15];
    const float* e_w1      = (const float*)d_in[16];
    const float* e_b1      = (const float*)d_in[17];
    const float* e_w2      = (const float*)d_in[18];
    const float* e_b2      = (const float*)d_in[19];
    const float* moeln_w   = (const float*)d_in[20];
    const float* moeln_b   = (const float*)d_in[21];
    const float* lastln_w  = (const float*)d_in[22];
    const float* lastln_b  = (const float*)d_in[23];

    float* ws = (float*)d_ws;
    const size_t NFH = (size_t)NF * H;
    float* buf0 = ws;
    float* buf1 = buf0 + NFH;
    float* buf2 = buf1 + NFH;
    float* buf3 = buf2 + NFH;
    float* buf4 = buf3 + NFH;            // buf3+buf4 contiguous -> MoE h region (2*NF rows worst-case)
    float* s0   = buf4 + NFH;
    float* s1   = s0 + (size_t)BATCH*H;
    float* s2   = s1 + (size_t)BATCH*H;
    float* s3   = s2 + (size_t)BATCH*H;
    float* s5   = s3 + (size_t)BATCH*H;
    float* s6   = s5 + (size_t)BATCH*H;
    float* s4   = s6 + (size_t)BATCH*H;  // 2*BATCH rows
    float* top_w   = s4 + (size_t)2*BATCH*H;
    float* pair_w  = top_w + (size_t)NF*2;
    int*   top_idx = (int*)(pair_w + (size_t)NF*2);
    int*   pair_tok= top_idx + (size_t)NF*2;
    int*   counts  = pair_tok + (size_t)NF*2;
    int*   offsets = counts + NEXP;
    int*   cursor  = offsets + NEXP;

    dim3 blk(256);
    dim3 gfull((NF+63)/64, H/64);
    dim3 gsmall((BATCH+63)/64, H/64);
    dim3 mfull((NF+63)/64, H/64, NEXP);
    dim3 msmall((BATCH+63)/64, H/64, NEXP);

    embed_kernel<<<NF, blk, 0, stream>>>(log_seqs, item_emb, pos_emb, buf0);

    // ================= block 0 : full sequence =================
    {
        const int i = 0;
        const float* Wq = inproj_w + (size_t)i*3*H*H;
        const float* Wk = Wq + (size_t)H*H;
        const float* Wv = Wk + (size_t)H*H;
        const float* bq = inproj_b + (size_t)i*3*H;
        ln_kernel<<<NF, blk, 0, stream>>>(buf0, nullptr, buf1, ln1_w + i*H, ln1_b + i*H, 1e-8f, 0, 1);
        gemm_nt<<<gfull, blk, 0, stream>>>(buf1, Wq, bq,       buf2, NF);   // q
        gemm_nt<<<gfull, blk, 0, stream>>>(buf0, Wk, bq + H,   buf3, NF);   // k
        gemm_nt<<<gfull, blk, 0, stream>>>(buf0, Wv, bq + 2*H, buf4, NF);   // v
        attn_kernel<<<dim3(BATCH, NHEAD), blk, 0, stream>>>(buf2, buf3, buf4, buf0, SEQL);
        gemm_nt<<<gfull, blk, 0, stream>>>(buf0, outproj_w + (size_t)i*H*H, outproj_b + i*H, buf2, NF);
        ln_kernel<<<NF, blk, 0, stream>>>(buf1, buf2, buf0, ln2_w + i*H, ln2_b + i*H, 1e-8f, 0, 1);
        zero_kernel<<<1, 32, 0, stream>>>((float*)counts, NEXP);
        gate_kernel<<<NF, blk, 0, stream>>>(buf0, gate_w + (size_t)i*NEXP*H, gate_b + i*NEXP,
                                            top_idx, top_w, NF);
        count_kernel<<<(NF+255)/256, blk, 0, stream>>>(top_idx, counts, NF);
        scan_kernel<<<1, 1, 0, stream>>>(counts, offsets, cursor);
        scatter_kernel<<<(NF+255)/256, blk, 0, stream>>>(top_idx, top_w, cursor, pair_tok, pair_w, NF);
        moe_gemm1<<<mfull, blk, 0, stream>>>(buf0, e_w1 + (size_t)i*NEXP*H*H, e_b1 + (size_t)i*NEXP*H,
                                             pair_tok, offsets, counts, buf3);
        zero_kernel<<<(int)((NFH+255)/256), blk, 0, stream>>>(buf2, (int)NFH);
        moe_gemm2<<<mfull, blk, 0, stream>>>(buf3, e_w2 + (size_t)i*NEXP*H*H, e_b2 + (size_t)i*NEXP*H,
                                             pair_tok, pair_w, offsets, counts, buf2);
        ln_kernel<<<NF, blk, 0, stream>>>(buf0, buf2, buf1, moeln_w + i*H, moeln_b + i*H, 1e-5f, 0, 1);
    }

    // ================= block 1 : only last position matters downstream =================
    {
        const int i = 1;
        const float* Wq = inproj_w + (size_t)i*3*H*H;
        const float* Wk = Wq + (size_t)H*H;
        const float* Wv = Wk + (size_t)H*H;
        const float* bq = inproj_b + (size_t)i*3*H;
        float* X = buf1;
        ln_kernel<<<BATCH, blk, 0, stream>>>(X, nullptr, s0, ln1_w + i*H, ln1_b + i*H, 1e-8f, SEQL-1, SEQL);
        gemm_nt<<<gsmall, blk, 0, stream>>>(s0, Wq, bq, s1, BATCH);          // q (last rows only)
        gemm_nt<<<gfull, blk, 0, stream>>>(X, Wk, bq + H,   buf3, NF);       // k (full)
        gemm_nt<<<gfull, blk, 0, stream>>>(X, Wv, bq + 2*H, buf4, NF);       // v (full)
        attn_kernel<<<dim3(BATCH, NHEAD), blk, 0, stream>>>(s1, buf3, buf4, s2, 1);
        gemm_nt<<<gsmall, blk, 0, stream>>>(s2, outproj_w + (size_t)i*H*H, outproj_b + i*H, s3, BATCH);
        ln_kernel<<<BATCH, blk, 0, stream>>>(s0, s3, s2, ln2_w + i*H, ln2_b + i*H, 1e-8f, 0, 1);
        zero_kernel<<<1, 32, 0, stream>>>((float*)counts, NEXP);
        gate_kernel<<<BATCH, blk, 0, stream>>>(s2, gate_w + (size_t)i*NEXP*H, gate_b + i*NEXP,
                                               top_idx, top_w, BATCH);
        count_kernel<<<1, blk, 0, stream>>>(top_idx, counts, BATCH);
        scan_kernel<<<1, 1, 0, stream>>>(counts, offsets, cursor);
        scatter_kernel<<<1, blk, 0, stream>>>(top_idx, top_w, cursor, pair_tok, pair_w, BATCH);
        moe_gemm1<<<msmall, blk, 0, stream>>>(s2, e_w1 + (size_t)i*NEXP*H*H, e_b1 + (size_t)i*NEXP*H,
                                              pair_tok, offsets, counts, s4);
        zero_kernel<<<(BATCH*H+255)/256, blk, 0, stream>>>(s5, BATCH*H);
        moe_gemm2<<<msmall, blk, 0, stream>>>(s4, e_w2 + (size_t)i*NEXP*H*H, e_b2 + (size_t)i*NEXP*H,
                                              pair_tok, pair_w, offsets, counts, s5);
        ln_kernel<<<BATCH, blk, 0, stream>>>(s2, s5, s6, moeln_w + i*H, moeln_b + i*H, 1e-5f, 0, 1);
    }

    final_kernel<<<BATCH, blk, 0, stream>>>(s6, lastln_w, lastln_b, user_emb, item_emb,
                                            user_ids, item_ids, (float*)d_out);
}

// Round 5
// 1117.305 us; speedup vs baseline: 1.7082x; 1.0383x over previous
//
#include <hip/hip_runtime.h>
#include <math.h>

#define H 256
#define NHEAD 4
#define HD 64
#define NEXP 8
#define SEQL 200
#define BATCH 128
#define NF (BATCH*SEQL)
#define KT 64

// ---------------- helpers ----------------
__device__ __forceinline__ float blk_sum256(float v, float* s4) {
    #pragma unroll
    for (int o = 32; o > 0; o >>= 1) v += __shfl_xor(v, o, 64);
    __syncthreads();
    if ((threadIdx.x & 63) == 0) s4[threadIdx.x >> 6] = v;
    __syncthreads();
    return s4[0] + s4[1] + s4[2] + s4[3];
}

// ---------------- embedding ----------------
__global__ __launch_bounds__(256) void embed_kernel(
    const int* __restrict__ seqs, const float* __restrict__ item_emb,
    const float* __restrict__ pos_emb, float* __restrict__ x)
{
    int n = blockIdx.x, t = threadIdx.x;
    int id = seqs[n];
    int pos = (id != 0) ? (n % SEQL) + 1 : 0;
    x[(size_t)n*H + t] = item_emb[(size_t)id*H + t] * 16.0f + pos_emb[(size_t)pos*H + t];
}

// ---------------- layernorm (gather + optional residual) ----------------
__global__ __launch_bounds__(256) void ln_kernel(
    const float* __restrict__ in, const float* __restrict__ res,
    float* __restrict__ out, const float* __restrict__ w, const float* __restrict__ b,
    float eps, int base, int step)
{
    __shared__ float s4[4];
    int r = blockIdx.x, t = threadIdx.x;
    float v = in[(size_t)(base + r*step)*H + t];
    if (res) v += res[(size_t)r*H + t];
    float mean = blk_sum256(v, s4) * (1.f/H);
    float d = v - mean;
    float var = blk_sum256(d*d, s4) * (1.f/H);
    out[(size_t)r*H + t] = d * rsqrtf(var + eps) * w[t] + b[t];
}

// ---------------- fused moe combine + layernorm ----------------
__global__ __launch_bounds__(256) void moe_ln_kernel(
    const float* __restrict__ x, const float* __restrict__ ybuf,
    const int* __restrict__ tok_pair, const float* __restrict__ top_w,
    float* __restrict__ out, const float* __restrict__ w, const float* __restrict__ b,
    float eps)
{
    __shared__ float s4[4];
    int r = blockIdx.x, t = threadIdx.x;
    int p0 = tok_pair[r*2], p1 = tok_pair[r*2+1];
    float v = x[(size_t)r*H + t]
            + top_w[r*2+0] * ybuf[(size_t)p0*H + t]
            + top_w[r*2+1] * ybuf[(size_t)p1*H + t];
    float mean = blk_sum256(v, s4) * (1.f/H);
    float d = v - mean;
    float var = blk_sum256(d*d, s4) * (1.f/H);
    out[(size_t)r*H + t] = d * rsqrtf(var + eps) * w[t] + b[t];
}

// ---------------- GEMM: out[r][o] = sum_h A[r][h]*W[o][h] + bias[o] ----------------
__global__ __launch_bounds__(256) void gemm_nt(
    const float* __restrict__ A, const float* __restrict__ W,
    const float* __restrict__ bias, float* __restrict__ out, int nrows)
{
    __shared__ float As[16][68];
    __shared__ float Ws[16][68];
    int r0 = blockIdx.x * 64;
    if (r0 >= nrows) return;
    int c0 = blockIdx.y * 64;
    int tid = threadIdx.x;
    int tx = tid & 15, ty = tid >> 4;
    int lrow = tid >> 2, lkg = (tid & 3) << 2;
    float acc[4][4] = {};
    for (int kk = 0; kk < H; kk += 16) {
        float4 av = make_float4(0.f,0.f,0.f,0.f);
        int gr = r0 + lrow;
        if (gr < nrows) av = *(const float4*)(A + (size_t)gr*H + kk + lkg);
        As[lkg+0][lrow]=av.x; As[lkg+1][lrow]=av.y; As[lkg+2][lrow]=av.z; As[lkg+3][lrow]=av.w;
        float4 wv = *(const float4*)(W + (size_t)(c0+lrow)*H + kk + lkg);
        Ws[lkg+0][lrow]=wv.x; Ws[lkg+1][lrow]=wv.y; Ws[lkg+2][lrow]=wv.z; Ws[lkg+3][lrow]=wv.w;
        __syncthreads();
        #pragma unroll
        for (int k = 0; k < 16; ++k) {
            float4 a = *(const float4*)&As[k][ty<<2];
            float4 bv = *(const float4*)&Ws[k][tx<<2];
            float aa[4] = {a.x,a.y,a.z,a.w};
            float bb[4] = {bv.x,bv.y,bv.z,bv.w};
            #pragma unroll
            for (int ii = 0; ii < 4; ++ii)
                #pragma unroll
                for (int jj = 0; jj < 4; ++jj)
                    acc[ii][jj] += aa[ii] * bb[jj];
        }
        __syncthreads();
    }
    #pragma unroll
    for (int ii = 0; ii < 4; ++ii) {
        int gr = r0 + (ty<<2) + ii;
        if (gr < nrows) {
            #pragma unroll
            for (int jj = 0; jj < 4; ++jj) {
                int gc = c0 + (tx<<2) + jj;
                out[(size_t)gr*H + gc] = acc[ii][jj] + bias[gc];
            }
        }
    }
}

// ---------------- flash-style fp32 attention ----------------
// grid (B, NH, qsplit); 4 waves = 4 queries per group; online softmax in registers.
__global__ __launch_bounds__(256) void attn_kernel(
    const float* __restrict__ qbuf, const float* __restrict__ kbuf,
    const float* __restrict__ vbuf, float* __restrict__ ctx, int nq)
{
    __shared__ float Ks[KT][HD+1];
    __shared__ float Vs[KT][HD+1];
    __shared__ float qs[4][HD];
    int b = blockIdx.x, h = blockIdx.y, z = blockIdx.z;
    int qsplit = gridDim.z;
    int tid = threadIdx.x;
    int w = tid >> 6, lane = tid & 63;
    int ngroups = (nq + 3) >> 2;
    int off = SEQL - nq;
    for (int g = z; g < ngroups; g += qsplit) {
        int q = g*4 + w;
        bool active = q < nq;
        int qpos = q + off;
        int gmaxq = (g*4 + 3 < nq ? g*4 + 3 : nq - 1) + off;
        int ntiles = (gmaxq + KT) / KT;
        if (active) qs[w][lane] = qbuf[(size_t)(b*nq + q)*H + h*HD + lane];
        float m = -1e30f, l = 0.f, acc = 0.f;
        for (int t = 0; t < ntiles; ++t) {
            __syncthreads();
            for (int i = tid; i < KT*(HD/4); i += 256) {
                int row = i >> 4, c4 = (i & 15) << 2;
                int key = t*KT + row;
                float4 kv = make_float4(0.f,0.f,0.f,0.f);
                float4 vv = make_float4(0.f,0.f,0.f,0.f);
                if (key < SEQL) {
                    size_t base = (size_t)(b*SEQL + key)*H + h*HD + c4;
                    kv = *(const float4*)(kbuf + base);
                    vv = *(const float4*)(vbuf + base);
                }
                Ks[row][c4+0]=kv.x; Ks[row][c4+1]=kv.y; Ks[row][c4+2]=kv.z; Ks[row][c4+3]=kv.w;
                Vs[row][c4+0]=vv.x; Vs[row][c4+1]=vv.y; Vs[row][c4+2]=vv.z; Vs[row][c4+3]=vv.w;
            }
            __syncthreads();
            // scores: this lane owns key t*KT+lane
            float s = 0.f;
            #pragma unroll
            for (int d = 0; d < HD; d += 4) {
                s += qs[w][d+0]*Ks[lane][d+0] + qs[w][d+1]*Ks[lane][d+1]
                   + qs[w][d+2]*Ks[lane][d+2] + qs[w][d+3]*Ks[lane][d+3];
            }
            s *= 0.125f;
            int key = t*KT + lane;
            bool valid = active && (key <= qpos);
            float sv = valid ? s : -1e30f;
            float tm = sv;
            #pragma unroll
            for (int o = 32; o > 0; o >>= 1) tm = fmaxf(tm, __shfl_xor(tm, o, 64));
            float mnew = fmaxf(m, tm);
            float p = valid ? expf(s - mnew) : 0.f;
            float psum = p;
            #pragma unroll
            for (int o = 32; o > 0; o >>= 1) psum += __shfl_xor(psum, o, 64);
            float scale = expf(m - mnew);
            l = l*scale + psum;
            acc *= scale;
            #pragma unroll 4
            for (int k = 0; k < KT; ++k) {
                float pk = __shfl(p, k, 64);
                acc += pk * Vs[k][lane];
            }
            m = mnew;
        }
        if (active) ctx[(size_t)(b*nq + q)*H + h*HD + lane] = acc / l;
    }
}

// ---------------- gate: logits + top-2 (no global atomics) ----------------
__global__ __launch_bounds__(256) void gate_kernel(
    const float* __restrict__ X, const float* __restrict__ gw, const float* __restrict__ gb,
    int* __restrict__ top_idx, float* __restrict__ top_w, int nrows)
{
    __shared__ float gl[NEXP];
    int n = blockIdx.x;
    int tid = threadIdx.x;
    int wv = tid >> 6, lane = tid & 63;
    float xv[4];
    #pragma unroll
    for (int c = 0; c < 4; ++c) xv[c] = X[(size_t)n*H + lane + (c<<6)];
    #pragma unroll
    for (int s = 0; s < 2; ++s) {
        int e = wv*2 + s;
        float acc = 0.f;
        #pragma unroll
        for (int c = 0; c < 4; ++c) acc += xv[c] * gw[(size_t)e*H + lane + (c<<6)];
        #pragma unroll
        for (int o = 32; o > 0; o >>= 1) acc += __shfl_xor(acc, o, 64);
        if (lane == 0) gl[e] = acc + gb[e];
    }
    __syncthreads();
    if (tid == 0) {
        int i0 = 0;
        for (int e = 1; e < NEXP; ++e) if (gl[e] > gl[i0]) i0 = e;
        int i1 = -1;
        for (int e = 0; e < NEXP; ++e) { if (e == i0) continue; if (i1 < 0 || gl[e] > gl[i1]) i1 = e; }
        float e1 = expf(gl[i1] - gl[i0]);
        float w0 = 1.f / (1.f + e1);
        top_idx[n*2+0] = i0; top_idx[n*2+1] = i1;
        top_w[n*2+0] = w0;  top_w[n*2+1] = 1.f - w0;
    }
}

// ---------------- count: LDS histogram ----------------
__global__ __launch_bounds__(256) void count_kernel(
    const int* __restrict__ top_idx, int* __restrict__ counts, int nrows)
{
    __shared__ int hist[NEXP];
    int tid = threadIdx.x;
    if (tid < NEXP) hist[tid] = 0;
    __syncthreads();
    int n = blockIdx.x * 256 + tid;
    if (n < nrows) {
        atomicAdd(&hist[top_idx[n*2+0]], 1);
        atomicAdd(&hist[top_idx[n*2+1]], 1);
    }
    __syncthreads();
    if (tid < NEXP && hist[tid] > 0) atomicAdd(&counts[tid], hist[tid]);
}

__global__ void scan_kernel(const int* __restrict__ counts, int* __restrict__ offsets,
                            int* __restrict__ cursor)
{
    int s = 0;
    for (int e = 0; e < NEXP; ++e) { offsets[e] = s; cursor[e] = s; s += counts[e]; }
}

// ---------------- block-aggregated scatter (+ inverse map tok_pair) ----------------
__global__ __launch_bounds__(256) void scatter_kernel(
    const int* __restrict__ top_idx,
    int* __restrict__ cursor, int* __restrict__ pair_tok, int* __restrict__ tok_pair, int nrows)
{
    __shared__ int lcnt[NEXP];
    __shared__ int lbase[NEXP];
    int tid = threadIdx.x;
    if (tid < NEXP) lcnt[tid] = 0;
    __syncthreads();
    int n = blockIdx.x * 256 + tid;
    int e0 = 0, e1 = 0, p0 = 0, p1 = 0;
    bool act = n < nrows;
    if (act) {
        e0 = top_idx[n*2+0]; e1 = top_idx[n*2+1];
        p0 = atomicAdd(&lcnt[e0], 1);
        p1 = atomicAdd(&lcnt[e1], 1);
    }
    __syncthreads();
    if (tid < NEXP) lbase[tid] = (lcnt[tid] > 0) ? atomicAdd(&cursor[tid], lcnt[tid]) : 0;
    __syncthreads();
    if (act) {
        int q0 = lbase[e0] + p0, q1 = lbase[e1] + p1;
        pair_tok[q0] = n; pair_tok[q1] = n;
        tok_pair[n*2+0] = q0; tok_pair[n*2+1] = q1;
    }
}

// ---------------- grouped MoE GEMM 1: h = relu(X[tok] @ W1[e] + b1[e]) ----------------
__global__ __launch_bounds__(256) void moe_gemm1(
    const float* __restrict__ X, const float* __restrict__ W1base,
    const float* __restrict__ b1base, const int* __restrict__ pair_tok,
    const int* __restrict__ offsets, const int* __restrict__ counts,
    float* __restrict__ hbuf)
{
    int e = blockIdx.z;
    int cnt = counts[e];
    int r0 = blockIdx.x * 64;
    if (r0 >= cnt) return;
    int off = offsets[e];
    int c0 = blockIdx.y * 64;
    const float* W = W1base + (size_t)e * H * H;
    const float* bias = b1base + (size_t)e * H;
    __shared__ float As[16][68];
    __shared__ float Bs[16][68];
    int tid = threadIdx.x, tx = tid & 15, ty = tid >> 4;
    int lrow = tid >> 2, lkg = (tid & 3) << 2;
    float acc[4][4] = {};
    for (int kk = 0; kk < H; kk += 16) {
        float4 av = make_float4(0.f,0.f,0.f,0.f);
        int pr = r0 + lrow;
        if (pr < cnt) {
            int tok = pair_tok[off + pr];
            av = *(const float4*)(X + (size_t)tok*H + kk + lkg);
        }
        As[lkg+0][lrow]=av.x; As[lkg+1][lrow]=av.y; As[lkg+2][lrow]=av.z; As[lkg+3][lrow]=av.w;
        float4 wv = *(const float4*)(W + (size_t)(kk+ty)*H + c0 + (tx<<2));
        *(float4*)&Bs[ty][tx<<2] = wv;
        __syncthreads();
        #pragma unroll
        for (int k = 0; k < 16; ++k) {
            float4 a = *(const float4*)&As[k][ty<<2];
            float4 bv = *(const float4*)&Bs[k][tx<<2];
            float aa[4] = {a.x,a.y,a.z,a.w};
            float bb[4] = {bv.x,bv.y,bv.z,bv.w};
            #pragma unroll
            for (int ii = 0; ii < 4; ++ii)
                #pragma unroll
                for (int jj = 0; jj < 4; ++jj)
                    acc[ii][jj] += aa[ii] * bb[jj];
        }
        __syncthreads();
    }
    #pragma unroll
    for (int ii = 0; ii < 4; ++ii) {
        int pr = r0 + (ty<<2) + ii;
        if (pr < cnt) {
            #pragma unroll
            for (int jj = 0; jj < 4; ++jj) {
                int gc = c0 + (tx<<2) + jj;
                hbuf[(size_t)(off+pr)*H + gc] = fmaxf(acc[ii][jj] + bias[gc], 0.f);
            }
        }
    }
}

// ---------------- grouped MoE GEMM 2: y[pair] = h @ W2[e] + b2[e]  (no atomics) ---------
__global__ __launch_bounds__(256) void moe_gemm2(
    const float* __restrict__ Hbuf, const float* __restrict__ W2base,
    const float* __restrict__ b2base, const int* __restrict__ offsets,
    const int* __restrict__ counts, float* __restrict__ ybuf)
{
    int e = blockIdx.z;
    int cnt = counts[e];
    int r0 = blockIdx.x * 64;
    if (r0 >= cnt) return;
    int off = offsets[e];
    int c0 = blockIdx.y * 64;
    const float* W = W2base + (size_t)e * H * H;
    const float* bias = b2base + (size_t)e * H;
    __shared__ float As[16][68];
    __shared__ float Bs[16][68];
    int tid = threadIdx.x, tx = tid & 15, ty = tid >> 4;
    int lrow = tid >> 2, lkg = (tid & 3) << 2;
    float acc[4][4] = {};
    for (int kk = 0; kk < H; kk += 16) {
        float4 av = make_float4(0.f,0.f,0.f,0.f);
        int pr = r0 + lrow;
        if (pr < cnt) av = *(const float4*)(Hbuf + (size_t)(off+pr)*H + kk + lkg);
        As[lkg+0][lrow]=av.x; As[lkg+1][lrow]=av.y; As[lkg+2][lrow]=av.z; As[lkg+3][lrow]=av.w;
        float4 wv = *(const float4*)(W + (size_t)(kk+ty)*H + c0 + (tx<<2));
        *(float4*)&Bs[ty][tx<<2] = wv;
        __syncthreads();
        #pragma unroll
        for (int k = 0; k < 16; ++k) {
            float4 a = *(const float4*)&As[k][ty<<2];
            float4 bv = *(const float4*)&Bs[k][tx<<2];
            float aa[4] = {a.x,a.y,a.z,a.w};
            float bb[4] = {bv.x,bv.y,bv.z,bv.w};
            #pragma unroll
            for (int ii = 0; ii < 4; ++ii)
                #pragma unroll
                for (int jj = 0; jj < 4; ++jj)
                    acc[ii][jj] += aa[ii] * bb[jj];
        }
        __syncthreads();
    }
    #pragma unroll
    for (int ii = 0; ii < 4; ++ii) {
        int pr = r0 + (ty<<2) + ii;
        if (pr < cnt) {
            #pragma unroll
            for (int jj = 0; jj < 4; ++jj) {
                int gc = c0 + (tx<<2) + jj;
                ybuf[(size_t)(off+pr)*H + gc] = acc[ii][jj] + bias[gc];
            }
        }
    }
}

__global__ void zero_kernel(float* __restrict__ p, int n) {
    int i = blockIdx.x * 256 + threadIdx.x;
    if (i < n) p[i] = 0.f;
}

// ---------------- final: LN + user emb + dot(item emb) ----------------
__global__ __launch_bounds__(256) void final_kernel(
    const float* __restrict__ xf, const float* __restrict__ lnw, const float* __restrict__ lnb,
    const float* __restrict__ user_emb, const float* __restrict__ item_emb,
    const int* __restrict__ user_ids, const int* __restrict__ item_ids, float* __restrict__ out)
{
    __shared__ float s4[4];
    int bb = blockIdx.x, t = threadIdx.x;
    float v = xf[(size_t)bb*H + t];
    float mean = blk_sum256(v, s4) * (1.f/H);
    float d = v - mean;
    float var = blk_sum256(d*d, s4) * (1.f/H);
    float lnv = d * rsqrtf(var + 1e-8f) * lnw[t] + lnb[t];
    float fin = lnv + user_emb[(size_t)user_ids[bb]*H + t];
    float prod = fin * item_emb[(size_t)item_ids[bb]*H + t];
    float tot = blk_sum256(prod, s4);
    if (t == 0) out[bb] = tot;
}

// ---------------- launch ----------------
extern "C" void kernel_launch(void* const* d_in, const int* in_sizes, int n_in,
                              void* d_out, int out_size, void* d_ws, size_t ws_size,
                              hipStream_t stream)
{
    (void)in_sizes; (void)n_in; (void)out_size; (void)ws_size;
    const int*   user_ids  = (const int*)d_in[0];
    const int*   log_seqs  = (const int*)d_in[1];
    const int*   item_ids  = (const int*)d_in[2];
    const float* item_emb  = (const float*)d_in[3];
    const float* pos_emb   = (const float*)d_in[4];
    const float* user_emb  = (const float*)d_in[5];
    const float* ln1_w     = (const float*)d_in[6];
    const float* ln1_b     = (const float*)d_in[7];
    const float* inproj_w  = (const float*)d_in[8];
    const float* inproj_b  = (const float*)d_in[9];
    const float* outproj_w = (const float*)d_in[10];
    const float* outproj_b = (const float*)d_in[11];
    const float* ln2_w     = (const float*)d_in[12];
    const float* ln2_b     = (const float*)d_in[13];
    const float* gate_w    = (const float*)d_in[14];
    const float* gate_b    = (const float*)d_in[15];
    const float* e_w1      = (const float*)d_in[16];
    const float* e_b1      = (const float*)d_in[17];
    const float* e_w2      = (const float*)d_in[18];
    const float* e_b2      = (const float*)d_in[19];
    const float* moeln_w   = (const float*)d_in[20];
    const float* moeln_b   = (const float*)d_in[21];
    const float* lastln_w  = (const float*)d_in[22];
    const float* lastln_b  = (const float*)d_in[23];

    float* ws = (float*)d_ws;
    const size_t NFH = (size_t)NF * H;
    float* buf0 = ws;
    float* buf1 = buf0 + NFH;   // buf1+buf2 contiguous -> ybuf region (2*NF rows)
    float* buf2 = buf1 + NFH;
    float* buf3 = buf2 + NFH;   // buf3+buf4 contiguous -> MoE h region (2*NF rows)
    float* buf4 = buf3 + NFH;
    float* s0   = buf4 + NFH;
    float* s1   = s0 + (size_t)BATCH*H;
    float* s2   = s1 + (size_t)BATCH*H;
    float* s3   = s2 + (size_t)BATCH*H;
    float* s6   = s3 + (size_t)BATCH*H;
    float* s4   = s6 + (size_t)BATCH*H;            // 2*BATCH rows (h)
    float* s5   = s4 + (size_t)2*BATCH*H;          // 2*BATCH rows (y)
    float* top_w   = s5 + (size_t)2*BATCH*H;
    int*   top_idx = (int*)(top_w + (size_t)NF*2);
    int*   pair_tok= top_idx + (size_t)NF*2;
    int*   tok_pair= pair_tok + (size_t)NF*2;
    int*   counts  = tok_pair + (size_t)NF*2;
    int*   offsets = counts + NEXP;
    int*   cursor  = offsets + NEXP;

    dim3 blk(256);
    dim3 gfull((NF+63)/64, H/64);
    dim3 gsmall((BATCH+63)/64, H/64);
    dim3 mfull((NF+63)/64, H/64, NEXP);
    dim3 msmall((BATCH+63)/64, H/64, NEXP);

    embed_kernel<<<NF, blk, 0, stream>>>(log_seqs, item_emb, pos_emb, buf0);

    // ================= block 0 : full sequence =================
    {
        const int i = 0;
        const float* Wq = inproj_w + (size_t)i*3*H*H;
        const float* Wk = Wq + (size_t)H*H;
        const float* Wv = Wk + (size_t)H*H;
        const float* bq = inproj_b + (size_t)i*3*H;
        ln_kernel<<<NF, blk, 0, stream>>>(buf0, nullptr, buf1, ln1_w + i*H, ln1_b + i*H, 1e-8f, 0, 1);
        gemm_nt<<<gfull, blk, 0, stream>>>(buf1, Wq, bq,       buf2, NF);   // q
        gemm_nt<<<gfull, blk, 0, stream>>>(buf0, Wk, bq + H,   buf3, NF);   // k
        gemm_nt<<<gfull, blk, 0, stream>>>(buf0, Wv, bq + 2*H, buf4, NF);   // v
        attn_kernel<<<dim3(BATCH, NHEAD, 2), blk, 0, stream>>>(buf2, buf3, buf4, buf2, SEQL); // ctx in-place
        gemm_nt<<<gfull, blk, 0, stream>>>(buf2, outproj_w + (size_t)i*H*H, outproj_b + i*H, buf3, NF);
        ln_kernel<<<NF, blk, 0, stream>>>(buf1, buf3, buf0, ln2_w + i*H, ln2_b + i*H, 1e-8f, 0, 1);
        zero_kernel<<<1, 32, 0, stream>>>((float*)counts, NEXP);
        gate_kernel<<<NF, blk, 0, stream>>>(buf0, gate_w + (size_t)i*NEXP*H, gate_b + i*NEXP,
                                            top_idx, top_w, NF);
        count_kernel<<<(NF+255)/256, blk, 0, stream>>>(top_idx, counts, NF);
        scan_kernel<<<1, 1, 0, stream>>>(counts, offsets, cursor);
        scatter_kernel<<<(NF+255)/256, blk, 0, stream>>>(top_idx, cursor, pair_tok, tok_pair, NF);
        moe_gemm1<<<mfull, blk, 0, stream>>>(buf0, e_w1 + (size_t)i*NEXP*H*H, e_b1 + (size_t)i*NEXP*H,
                                             pair_tok, offsets, counts, buf3);
        moe_gemm2<<<mfull, blk, 0, stream>>>(buf3, e_w2 + (size_t)i*NEXP*H*H, e_b2 + (size_t)i*NEXP*H,
                                             offsets, counts, buf1);
        moe_ln_kernel<<<NF, blk, 0, stream>>>(buf0, buf1, tok_pair, top_w, buf3,
                                              moeln_w + i*H, moeln_b + i*H, 1e-5f);
    }

    // ================= block 1 : only last position matters downstream =================
    {
        const int i = 1;
        const float* Wq = inproj_w + (size_t)i*3*H*H;
        const float* Wk = Wq + (size_t)H*H;
        const float* Wv = Wk + (size_t)H*H;
        const float* bq = inproj_b + (size_t)i*3*H;
        float* X = buf3;
        ln_kernel<<<BATCH, blk, 0, stream>>>(X, nullptr, s0, ln1_w + i*H, ln1_b + i*H, 1e-8f, SEQL-1, SEQL);
        gemm_nt<<<gsmall, blk, 0, stream>>>(s0, Wq, bq, s1, BATCH);          // q (last rows only)
        gemm_nt<<<gfull, blk, 0, stream>>>(X, Wk, bq + H,   buf0, NF);       // k (full)
        gemm_nt<<<gfull, blk, 0, stream>>>(X, Wv, bq + 2*H, buf1, NF);       // v (full)
        attn_kernel<<<dim3(BATCH, NHEAD, 1), blk, 0, stream>>>(s1, buf0, buf1, s2, 1);
        gemm_nt<<<gsmall, blk, 0, stream>>>(s2, outproj_w + (size_t)i*H*H, outproj_b + i*H, s3, BATCH);
        ln_kernel<<<BATCH, blk, 0, stream>>>(s0, s3, s2, ln2_w + i*H, ln2_b + i*H, 1e-8f, 0, 1);
        zero_kernel<<<1, 32, 0, stream>>>((float*)counts, NEXP);
        gate_kernel<<<BATCH, blk, 0, stream>>>(s2, gate_w + (size_t)i*NEXP*H, gate_b + i*NEXP,
                                               top_idx, top_w, BATCH);
        count_kernel<<<1, blk, 0, stream>>>(top_idx, counts, BATCH);
        scan_kernel<<<1, 1, 0, stream>>>(counts, offsets, cursor);
        scatter_kernel<<<1, blk, 0, stream>>>(top_idx, cursor, pair_tok, tok_pair, BATCH);
        moe_gemm1<<<msmall, blk, 0, stream>>>(s2, e_w1 + (size_t)i*NEXP*H*H, e_b1 + (size_t)i*NEXP*H,
                                              pair_tok, offsets, counts, s4);
        moe_gemm2<<<msmall, blk, 0, stream>>>(s4, e_w2 + (size_t)i*NEXP*H*H, e_b2 + (size_t)i*NEXP*H,
                                              offsets, counts, s5);
        moe_ln_kernel<<<BATCH, blk, 0, stream>>>(s2, s5, tok_pair, top_w, s6,
                                                 moeln_w + i*H, moeln_b + i*H, 1e-5f);
    }

    final_kernel<<<BATCH, blk, 0, stream>>>(s6, lastln_w, lastln_b, user_emb, item_emb,
                                            user_ids, item_ids, (float*)d_out);
}

// Round 6
// 1093.861 us; speedup vs baseline: 1.7448x; 1.0214x over previous
//
#include <hip/hip_runtime.h>
#include <math.h>

#define H 256
#define NHEAD 4
#define HD 64
#define NEXP 8
#define SEQL 200
#define BATCH 128
#define NF (BATCH*SEQL)
#define KT 64
#define QT 64
#define NQW 16

// ---------------- helpers ----------------
__device__ __forceinline__ float blk_sum256(float v, float* s4) {
    #pragma unroll
    for (int o = 32; o > 0; o >>= 1) v += __shfl_xor(v, o, 64);
    __syncthreads();
    if ((threadIdx.x & 63) == 0) s4[threadIdx.x >> 6] = v;
    __syncthreads();
    return s4[0] + s4[1] + s4[2] + s4[3];
}

// ---------------- embedding ----------------
__global__ __launch_bounds__(256) void embed_kernel(
    const int* __restrict__ seqs, const float* __restrict__ item_emb,
    const float* __restrict__ pos_emb, float* __restrict__ x)
{
    int n = blockIdx.x, t = threadIdx.x;
    int id = seqs[n];
    int pos = (id != 0) ? (n % SEQL) + 1 : 0;
    x[(size_t)n*H + t] = item_emb[(size_t)id*H + t] * 16.0f + pos_emb[(size_t)pos*H + t];
}

// ---------------- layernorm (gather + optional residual) ----------------
__global__ __launch_bounds__(256) void ln_kernel(
    const float* __restrict__ in, const float* __restrict__ res,
    float* __restrict__ out, const float* __restrict__ w, const float* __restrict__ b,
    float eps, int base, int step)
{
    __shared__ float s4[4];
    int r = blockIdx.x, t = threadIdx.x;
    float v = in[(size_t)(base + r*step)*H + t];
    if (res) v += res[(size_t)r*H + t];
    float mean = blk_sum256(v, s4) * (1.f/H);
    float d = v - mean;
    float var = blk_sum256(d*d, s4) * (1.f/H);
    out[(size_t)r*H + t] = d * rsqrtf(var + eps) * w[t] + b[t];
}

// ---------------- fused moe combine + layernorm ----------------
__global__ __launch_bounds__(256) void moe_ln_kernel(
    const float* __restrict__ x, const float* __restrict__ ybuf,
    const int* __restrict__ tok_pair, const float* __restrict__ top_w,
    float* __restrict__ out, const float* __restrict__ w, const float* __restrict__ b,
    float eps)
{
    __shared__ float s4[4];
    int r = blockIdx.x, t = threadIdx.x;
    int p0 = tok_pair[r*2], p1 = tok_pair[r*2+1];
    float v = x[(size_t)r*H + t]
            + top_w[r*2+0] * ybuf[(size_t)p0*H + t]
            + top_w[r*2+1] * ybuf[(size_t)p1*H + t];
    float mean = blk_sum256(v, s4) * (1.f/H);
    float d = v - mean;
    float var = blk_sum256(d*d, s4) * (1.f/H);
    out[(size_t)r*H + t] = d * rsqrtf(var + eps) * w[t] + b[t];
}

// ---------------- GEMM: out[r][o] = sum_h A[r][h]*W[o][h] + bias[o] ----------------
__global__ __launch_bounds__(256) void gemm_nt(
    const float* __restrict__ A, const float* __restrict__ W,
    const float* __restrict__ bias, float* __restrict__ out, int nrows)
{
    __shared__ float As[16][68];
    __shared__ float Ws[16][68];
    int r0 = blockIdx.x * 64;
    if (r0 >= nrows) return;
    int c0 = blockIdx.y * 64;
    int tid = threadIdx.x;
    int tx = tid & 15, ty = tid >> 4;
    int lrow = tid >> 2, lkg = (tid & 3) << 2;
    float acc[4][4] = {};
    for (int kk = 0; kk < H; kk += 16) {
        float4 av = make_float4(0.f,0.f,0.f,0.f);
        int gr = r0 + lrow;
        if (gr < nrows) av = *(const float4*)(A + (size_t)gr*H + kk + lkg);
        As[lkg+0][lrow]=av.x; As[lkg+1][lrow]=av.y; As[lkg+2][lrow]=av.z; As[lkg+3][lrow]=av.w;
        float4 wv = *(const float4*)(W + (size_t)(c0+lrow)*H + kk + lkg);
        Ws[lkg+0][lrow]=wv.x; Ws[lkg+1][lrow]=wv.y; Ws[lkg+2][lrow]=wv.z; Ws[lkg+3][lrow]=wv.w;
        __syncthreads();
        #pragma unroll
        for (int k = 0; k < 16; ++k) {
            float4 a = *(const float4*)&As[k][ty<<2];
            float4 bv = *(const float4*)&Ws[k][tx<<2];
            float aa[4] = {a.x,a.y,a.z,a.w};
            float bb[4] = {bv.x,bv.y,bv.z,bv.w};
            #pragma unroll
            for (int ii = 0; ii < 4; ++ii)
                #pragma unroll
                for (int jj = 0; jj < 4; ++jj)
                    acc[ii][jj] += aa[ii] * bb[jj];
        }
        __syncthreads();
    }
    #pragma unroll
    for (int ii = 0; ii < 4; ++ii) {
        int gr = r0 + (ty<<2) + ii;
        if (gr < nrows) {
            #pragma unroll
            for (int jj = 0; jj < 4; ++jj) {
                int gc = c0 + (tx<<2) + jj;
                out[(size_t)gr*H + gc] = acc[ii][jj] + bias[gc];
            }
        }
    }
}

// ---------------- flash attention, fp32, q-tile per block ----------------
// grid (B, NH, ceil(nq/QT)); 4 waves x 16 queries; K/V staged once per k-tile.
__global__ __launch_bounds__(256) void attn_kernel(
    const float* __restrict__ qbuf, const float* __restrict__ kbuf,
    const float* __restrict__ vbuf, float* __restrict__ ctx, int nq)
{
    __shared__ float Ks[KT][HD+4];
    __shared__ float VsT[HD][KT+4];
    __shared__ float ps[QT][KT+4];
    int b = blockIdx.x, h = blockIdx.y, z = blockIdx.z;
    int qbase = z * QT;
    int nqt = nq - qbase;
    if (nqt <= 0) return;
    if (nqt > QT) nqt = QT;
    int tid = threadIdx.x, w = tid >> 6, lane = tid & 63;
    int off = SEQL - nq;
    const float* qrow0 = qbuf + (size_t)(b*nq + qbase)*H + h*HD;
    float m[NQW], l[NQW], acc[NQW];
    #pragma unroll
    for (int i = 0; i < NQW; ++i) { m[i] = -3e30f; l[i] = 0.f; acc[i] = 0.f; }
    int wq0 = w * NQW;
    int wqn = nqt - wq0; if (wqn > NQW) wqn = NQW;   // may be <= 0 (idle wave)
    int wmaxpos = qbase + wq0 + (wqn > 0 ? wqn - 1 : 0) + off;
    int ntiles = (qbase + nqt - 1 + off) / KT + 1;
    for (int t = 0; t < ntiles; ++t) {
        int kbase = t * KT;
        __syncthreads();
        // stage K row-major (coalesced; b128 LDS writes, 16B-aligned rows)
        for (int i = tid; i < KT*(HD/4); i += 256) {
            int row = i >> 4, c4 = (i & 15) << 2;
            int key = kbase + row;
            float4 kv = make_float4(0.f,0.f,0.f,0.f);
            if (key < SEQL) kv = *(const float4*)(kbuf + (size_t)(b*SEQL + key)*H + h*HD + c4);
            *(float4*)&Ks[row][c4] = kv;
        }
        // stage V transposed (lane-major: conflict-free scattered b32 writes)
        {
            int key = kbase + lane;
            bool kval = key < SEQL;
            const float* vp = vbuf + (size_t)(b*SEQL + (kval ? key : 0))*H + h*HD;
            #pragma unroll
            for (int it = 0; it < 4; ++it) {
                int c4 = ((it << 2) + w) << 2;
                float4 vv = make_float4(0.f,0.f,0.f,0.f);
                if (kval) vv = *(const float4*)(vp + c4);
                VsT[c4+0][lane] = vv.x; VsT[c4+1][lane] = vv.y;
                VsT[c4+2][lane] = vv.z; VsT[c4+3][lane] = vv.w;
            }
        }
        __syncthreads();
        if (wqn > 0 && kbase <= wmaxpos) {
            // ---- scores: lane = key; Ks read amortized over 16 queries ----
            float s[NQW];
            #pragma unroll
            for (int qi = 0; qi < NQW; ++qi) s[qi] = 0.f;
            for (int d4 = 0; d4 < HD; d4 += 4) {
                float4 k4 = *(const float4*)&Ks[lane][d4];
                #pragma unroll
                for (int qi = 0; qi < NQW; ++qi) {
                    if (qi < wqn) {
                        float4 q4 = *(const float4*)(qrow0 + (size_t)(wq0+qi)*H + d4);
                        s[qi] += k4.x*q4.x + k4.y*q4.y + k4.z*q4.z + k4.w*q4.w;
                    }
                }
            }
            // ---- online softmax per query (state in registers) ----
            #pragma unroll
            for (int qi = 0; qi < NQW; ++qi) {
                if (qi < wqn) {
                    int qpos = qbase + wq0 + qi + off;
                    bool valid = (kbase + lane) <= qpos;
                    float sc = s[qi] * 0.125f;
                    float sv = valid ? sc : -3e30f;
                    float tm = sv;
                    #pragma unroll
                    for (int o = 32; o > 0; o >>= 1) tm = fmaxf(tm, __shfl_xor(tm, o, 64));
                    float mn = fmaxf(m[qi], tm);
                    float p = valid ? expf(sc - mn) : 0.f;
                    float psum = p;
                    #pragma unroll
                    for (int o = 32; o > 0; o >>= 1) psum += __shfl_xor(psum, o, 64);
                    float scl = expf(m[qi] - mn);
                    l[qi] = l[qi]*scl + psum;
                    acc[qi] *= scl;
                    m[qi] = mn;
                    ps[wq0+qi][lane] = p;
                }
            }
            // ---- PV: lane = dim; VsT read amortized over 16 queries ----
            for (int k4 = 0; k4 < KT; k4 += 4) {
                float4 v4 = *(const float4*)&VsT[lane][k4];
                #pragma unroll
                for (int qi = 0; qi < NQW; ++qi) {
                    if (qi < wqn) {
                        float4 p4 = *(const float4*)&ps[wq0+qi][k4];
                        acc[qi] += p4.x*v4.x + p4.y*v4.y + p4.z*v4.z + p4.w*v4.w;
                    }
                }
            }
        }
    }
    #pragma unroll
    for (int qi = 0; qi < NQW; ++qi) {
        if (qi < wqn) {
            int qrow = wq0 + qi;
            ctx[(size_t)(b*nq + qbase + qrow)*H + h*HD + lane] = acc[qi] / l[qi];
        }
    }
}

// ---------------- gate: logits + top-2 (no global atomics) ----------------
__global__ __launch_bounds__(256) void gate_kernel(
    const float* __restrict__ X, const float* __restrict__ gw, const float* __restrict__ gb,
    int* __restrict__ top_idx, float* __restrict__ top_w, int nrows)
{
    __shared__ float gl[NEXP];
    int n = blockIdx.x;
    int tid = threadIdx.x;
    int wv = tid >> 6, lane = tid & 63;
    float xv[4];
    #pragma unroll
    for (int c = 0; c < 4; ++c) xv[c] = X[(size_t)n*H + lane + (c<<6)];
    #pragma unroll
    for (int s = 0; s < 2; ++s) {
        int e = wv*2 + s;
        float acc = 0.f;
        #pragma unroll
        for (int c = 0; c < 4; ++c) acc += xv[c] * gw[(size_t)e*H + lane + (c<<6)];
        #pragma unroll
        for (int o = 32; o > 0; o >>= 1) acc += __shfl_xor(acc, o, 64);
        if (lane == 0) gl[e] = acc + gb[e];
    }
    __syncthreads();
    if (tid == 0) {
        int i0 = 0;
        for (int e = 1; e < NEXP; ++e) if (gl[e] > gl[i0]) i0 = e;
        int i1 = -1;
        for (int e = 0; e < NEXP; ++e) { if (e == i0) continue; if (i1 < 0 || gl[e] > gl[i1]) i1 = e; }
        float e1 = expf(gl[i1] - gl[i0]);
        float w0 = 1.f / (1.f + e1);
        top_idx[n*2+0] = i0; top_idx[n*2+1] = i1;
        top_w[n*2+0] = w0;  top_w[n*2+1] = 1.f - w0;
    }
}

// ---------------- count: LDS histogram ----------------
__global__ __launch_bounds__(256) void count_kernel(
    const int* __restrict__ top_idx, int* __restrict__ counts, int nrows)
{
    __shared__ int hist[NEXP];
    int tid = threadIdx.x;
    if (tid < NEXP) hist[tid] = 0;
    __syncthreads();
    int n = blockIdx.x * 256 + tid;
    if (n < nrows) {
        atomicAdd(&hist[top_idx[n*2+0]], 1);
        atomicAdd(&hist[top_idx[n*2+1]], 1);
    }
    __syncthreads();
    if (tid < NEXP && hist[tid] > 0) atomicAdd(&counts[tid], hist[tid]);
}

__global__ void scan_kernel(const int* __restrict__ counts, int* __restrict__ offsets,
                            int* __restrict__ cursor)
{
    int s = 0;
    for (int e = 0; e < NEXP; ++e) { offsets[e] = s; cursor[e] = s; s += counts[e]; }
}

// ---------------- block-aggregated scatter (+ inverse map tok_pair) ----------------
__global__ __launch_bounds__(256) void scatter_kernel(
    const int* __restrict__ top_idx,
    int* __restrict__ cursor, int* __restrict__ pair_tok, int* __restrict__ tok_pair, int nrows)
{
    __shared__ int lcnt[NEXP];
    __shared__ int lbase[NEXP];
    int tid = threadIdx.x;
    if (tid < NEXP) lcnt[tid] = 0;
    __syncthreads();
    int n = blockIdx.x * 256 + tid;
    int e0 = 0, e1 = 0, p0 = 0, p1 = 0;
    bool act = n < nrows;
    if (act) {
        e0 = top_idx[n*2+0]; e1 = top_idx[n*2+1];
        p0 = atomicAdd(&lcnt[e0], 1);
        p1 = atomicAdd(&lcnt[e1], 1);
    }
    __syncthreads();
    if (tid < NEXP) lbase[tid] = (lcnt[tid] > 0) ? atomicAdd(&cursor[tid], lcnt[tid]) : 0;
    __syncthreads();
    if (act) {
        int q0 = lbase[e0] + p0, q1 = lbase[e1] + p1;
        pair_tok[q0] = n; pair_tok[q1] = n;
        tok_pair[n*2+0] = q0; tok_pair[n*2+1] = q1;
    }
}

// ---------------- grouped MoE GEMM 1: h = relu(X[tok] @ W1[e] + b1[e]) ----------------
__global__ __launch_bounds__(256) void moe_gemm1(
    const float* __restrict__ X, const float* __restrict__ W1base,
    const float* __restrict__ b1base, const int* __restrict__ pair_tok,
    const int* __restrict__ offsets, const int* __restrict__ counts,
    float* __restrict__ hbuf)
{
    int e = blockIdx.z;
    int cnt = counts[e];
    int r0 = blockIdx.x * 64;
    if (r0 >= cnt) return;
    int off = offsets[e];
    int c0 = blockIdx.y * 64;
    const float* W = W1base + (size_t)e * H * H;
    const float* bias = b1base + (size_t)e * H;
    __shared__ float As[16][68];
    __shared__ float Bs[16][68];
    int tid = threadIdx.x, tx = tid & 15, ty = tid >> 4;
    int lrow = tid >> 2, lkg = (tid & 3) << 2;
    float acc[4][4] = {};
    for (int kk = 0; kk < H; kk += 16) {
        float4 av = make_float4(0.f,0.f,0.f,0.f);
        int pr = r0 + lrow;
        if (pr < cnt) {
            int tok = pair_tok[off + pr];
            av = *(const float4*)(X + (size_t)tok*H + kk + lkg);
        }
        As[lkg+0][lrow]=av.x; As[lkg+1][lrow]=av.y; As[lkg+2][lrow]=av.z; As[lkg+3][lrow]=av.w;
        float4 wv = *(const float4*)(W + (size_t)(kk+ty)*H + c0 + (tx<<2));
        *(float4*)&Bs[ty][tx<<2] = wv;
        __syncthreads();
        #pragma unroll
        for (int k = 0; k < 16; ++k) {
            float4 a = *(const float4*)&As[k][ty<<2];
            float4 bv = *(const float4*)&Bs[k][tx<<2];
            float aa[4] = {a.x,a.y,a.z,a.w};
            float bb[4] = {bv.x,bv.y,bv.z,bv.w};
            #pragma unroll
            for (int ii = 0; ii < 4; ++ii)
                #pragma unroll
                for (int jj = 0; jj < 4; ++jj)
                    acc[ii][jj] += aa[ii] * bb[jj];
        }
        __syncthreads();
    }
    #pragma unroll
    for (int ii = 0; ii < 4; ++ii) {
        int pr = r0 + (ty<<2) + ii;
        if (pr < cnt) {
            #pragma unroll
            for (int jj = 0; jj < 4; ++jj) {
                int gc = c0 + (tx<<2) + jj;
                hbuf[(size_t)(off+pr)*H + gc] = fmaxf(acc[ii][jj] + bias[gc], 0.f);
            }
        }
    }
}

// ---------------- grouped MoE GEMM 2: y[pair] = h @ W2[e] + b2[e]  (no atomics) ---------
__global__ __launch_bounds__(256) void moe_gemm2(
    const float* __restrict__ Hbuf, const float* __restrict__ W2base,
    const float* __restrict__ b2base, const int* __restrict__ offsets,
    const int* __restrict__ counts, float* __restrict__ ybuf)
{
    int e = blockIdx.z;
    int cnt = counts[e];
    int r0 = blockIdx.x * 64;
    if (r0 >= cnt) return;
    int off = offsets[e];
    int c0 = blockIdx.y * 64;
    const float* W = W2base + (size_t)e * H * H;
    const float* bias = b2base + (size_t)e * H;
    __shared__ float As[16][68];
    __shared__ float Bs[16][68];
    int tid = threadIdx.x, tx = tid & 15, ty = tid >> 4;
    int lrow = tid >> 2, lkg = (tid & 3) << 2;
    float acc[4][4] = {};
    for (int kk = 0; kk < H; kk += 16) {
        float4 av = make_float4(0.f,0.f,0.f,0.f);
        int pr = r0 + lrow;
        if (pr < cnt) av = *(const float4*)(Hbuf + (size_t)(off+pr)*H + kk + lkg);
        As[lkg+0][lrow]=av.x; As[lkg+1][lrow]=av.y; As[lkg+2][lrow]=av.z; As[lkg+3][lrow]=av.w;
        float4 wv = *(const float4*)(W + (size_t)(kk+ty)*H + c0 + (tx<<2));
        *(float4*)&Bs[ty][tx<<2] = wv;
        __syncthreads();
        #pragma unroll
        for (int k = 0; k < 16; ++k) {
            float4 a = *(const float4*)&As[k][ty<<2];
            float4 bv = *(const float4*)&Bs[k][tx<<2];
            float aa[4] = {a.x,a.y,a.z,a.w};
            float bb[4] = {bv.x,bv.y,bv.z,bv.w};
            #pragma unroll
            for (int ii = 0; ii < 4; ++ii)
                #pragma unroll
                for (int jj = 0; jj < 4; ++jj)
                    acc[ii][jj] += aa[ii] * bb[jj];
        }
        __syncthreads();
    }
    #pragma unroll
    for (int ii = 0; ii < 4; ++ii) {
        int pr = r0 + (ty<<2) + ii;
        if (pr < cnt) {
            #pragma unroll
            for (int jj = 0; jj < 4; ++jj) {
                int gc = c0 + (tx<<2) + jj;
                ybuf[(size_t)(off+pr)*H + gc] = acc[ii][jj] + bias[gc];
            }
        }
    }
}

__global__ void zero_kernel(float* __restrict__ p, int n) {
    int i = blockIdx.x * 256 + threadIdx.x;
    if (i < n) p[i] = 0.f;
}

// ---------------- final: LN + user emb + dot(item emb) ----------------
__global__ __launch_bounds__(256) void final_kernel(
    const float* __restrict__ xf, const float* __restrict__ lnw, const float* __restrict__ lnb,
    const float* __restrict__ user_emb, const float* __restrict__ item_emb,
    const int* __restrict__ user_ids, const int* __restrict__ item_ids, float* __restrict__ out)
{
    __shared__ float s4[4];
    int bb = blockIdx.x, t = threadIdx.x;
    float v = xf[(size_t)bb*H + t];
    float mean = blk_sum256(v, s4) * (1.f/H);
    float d = v - mean;
    float var = blk_sum256(d*d, s4) * (1.f/H);
    float lnv = d * rsqrtf(var + 1e-8f) * lnw[t] + lnb[t];
    float fin = lnv + user_emb[(size_t)user_ids[bb]*H + t];
    float prod = fin * item_emb[(size_t)item_ids[bb]*H + t];
    float tot = blk_sum256(prod, s4);
    if (t == 0) out[bb] = tot;
}

// ---------------- launch ----------------
extern "C" void kernel_launch(void* const* d_in, const int* in_sizes, int n_in,
                              void* d_out, int out_size, void* d_ws, size_t ws_size,
                              hipStream_t stream)
{
    (void)in_sizes; (void)n_in; (void)out_size; (void)ws_size;
    const int*   user_ids  = (const int*)d_in[0];
    const int*   log_seqs  = (const int*)d_in[1];
    const int*   item_ids  = (const int*)d_in[2];
    const float* item_emb  = (const float*)d_in[3];
    const float* pos_emb   = (const float*)d_in[4];
    const float* user_emb  = (const float*)d_in[5];
    const float* ln1_w     = (const float*)d_in[6];
    const float* ln1_b     = (const float*)d_in[7];
    const float* inproj_w  = (const float*)d_in[8];
    const float* inproj_b  = (const float*)d_in[9];
    const float* outproj_w = (const float*)d_in[10];
    const float* outproj_b = (const float*)d_in[11];
    const float* ln2_w     = (const float*)d_in[12];
    const float* ln2_b     = (const float*)d_in[13];
    const float* gate_w    = (const float*)d_in[14];
    const float* gate_b    = (const float*)d_in[15];
    const float* e_w1      = (const float*)d_in[16];
    const float* e_b1      = (const float*)d_in[17];
    const float* e_w2      = (const float*)d_in[18];
    const float* e_b2      = (const float*)d_in[19];
    const float* moeln_w   = (const float*)d_in[20];
    const float* moeln_b   = (const float*)d_in[21];
    const float* lastln_w  = (const float*)d_in[22];
    const float* lastln_b  = (const float*)d_in[23];

    float* ws = (float*)d_ws;
    const size_t NFH = (size_t)NF * H;
    float* buf0 = ws;
    float* buf1 = buf0 + NFH;   // buf1+buf2 contiguous -> ybuf region (2*NF rows)
    float* buf2 = buf1 + NFH;
    float* buf3 = buf2 + NFH;   // buf3+buf4 contiguous -> MoE h region (2*NF rows)
    float* buf4 = buf3 + NFH;
    float* s0   = buf4 + NFH;
    float* s1   = s0 + (size_t)BATCH*H;
    float* s2   = s1 + (size_t)BATCH*H;
    float* s3   = s2 + (size_t)BATCH*H;
    float* s6   = s3 + (size_t)BATCH*H;
    float* s4   = s6 + (size_t)BATCH*H;            // 2*BATCH rows (h)
    float* s5   = s4 + (size_t)2*BATCH*H;          // 2*BATCH rows (y)
    float* top_w   = s5 + (size_t)2*BATCH*H;
    int*   top_idx = (int*)(top_w + (size_t)NF*2);
    int*   pair_tok= top_idx + (size_t)NF*2;
    int*   tok_pair= pair_tok + (size_t)NF*2;
    int*   counts  = tok_pair + (size_t)NF*2;
    int*   offsets = counts + NEXP;
    int*   cursor  = offsets + NEXP;

    dim3 blk(256);
    dim3 gfull((NF+63)/64, H/64);
    dim3 gsmall((BATCH+63)/64, H/64);
    dim3 mfull((NF+63)/64, H/64, NEXP);
    dim3 msmall((BATCH+63)/64, H/64, NEXP);

    embed_kernel<<<NF, blk, 0, stream>>>(log_seqs, item_emb, pos_emb, buf0);

    // ================= block 0 : full sequence =================
    {
        const int i = 0;
        const float* Wq = inproj_w + (size_t)i*3*H*H;
        const float* Wk = Wq + (size_t)H*H;
        const float* Wv = Wk + (size_t)H*H;
        const float* bq = inproj_b + (size_t)i*3*H;
        ln_kernel<<<NF, blk, 0, stream>>>(buf0, nullptr, buf1, ln1_w + i*H, ln1_b + i*H, 1e-8f, 0, 1);
        gemm_nt<<<gfull, blk, 0, stream>>>(buf1, Wq, bq,       buf2, NF);   // q
        gemm_nt<<<gfull, blk, 0, stream>>>(buf0, Wk, bq + H,   buf3, NF);   // k
        gemm_nt<<<gfull, blk, 0, stream>>>(buf0, Wv, bq + 2*H, buf4, NF);   // v
        attn_kernel<<<dim3(BATCH, NHEAD, (SEQL+QT-1)/QT), blk, 0, stream>>>(buf2, buf3, buf4, buf2, SEQL);
        gemm_nt<<<gfull, blk, 0, stream>>>(buf2, outproj_w + (size_t)i*H*H, outproj_b + i*H, buf3, NF);
        ln_kernel<<<NF, blk, 0, stream>>>(buf1, buf3, buf0, ln2_w + i*H, ln2_b + i*H, 1e-8f, 0, 1);
        zero_kernel<<<1, 32, 0, stream>>>((float*)counts, NEXP);
        gate_kernel<<<NF, blk, 0, stream>>>(buf0, gate_w + (size_t)i*NEXP*H, gate_b + i*NEXP,
                                            top_idx, top_w, NF);
        count_kernel<<<(NF+255)/256, blk, 0, stream>>>(top_idx, counts, NF);
        scan_kernel<<<1, 1, 0, stream>>>(counts, offsets, cursor);
        scatter_kernel<<<(NF+255)/256, blk, 0, stream>>>(top_idx, cursor, pair_tok, tok_pair, NF);
        moe_gemm1<<<mfull, blk, 0, stream>>>(buf0, e_w1 + (size_t)i*NEXP*H*H, e_b1 + (size_t)i*NEXP*H,
                                             pair_tok, offsets, counts, buf3);
        moe_gemm2<<<mfull, blk, 0, stream>>>(buf3, e_w2 + (size_t)i*NEXP*H*H, e_b2 + (size_t)i*NEXP*H,
                                             offsets, counts, buf1);
        moe_ln_kernel<<<NF, blk, 0, stream>>>(buf0, buf1, tok_pair, top_w, buf3,
                                              moeln_w + i*H, moeln_b + i*H, 1e-5f);
    }

    // ================= block 1 : only last position matters downstream =================
    {
        const int i = 1;
        const float* Wq = inproj_w + (size_t)i*3*H*H;
        const float* Wk = Wq + (size_t)H*H;
        const float* Wv = Wk + (size_t)H*H;
        const float* bq = inproj_b + (size_t)i*3*H;
        float* X = buf3;
        ln_kernel<<<BATCH, blk, 0, stream>>>(X, nullptr, s0, ln1_w + i*H, ln1_b + i*H, 1e-8f, SEQL-1, SEQL);
        gemm_nt<<<gsmall, blk, 0, stream>>>(s0, Wq, bq, s1, BATCH);          // q (last rows only)
        gemm_nt<<<gfull, blk, 0, stream>>>(X, Wk, bq + H,   buf0, NF);       // k (full)
        gemm_nt<<<gfull, blk, 0, stream>>>(X, Wv, bq + 2*H, buf1, NF);       // v (full)
        attn_kernel<<<dim3(BATCH, NHEAD, 1), blk, 0, stream>>>(s1, buf0, buf1, s2, 1);
        gemm_nt<<<gsmall, blk, 0, stream>>>(s2, outproj_w + (size_t)i*H*H, outproj_b + i*H, s3, BATCH);
        ln_kernel<<<BATCH, blk, 0, stream>>>(s0, s3, s2, ln2_w + i*H, ln2_b + i*H, 1e-8f, 0, 1);
        zero_kernel<<<1, 32, 0, stream>>>((float*)counts, NEXP);
        gate_kernel<<<BATCH, blk, 0, stream>>>(s2, gate_w + (size_t)i*NEXP*H, gate_b + i*NEXP,
                                               top_idx, top_w, BATCH);
        count_kernel<<<1, blk, 0, stream>>>(top_idx, counts, BATCH);
        scan_kernel<<<1, 1, 0, stream>>>(counts, offsets, cursor);
        scatter_kernel<<<1, blk, 0, stream>>>(top_idx, cursor, pair_tok, tok_pair, BATCH);
        moe_gemm1<<<msmall, blk, 0, stream>>>(s2, e_w1 + (size_t)i*NEXP*H*H, e_b1 + (size_t)i*NEXP*H,
                                              pair_tok, offsets, counts, s4);
        moe_gemm2<<<msmall, blk, 0, stream>>>(s4, e_w2 + (size_t)i*NEXP*H*H, e_b2 + (size_t)i*NEXP*H,
                                              offsets, counts, s5);
        moe_ln_kernel<<<BATCH, blk, 0, stream>>>(s2, s5, tok_pair, top_w, s6,
                                                 moeln_w + i*H, moeln_b + i*H, 1e-5f);
    }

    final_kernel<<<BATCH, blk, 0, stream>>>(s6, lastln_w, lastln_b, user_emb, item_emb,
                                            user_ids, item_ids, (float*)d_out);
}

// Round 7
// 928.186 us; speedup vs baseline: 2.0563x; 1.1785x over previous
//
#include <hip/hip_runtime.h>
#include <math.h>

#define H 256
#define NHEAD 4
#define HD 64
#define NEXP 8
#define SEQL 200
#define BATCH 128
#define NF (BATCH*SEQL)
#define KT 64
#define QT 32
#define QW 8   // queries per wave

// ---------------- helpers ----------------
__device__ __forceinline__ float blk_sum256(float v, float* s4) {
    #pragma unroll
    for (int o = 32; o > 0; o >>= 1) v += __shfl_xor(v, o, 64);
    __syncthreads();
    if ((threadIdx.x & 63) == 0) s4[threadIdx.x >> 6] = v;
    __syncthreads();
    return s4[0] + s4[1] + s4[2] + s4[3];
}

// ---------------- embedding ----------------
__global__ __launch_bounds__(256) void embed_kernel(
    const int* __restrict__ seqs, const float* __restrict__ item_emb,
    const float* __restrict__ pos_emb, float* __restrict__ x)
{
    int n = blockIdx.x, t = threadIdx.x;
    int id = seqs[n];
    int pos = (id != 0) ? (n % SEQL) + 1 : 0;
    x[(size_t)n*H + t] = item_emb[(size_t)id*H + t] * 16.0f + pos_emb[(size_t)pos*H + t];
}

// ---------------- layernorm (gather + optional residual) ----------------
__global__ __launch_bounds__(256) void ln_kernel(
    const float* __restrict__ in, const float* __restrict__ res,
    float* __restrict__ out, const float* __restrict__ w, const float* __restrict__ b,
    float eps, int base, int step)
{
    __shared__ float s4[4];
    int r = blockIdx.x, t = threadIdx.x;
    float v = in[(size_t)(base + r*step)*H + t];
    if (res) v += res[(size_t)r*H + t];
    float mean = blk_sum256(v, s4) * (1.f/H);
    float d = v - mean;
    float var = blk_sum256(d*d, s4) * (1.f/H);
    out[(size_t)r*H + t] = d * rsqrtf(var + eps) * w[t] + b[t];
}

// ---------------- fused moe combine + layernorm ----------------
__global__ __launch_bounds__(256) void moe_ln_kernel(
    const float* __restrict__ x, const float* __restrict__ ybuf,
    const int* __restrict__ tok_pair, const float* __restrict__ top_w,
    float* __restrict__ out, const float* __restrict__ w, const float* __restrict__ b,
    float eps)
{
    __shared__ float s4[4];
    int r = blockIdx.x, t = threadIdx.x;
    int p0 = tok_pair[r*2], p1 = tok_pair[r*2+1];
    float v = x[(size_t)r*H + t]
            + top_w[r*2+0] * ybuf[(size_t)p0*H + t]
            + top_w[r*2+1] * ybuf[(size_t)p1*H + t];
    float mean = blk_sum256(v, s4) * (1.f/H);
    float d = v - mean;
    float var = blk_sum256(d*d, s4) * (1.f/H);
    out[(size_t)r*H + t] = d * rsqrtf(var + eps) * w[t] + b[t];
}

// ---------------- GEMM: out[r][o] = sum_h A[r][h]*W[o][h] + bias[o] ----------------
__global__ __launch_bounds__(256) void gemm_nt(
    const float* __restrict__ A, const float* __restrict__ W,
    const float* __restrict__ bias, float* __restrict__ out, int nrows)
{
    __shared__ float As[16][68];
    __shared__ float Ws[16][68];
    int r0 = blockIdx.x * 64;
    if (r0 >= nrows) return;
    int c0 = blockIdx.y * 64;
    int tid = threadIdx.x;
    int tx = tid & 15, ty = tid >> 4;
    int lrow = tid >> 2, lkg = (tid & 3) << 2;
    float acc[4][4] = {};
    for (int kk = 0; kk < H; kk += 16) {
        float4 av = make_float4(0.f,0.f,0.f,0.f);
        int gr = r0 + lrow;
        if (gr < nrows) av = *(const float4*)(A + (size_t)gr*H + kk + lkg);
        As[lkg+0][lrow]=av.x; As[lkg+1][lrow]=av.y; As[lkg+2][lrow]=av.z; As[lkg+3][lrow]=av.w;
        float4 wv = *(const float4*)(W + (size_t)(c0+lrow)*H + kk + lkg);
        Ws[lkg+0][lrow]=wv.x; Ws[lkg+1][lrow]=wv.y; Ws[lkg+2][lrow]=wv.z; Ws[lkg+3][lrow]=wv.w;
        __syncthreads();
        #pragma unroll
        for (int k = 0; k < 16; ++k) {
            float4 a = *(const float4*)&As[k][ty<<2];
            float4 bv = *(const float4*)&Ws[k][tx<<2];
            float aa[4] = {a.x,a.y,a.z,a.w};
            float bb[4] = {bv.x,bv.y,bv.z,bv.w};
            #pragma unroll
            for (int ii = 0; ii < 4; ++ii)
                #pragma unroll
                for (int jj = 0; jj < 4; ++jj)
                    acc[ii][jj] += aa[ii] * bb[jj];
        }
        __syncthreads();
    }
    #pragma unroll
    for (int ii = 0; ii < 4; ++ii) {
        int gr = r0 + (ty<<2) + ii;
        if (gr < nrows) {
            #pragma unroll
            for (int jj = 0; jj < 4; ++jj) {
                int gc = c0 + (tx<<2) + jj;
                out[(size_t)gr*H + gc] = acc[ii][jj] + bias[gc];
            }
        }
    }
}

// ---------------- flash attention, fp32, q in LDS, transposed softmax ----------------
// grid (B, NH, ceil(nq/QT)); 4 waves x 8 queries; K/V staged once per k-tile.
__global__ __launch_bounds__(256) void attn_kernel(
    const float* __restrict__ qbuf, const float* __restrict__ kbuf,
    const float* __restrict__ vbuf, float* __restrict__ ctx, int nq)
{
    __shared__ float Ks[KT][HD+4];
    __shared__ float VsT[HD][KT+4];
    __shared__ float qs[QT][HD+4];
    __shared__ float ps[QT][KT+4];
    int b = blockIdx.x, h = blockIdx.y, z = blockIdx.z;
    int qbase = z * QT;
    int nqt = nq - qbase;
    if (nqt <= 0) return;
    if (nqt > QT) nqt = QT;
    int tid = threadIdx.x, w = tid >> 6, lane = tid & 63;
    int off = SEQL - nq;
    // stage q tile once
    for (int i = tid; i < QT*(HD/4); i += 256) {
        int row = i >> 4, c4 = (i & 15) << 2;
        float4 qv = make_float4(0.f,0.f,0.f,0.f);
        if (row < nqt) qv = *(const float4*)(qbuf + (size_t)(b*nq + qbase + row)*H + h*HD + c4);
        *(float4*)&qs[row][c4] = qv;
    }
    float m[QW], l[QW], acc[QW];
    #pragma unroll
    for (int i = 0; i < QW; ++i) { m[i] = -3e30f; l[i] = 0.f; acc[i] = 0.f; }
    int wq0 = w * QW;
    int wqn = nqt - wq0; if (wqn > QW) wqn = QW;      // may be <= 0 (idle wave)
    int wmaxpos = qbase + wq0 + (wqn > 0 ? wqn - 1 : 0) + off;
    int ntiles = (qbase + nqt - 1 + off) / KT + 1;
    int q_sub = lane >> 3, kq = lane & 7;
    for (int t = 0; t < ntiles; ++t) {
        int kbase = t * KT;
        __syncthreads();
        // stage K row-major
        for (int i = tid; i < KT*(HD/4); i += 256) {
            int row = i >> 4, c4 = (i & 15) << 2;
            int key = kbase + row;
            float4 kv = make_float4(0.f,0.f,0.f,0.f);
            if (key < SEQL) kv = *(const float4*)(kbuf + (size_t)(b*SEQL + key)*H + h*HD + c4);
            *(float4*)&Ks[row][c4] = kv;
        }
        // stage V transposed
        {
            int key = kbase + lane;
            bool kval = key < SEQL;
            const float* vp = vbuf + (size_t)(b*SEQL + (kval ? key : 0))*H + h*HD;
            #pragma unroll
            for (int it = 0; it < 4; ++it) {
                int c4 = ((it << 2) + w) << 2;
                float4 vv = make_float4(0.f,0.f,0.f,0.f);
                if (kval) vv = *(const float4*)(vp + c4);
                VsT[c4+0][lane] = vv.x; VsT[c4+1][lane] = vv.y;
                VsT[c4+2][lane] = vv.z; VsT[c4+3][lane] = vv.w;
            }
        }
        __syncthreads();
        if (wqn > 0 && kbase <= wmaxpos) {
            // ---- phase 1: scores, lane = key ----
            float s[QW];
            #pragma unroll
            for (int qi = 0; qi < QW; ++qi) s[qi] = 0.f;
            #pragma unroll 4
            for (int d4 = 0; d4 < HD; d4 += 4) {
                float4 k4 = *(const float4*)&Ks[lane][d4];
                #pragma unroll
                for (int qi = 0; qi < QW; ++qi) {
                    float4 q4 = *(const float4*)&qs[wq0+qi][d4];
                    s[qi] += k4.x*q4.x + k4.y*q4.y + k4.z*q4.z + k4.w*q4.w;
                }
            }
            #pragma unroll
            for (int qi = 0; qi < QW; ++qi) {
                if (qi < wqn) {
                    int qpos = qbase + wq0 + qi + off;
                    bool valid = (kbase + lane) <= qpos;
                    ps[wq0+qi][lane] = valid ? s[qi]*0.125f : -3e30f;
                }
            }
            // ---- phase 2: transposed softmax; lane = (q_sub, 8-key group) ----
            float mq = m[0];
            #pragma unroll
            for (int i = 1; i < QW; ++i) if (q_sub == i) mq = m[i];
            const float2* pr = (const float2*)&ps[wq0+q_sub][kq*8];
            float2 a0 = pr[0], a1 = pr[1], a2 = pr[2], a3 = pr[3];
            float mloc = fmaxf(fmaxf(fmaxf(a0.x,a0.y), fmaxf(a1.x,a1.y)),
                               fmaxf(fmaxf(a2.x,a2.y), fmaxf(a3.x,a3.y)));
            float tm = mloc;
            #pragma unroll
            for (int o = 1; o < 8; o <<= 1) tm = fmaxf(tm, __shfl_xor(tm, o, 64));
            float mn = fmaxf(mq, tm);
            float p0 = expf(a0.x-mn), p1 = expf(a0.y-mn), p2 = expf(a1.x-mn), p3 = expf(a1.y-mn);
            float p4 = expf(a2.x-mn), p5 = expf(a2.y-mn), p6 = expf(a3.x-mn), p7 = expf(a3.y-mn);
            float psum = ((p0+p1)+(p2+p3)) + ((p4+p5)+(p6+p7));
            #pragma unroll
            for (int o = 1; o < 8; o <<= 1) psum += __shfl_xor(psum, o, 64);
            float2* pw = (float2*)&ps[wq0+q_sub][kq*8];
            pw[0] = make_float2(p0,p1); pw[1] = make_float2(p2,p3);
            pw[2] = make_float2(p4,p5); pw[3] = make_float2(p6,p7);
            // broadcast per-query (tm,psum) to all lanes; update state statically
            #pragma unroll
            for (int qi = 0; qi < QW; ++qi) {
                float tmv = __shfl(tm, qi*8, 64);
                float psv = __shfl(psum, qi*8, 64);
                if (qi < wqn) {
                    float mn2 = fmaxf(m[qi], tmv);
                    float scl = expf(m[qi] - mn2);
                    l[qi] = l[qi]*scl + psv;
                    acc[qi] *= scl;
                    m[qi] = mn2;
                }
            }
            // ---- phase 3: PV, lane = dim ----
            #pragma unroll 4
            for (int k4 = 0; k4 < KT; k4 += 4) {
                float4 v4 = *(const float4*)&VsT[lane][k4];
                #pragma unroll
                for (int qi = 0; qi < QW; ++qi) {
                    if (qi < wqn) {
                        float4 p4v = *(const float4*)&ps[wq0+qi][k4];
                        acc[qi] += p4v.x*v4.x + p4v.y*v4.y + p4v.z*v4.z + p4v.w*v4.w;
                    }
                }
            }
        }
    }
    #pragma unroll
    for (int qi = 0; qi < QW; ++qi) {
        if (qi < wqn) {
            ctx[(size_t)(b*nq + qbase + wq0 + qi)*H + h*HD + lane] = acc[qi] / l[qi];
        }
    }
}

// ---------------- gate: logits + top-2 (no global atomics) ----------------
__global__ __launch_bounds__(256) void gate_kernel(
    const float* __restrict__ X, const float* __restrict__ gw, const float* __restrict__ gb,
    int* __restrict__ top_idx, float* __restrict__ top_w, int nrows)
{
    __shared__ float gl[NEXP];
    int n = blockIdx.x;
    int tid = threadIdx.x;
    int wv = tid >> 6, lane = tid & 63;
    float xv[4];
    #pragma unroll
    for (int c = 0; c < 4; ++c) xv[c] = X[(size_t)n*H + lane + (c<<6)];
    #pragma unroll
    for (int s = 0; s < 2; ++s) {
        int e = wv*2 + s;
        float acc = 0.f;
        #pragma unroll
        for (int c = 0; c < 4; ++c) acc += xv[c] * gw[(size_t)e*H + lane + (c<<6)];
        #pragma unroll
        for (int o = 32; o > 0; o >>= 1) acc += __shfl_xor(acc, o, 64);
        if (lane == 0) gl[e] = acc + gb[e];
    }
    __syncthreads();
    if (tid == 0) {
        int i0 = 0;
        for (int e = 1; e < NEXP; ++e) if (gl[e] > gl[i0]) i0 = e;
        int i1 = -1;
        for (int e = 0; e < NEXP; ++e) { if (e == i0) continue; if (i1 < 0 || gl[e] > gl[i1]) i1 = e; }
        float e1 = expf(gl[i1] - gl[i0]);
        float w0 = 1.f / (1.f + e1);
        top_idx[n*2+0] = i0; top_idx[n*2+1] = i1;
        top_w[n*2+0] = w0;  top_w[n*2+1] = 1.f - w0;
    }
}

// ---------------- count: LDS histogram ----------------
__global__ __launch_bounds__(256) void count_kernel(
    const int* __restrict__ top_idx, int* __restrict__ counts, int nrows)
{
    __shared__ int hist[NEXP];
    int tid = threadIdx.x;
    if (tid < NEXP) hist[tid] = 0;
    __syncthreads();
    int n = blockIdx.x * 256 + tid;
    if (n < nrows) {
        atomicAdd(&hist[top_idx[n*2+0]], 1);
        atomicAdd(&hist[top_idx[n*2+1]], 1);
    }
    __syncthreads();
    if (tid < NEXP && hist[tid] > 0) atomicAdd(&counts[tid], hist[tid]);
}

__global__ void scan_kernel(const int* __restrict__ counts, int* __restrict__ offsets,
                            int* __restrict__ cursor)
{
    int s = 0;
    for (int e = 0; e < NEXP; ++e) { offsets[e] = s; cursor[e] = s; s += counts[e]; }
}

// ---------------- block-aggregated scatter (+ inverse map tok_pair) ----------------
__global__ __launch_bounds__(256) void scatter_kernel(
    const int* __restrict__ top_idx,
    int* __restrict__ cursor, int* __restrict__ pair_tok, int* __restrict__ tok_pair, int nrows)
{
    __shared__ int lcnt[NEXP];
    __shared__ int lbase[NEXP];
    int tid = threadIdx.x;
    if (tid < NEXP) lcnt[tid] = 0;
    __syncthreads();
    int n = blockIdx.x * 256 + tid;
    int e0 = 0, e1 = 0, p0 = 0, p1 = 0;
    bool act = n < nrows;
    if (act) {
        e0 = top_idx[n*2+0]; e1 = top_idx[n*2+1];
        p0 = atomicAdd(&lcnt[e0], 1);
        p1 = atomicAdd(&lcnt[e1], 1);
    }
    __syncthreads();
    if (tid < NEXP) lbase[tid] = (lcnt[tid] > 0) ? atomicAdd(&cursor[tid], lcnt[tid]) : 0;
    __syncthreads();
    if (act) {
        int q0 = lbase[e0] + p0, q1 = lbase[e1] + p1;
        pair_tok[q0] = n; pair_tok[q1] = n;
        tok_pair[n*2+0] = q0; tok_pair[n*2+1] = q1;
    }
}

// ---------------- grouped MoE GEMM 1: h = relu(X[tok] @ W1[e] + b1[e]) ----------------
__global__ __launch_bounds__(256) void moe_gemm1(
    const float* __restrict__ X, const float* __restrict__ W1base,
    const float* __restrict__ b1base, const int* __restrict__ pair_tok,
    const int* __restrict__ offsets, const int* __restrict__ counts,
    float* __restrict__ hbuf)
{
    int e = blockIdx.z;
    int cnt = counts[e];
    int r0 = blockIdx.x * 64;
    if (r0 >= cnt) return;
    int off = offsets[e];
    int c0 = blockIdx.y * 64;
    const float* W = W1base + (size_t)e * H * H;
    const float* bias = b1base + (size_t)e * H;
    __shared__ float As[16][68];
    __shared__ float Bs[16][68];
    int tid = threadIdx.x, tx = tid & 15, ty = tid >> 4;
    int lrow = tid >> 2, lkg = (tid & 3) << 2;
    float acc[4][4] = {};
    for (int kk = 0; kk < H; kk += 16) {
        float4 av = make_float4(0.f,0.f,0.f,0.f);
        int pr = r0 + lrow;
        if (pr < cnt) {
            int tok = pair_tok[off + pr];
            av = *(const float4*)(X + (size_t)tok*H + kk + lkg);
        }
        As[lkg+0][lrow]=av.x; As[lkg+1][lrow]=av.y; As[lkg+2][lrow]=av.z; As[lkg+3][lrow]=av.w;
        float4 wv = *(const float4*)(W + (size_t)(kk+ty)*H + c0 + (tx<<2));
        *(float4*)&Bs[ty][tx<<2] = wv;
        __syncthreads();
        #pragma unroll
        for (int k = 0; k < 16; ++k) {
            float4 a = *(const float4*)&As[k][ty<<2];
            float4 bv = *(const float4*)&Bs[k][tx<<2];
            float aa[4] = {a.x,a.y,a.z,a.w};
            float bb[4] = {bv.x,bv.y,bv.z,bv.w};
            #pragma unroll
            for (int ii = 0; ii < 4; ++ii)
                #pragma unroll
                for (int jj = 0; jj < 4; ++jj)
                    acc[ii][jj] += aa[ii] * bb[jj];
        }
        __syncthreads();
    }
    #pragma unroll
    for (int ii = 0; ii < 4; ++ii) {
        int pr = r0 + (ty<<2) + ii;
        if (pr < cnt) {
            #pragma unroll
            for (int jj = 0; jj < 4; ++jj) {
                int gc = c0 + (tx<<2) + jj;
                hbuf[(size_t)(off+pr)*H + gc] = fmaxf(acc[ii][jj] + bias[gc], 0.f);
            }
        }
    }
}

// ---------------- grouped MoE GEMM 2: y[pair] = h @ W2[e] + b2[e]  (no atomics) ---------
__global__ __launch_bounds__(256) void moe_gemm2(
    const float* __restrict__ Hbuf, const float* __restrict__ W2base,
    const float* __restrict__ b2base, const int* __restrict__ offsets,
    const int* __restrict__ counts, float* __restrict__ ybuf)
{
    int e = blockIdx.z;
    int cnt = counts[e];
    int r0 = blockIdx.x * 64;
    if (r0 >= cnt) return;
    int off = offsets[e];
    int c0 = blockIdx.y * 64;
    const float* W = W2base + (size_t)e * H * H;
    const float* bias = b2base + (size_t)e * H;
    __shared__ float As[16][68];
    __shared__ float Bs[16][68];
    int tid = threadIdx.x, tx = tid & 15, ty = tid >> 4;
    int lrow = tid >> 2, lkg = (tid & 3) << 2;
    float acc[4][4] = {};
    for (int kk = 0; kk < H; kk += 16) {
        float4 av = make_float4(0.f,0.f,0.f,0.f);
        int pr = r0 + lrow;
        if (pr < cnt) av = *(const float4*)(Hbuf + (size_t)(off+pr)*H + kk + lkg);
        As[lkg+0][lrow]=av.x; As[lkg+1][lrow]=av.y; As[lkg+2][lrow]=av.z; As[lkg+3][lrow]=av.w;
        float4 wv = *(const float4*)(W + (size_t)(kk+ty)*H + c0 + (tx<<2));
        *(float4*)&Bs[ty][tx<<2] = wv;
        __syncthreads();
        #pragma unroll
        for (int k = 0; k < 16; ++k) {
            float4 a = *(const float4*)&As[k][ty<<2];
            float4 bv = *(const float4*)&Bs[k][tx<<2];
            float aa[4] = {a.x,a.y,a.z,a.w};
            float bb[4] = {bv.x,bv.y,bv.z,bv.w};
            #pragma unroll
            for (int ii = 0; ii < 4; ++ii)
                #pragma unroll
                for (int jj = 0; jj < 4; ++jj)
                    acc[ii][jj] += aa[ii] * bb[jj];
        }
        __syncthreads();
    }
    #pragma unroll
    for (int ii = 0; ii < 4; ++ii) {
        int pr = r0 + (ty<<2) + ii;
        if (pr < cnt) {
            #pragma unroll
            for (int jj = 0; jj < 4; ++jj) {
                int gc = c0 + (tx<<2) + jj;
                ybuf[(size_t)(off+pr)*H + gc] = acc[ii][jj] + bias[gc];
            }
        }
    }
}

__global__ void zero_kernel(float* __restrict__ p, int n) {
    int i = blockIdx.x * 256 + threadIdx.x;
    if (i < n) p[i] = 0.f;
}

// ---------------- final: LN + user emb + dot(item emb) ----------------
__global__ __launch_bounds__(256) void final_kernel(
    const float* __restrict__ xf, const float* __restrict__ lnw, const float* __restrict__ lnb,
    const float* __restrict__ user_emb, const float* __restrict__ item_emb,
    const int* __restrict__ user_ids, const int* __restrict__ item_ids, float* __restrict__ out)
{
    __shared__ float s4[4];
    int bb = blockIdx.x, t = threadIdx.x;
    float v = xf[(size_t)bb*H + t];
    float mean = blk_sum256(v, s4) * (1.f/H);
    float d = v - mean;
    float var = blk_sum256(d*d, s4) * (1.f/H);
    float lnv = d * rsqrtf(var + 1e-8f) * lnw[t] + lnb[t];
    float fin = lnv + user_emb[(size_t)user_ids[bb]*H + t];
    float prod = fin * item_emb[(size_t)item_ids[bb]*H + t];
    float tot = blk_sum256(prod, s4);
    if (t == 0) out[bb] = tot;
}

// ---------------- launch ----------------
extern "C" void kernel_launch(void* const* d_in, const int* in_sizes, int n_in,
                              void* d_out, int out_size, void* d_ws, size_t ws_size,
                              hipStream_t stream)
{
    (void)in_sizes; (void)n_in; (void)out_size; (void)ws_size;
    const int*   user_ids  = (const int*)d_in[0];
    const int*   log_seqs  = (const int*)d_in[1];
    const int*   item_ids  = (const int*)d_in[2];
    const float* item_emb  = (const float*)d_in[3];
    const float* pos_emb   = (const float*)d_in[4];
    const float* user_emb  = (const float*)d_in[5];
    const float* ln1_w     = (const float*)d_in[6];
    const float* ln1_b     = (const float*)d_in[7];
    const float* inproj_w  = (const float*)d_in[8];
    const float* inproj_b  = (const float*)d_in[9];
    const float* outproj_w = (const float*)d_in[10];
    const float* outproj_b = (const float*)d_in[11];
    const float* ln2_w     = (const float*)d_in[12];
    const float* ln2_b     = (const float*)d_in[13];
    const float* gate_w    = (const float*)d_in[14];
    const float* gate_b    = (const float*)d_in[15];
    const float* e_w1      = (const float*)d_in[16];
    const float* e_b1      = (const float*)d_in[17];
    const float* e_w2      = (const float*)d_in[18];
    const float* e_b2      = (const float*)d_in[19];
    const float* moeln_w   = (const float*)d_in[20];
    const float* moeln_b   = (const float*)d_in[21];
    const float* lastln_w  = (const float*)d_in[22];
    const float* lastln_b  = (const float*)d_in[23];

    float* ws = (float*)d_ws;
    const size_t NFH = (size_t)NF * H;
    float* buf0 = ws;
    float* buf1 = buf0 + NFH;   // buf1+buf2 contiguous -> ybuf region (2*NF rows)
    float* buf2 = buf1 + NFH;
    float* buf3 = buf2 + NFH;   // buf3+buf4 contiguous -> MoE h region (2*NF rows)
    float* buf4 = buf3 + NFH;
    float* s0   = buf4 + NFH;
    float* s1   = s0 + (size_t)BATCH*H;
    float* s2   = s1 + (size_t)BATCH*H;
    float* s3   = s2 + (size_t)BATCH*H;
    float* s6   = s3 + (size_t)BATCH*H;
    float* s4   = s6 + (size_t)BATCH*H;            // 2*BATCH rows (h)
    float* s5   = s4 + (size_t)2*BATCH*H;          // 2*BATCH rows (y)
    float* top_w   = s5 + (size_t)2*BATCH*H;
    int*   top_idx = (int*)(top_w + (size_t)NF*2);
    int*   pair_tok= top_idx + (size_t)NF*2;
    int*   tok_pair= pair_tok + (size_t)NF*2;
    int*   counts  = tok_pair + (size_t)NF*2;
    int*   offsets = counts + NEXP;
    int*   cursor  = offsets + NEXP;

    dim3 blk(256);
    dim3 gfull((NF+63)/64, H/64);
    dim3 gsmall((BATCH+63)/64, H/64);
    dim3 mfull((NF+63)/64, H/64, NEXP);
    dim3 msmall((BATCH+63)/64, H/64, NEXP);

    embed_kernel<<<NF, blk, 0, stream>>>(log_seqs, item_emb, pos_emb, buf0);

    // ================= block 0 : full sequence =================
    {
        const int i = 0;
        const float* Wq = inproj_w + (size_t)i*3*H*H;
        const float* Wk = Wq + (size_t)H*H;
        const float* Wv = Wk + (size_t)H*H;
        const float* bq = inproj_b + (size_t)i*3*H;
        ln_kernel<<<NF, blk, 0, stream>>>(buf0, nullptr, buf1, ln1_w + i*H, ln1_b + i*H, 1e-8f, 0, 1);
        gemm_nt<<<gfull, blk, 0, stream>>>(buf1, Wq, bq,       buf2, NF);   // q
        gemm_nt<<<gfull, blk, 0, stream>>>(buf0, Wk, bq + H,   buf3, NF);   // k
        gemm_nt<<<gfull, blk, 0, stream>>>(buf0, Wv, bq + 2*H, buf4, NF);   // v
        attn_kernel<<<dim3(BATCH, NHEAD, (SEQL+QT-1)/QT), blk, 0, stream>>>(buf2, buf3, buf4, buf2, SEQL);
        gemm_nt<<<gfull, blk, 0, stream>>>(buf2, outproj_w + (size_t)i*H*H, outproj_b + i*H, buf3, NF);
        ln_kernel<<<NF, blk, 0, stream>>>(buf1, buf3, buf0, ln2_w + i*H, ln2_b + i*H, 1e-8f, 0, 1);
        zero_kernel<<<1, 32, 0, stream>>>((float*)counts, NEXP);
        gate_kernel<<<NF, blk, 0, stream>>>(buf0, gate_w + (size_t)i*NEXP*H, gate_b + i*NEXP,
                                            top_idx, top_w, NF);
        count_kernel<<<(NF+255)/256, blk, 0, stream>>>(top_idx, counts, NF);
        scan_kernel<<<1, 1, 0, stream>>>(counts, offsets, cursor);
        scatter_kernel<<<(NF+255)/256, blk, 0, stream>>>(top_idx, cursor, pair_tok, tok_pair, NF);
        moe_gemm1<<<mfull, blk, 0, stream>>>(buf0, e_w1 + (size_t)i*NEXP*H*H, e_b1 + (size_t)i*NEXP*H,
                                             pair_tok, offsets, counts, buf3);
        moe_gemm2<<<mfull, blk, 0, stream>>>(buf3, e_w2 + (size_t)i*NEXP*H*H, e_b2 + (size_t)i*NEXP*H,
                                             offsets, counts, buf1);
        moe_ln_kernel<<<NF, blk, 0, stream>>>(buf0, buf1, tok_pair, top_w, buf3,
                                              moeln_w + i*H, moeln_b + i*H, 1e-5f);
    }

    // ================= block 1 : only last position matters downstream =================
    {
        const int i = 1;
        const float* Wq = inproj_w + (size_t)i*3*H*H;
        const float* Wk = Wq + (size_t)H*H;
        const float* Wv = Wk + (size_t)H*H;
        const float* bq = inproj_b + (size_t)i*3*H;
        float* X = buf3;
        ln_kernel<<<BATCH, blk, 0, stream>>>(X, nullptr, s0, ln1_w + i*H, ln1_b + i*H, 1e-8f, SEQL-1, SEQL);
        gemm_nt<<<gsmall, blk, 0, stream>>>(s0, Wq, bq, s1, BATCH);          // q (last rows only)
        gemm_nt<<<gfull, blk, 0, stream>>>(X, Wk, bq + H,   buf0, NF);       // k (full)
        gemm_nt<<<gfull, blk, 0, stream>>>(X, Wv, bq + 2*H, buf1, NF);       // v (full)
        attn_kernel<<<dim3(BATCH, NHEAD, 1), blk, 0, stream>>>(s1, buf0, buf1, s2, 1);
        gemm_nt<<<gsmall, blk, 0, stream>>>(s2, outproj_w + (size_t)i*H*H, outproj_b + i*H, s3, BATCH);
        ln_kernel<<<BATCH, blk, 0, stream>>>(s0, s3, s2, ln2_w + i*H, ln2_b + i*H, 1e-8f, 0, 1);
        zero_kernel<<<1, 32, 0, stream>>>((float*)counts, NEXP);
        gate_kernel<<<BATCH, blk, 0, stream>>>(s2, gate_w + (size_t)i*NEXP*H, gate_b + i*NEXP,
                                               top_idx, top_w, BATCH);
        count_kernel<<<1, blk, 0, stream>>>(top_idx, counts, BATCH);
        scan_kernel<<<1, 1, 0, stream>>>(counts, offsets, cursor);
        scatter_kernel<<<1, blk, 0, stream>>>(top_idx, cursor, pair_tok, tok_pair, BATCH);
        moe_gemm1<<<msmall, blk, 0, stream>>>(s2, e_w1 + (size_t)i*NEXP*H*H, e_b1 + (size_t)i*NEXP*H,
                                              pair_tok, offsets, counts, s4);
        moe_gemm2<<<msmall, blk, 0, stream>>>(s4, e_w2 + (size_t)i*NEXP*H*H, e_b2 + (size_t)i*NEXP*H,
                                              offsets, counts, s5);
        moe_ln_kernel<<<BATCH, blk, 0, stream>>>(s2, s5, tok_pair, top_w, s6,
                                                 moeln_w + i*H, moeln_b + i*H, 1e-5f);
    }

    final_kernel<<<BATCH, blk, 0, stream>>>(s6, lastln_w, lastln_b, user_emb, item_emb,
                                            user_ids, item_ids, (float*)d_out);
}

// Round 11
// 902.526 us; speedup vs baseline: 2.1147x; 1.0284x over previous
//
#include <hip/hip_runtime.h>
#include <math.h>

#define H 256
#define NHEAD 4
#define HD 64
#define NEXP 8
#define SEQL 200
#define BATCH 128
#define NF (BATCH*SEQL)
#define KT 64
#define QT 32
#define QW 8   // queries per wave

// ---------------- helpers ----------------
__device__ __forceinline__ float blk_sum256(float v, float* s4) {
    #pragma unroll
    for (int o = 32; o > 0; o >>= 1) v += __shfl_xor(v, o, 64);
    __syncthreads();
    if ((threadIdx.x & 63) == 0) s4[threadIdx.x >> 6] = v;
    __syncthreads();
    return s4[0] + s4[1] + s4[2] + s4[3];
}

// ---------------- embedding ----------------
__global__ __launch_bounds__(256) void embed_kernel(
    const int* __restrict__ seqs, const float* __restrict__ item_emb,
    const float* __restrict__ pos_emb, float* __restrict__ x)
{
    int n = blockIdx.x, t = threadIdx.x;
    int id = seqs[n];
    int pos = (id != 0) ? (n % SEQL) + 1 : 0;
    x[(size_t)n*H + t] = item_emb[(size_t)id*H + t] * 16.0f + pos_emb[(size_t)pos*H + t];
}

// ---------------- layernorm (gather + optional residual) ----------------
__global__ __launch_bounds__(256) void ln_kernel(
    const float* __restrict__ in, const float* __restrict__ res,
    float* __restrict__ out, const float* __restrict__ w, const float* __restrict__ b,
    float eps, int base, int step)
{
    __shared__ float s4[4];
    int r = blockIdx.x, t = threadIdx.x;
    float v = in[(size_t)(base + r*step)*H + t];
    if (res) v += res[(size_t)r*H + t];
    float mean = blk_sum256(v, s4) * (1.f/H);
    float d = v - mean;
    float var = blk_sum256(d*d, s4) * (1.f/H);
    out[(size_t)r*H + t] = d * rsqrtf(var + eps) * w[t] + b[t];
}

// ---------------- fused moe combine + layernorm ----------------
__global__ __launch_bounds__(256) void moe_ln_kernel(
    const float* __restrict__ x, const float* __restrict__ ybuf,
    const int* __restrict__ tok_pair, const float* __restrict__ top_w,
    float* __restrict__ out, const float* __restrict__ w, const float* __restrict__ b,
    float eps)
{
    __shared__ float s4[4];
    int r = blockIdx.x, t = threadIdx.x;
    int p0 = tok_pair[r*2], p1 = tok_pair[r*2+1];
    float v = x[(size_t)r*H + t]
            + top_w[r*2+0] * ybuf[(size_t)p0*H + t]
            + top_w[r*2+1] * ybuf[(size_t)p1*H + t];
    float mean = blk_sum256(v, s4) * (1.f/H);
    float d = v - mean;
    float var = blk_sum256(d*d, s4) * (1.f/H);
    out[(size_t)r*H + t] = d * rsqrtf(var + eps) * w[t] + b[t];
}

// ---------------- GEMM (64x64 tile) — proven bit-path ----------------
__global__ __launch_bounds__(256) void gemm_nt(
    const float* __restrict__ A, const float* __restrict__ W,
    const float* __restrict__ bias, float* __restrict__ out, int nrows)
{
    __shared__ float As[16][68];
    __shared__ float Ws[16][68];
    int r0 = blockIdx.x * 64;
    if (r0 >= nrows) return;
    int c0 = blockIdx.y * 64;
    int tid = threadIdx.x;
    int tx = tid & 15, ty = tid >> 4;
    int lrow = tid >> 2, lkg = (tid & 3) << 2;
    float acc[4][4] = {};
    for (int kk = 0; kk < H; kk += 16) {
        float4 av = make_float4(0.f,0.f,0.f,0.f);
        int gr = r0 + lrow;
        if (gr < nrows) av = *(const float4*)(A + (size_t)gr*H + kk + lkg);
        As[lkg+0][lrow]=av.x; As[lkg+1][lrow]=av.y; As[lkg+2][lrow]=av.z; As[lkg+3][lrow]=av.w;
        float4 wv = *(const float4*)(W + (size_t)(c0+lrow)*H + kk + lkg);
        Ws[lkg+0][lrow]=wv.x; Ws[lkg+1][lrow]=wv.y; Ws[lkg+2][lrow]=wv.z; Ws[lkg+3][lrow]=wv.w;
        __syncthreads();
        #pragma unroll
        for (int k = 0; k < 16; ++k) {
            float4 a = *(const float4*)&As[k][ty<<2];
            float4 bv = *(const float4*)&Ws[k][tx<<2];
            float aa[4] = {a.x,a.y,a.z,a.w};
            float bb[4] = {bv.x,bv.y,bv.z,bv.w};
            #pragma unroll
            for (int ii = 0; ii < 4; ++ii)
                #pragma unroll
                for (int jj = 0; jj < 4; ++jj)
                    acc[ii][jj] += aa[ii] * bb[jj];
        }
        __syncthreads();
    }
    #pragma unroll
    for (int ii = 0; ii < 4; ++ii) {
        int gr = r0 + (ty<<2) + ii;
        if (gr < nrows) {
            #pragma unroll
            for (int jj = 0; jj < 4; ++jj) {
                int gc = c0 + (tx<<2) + jj;
                out[(size_t)gr*H + gc] = acc[ii][jj] + bias[gc];
            }
        }
    }
}

// ---------------- 128x128 GEMM body ----------------
// GATHER: A rows via pair_tok. RELU: relu epilogue.
// BT=1: W is [N][K] (inproj/outproj, B-transposed)  — proven bit-clean (R9/R10 diff).
// BT=0: W is [K][N] (MoE expert weights, B normal) — matches moe_gemm1/2 bit-path.
template<int GATHER, int RELU, int BT>
__device__ __forceinline__ void gemm128_body(
    const float* __restrict__ A, const float* __restrict__ W,
    const float* __restrict__ bias, float* __restrict__ out, int nrows,
    const int* __restrict__ pair_tok)
{
    __shared__ float As[16][132];
    __shared__ float Ws[16][132];
    int r0 = blockIdx.x * 128;
    if (r0 >= nrows) return;
    int c0 = blockIdx.y * 128;
    int tid = threadIdx.x;
    int tx = tid & 15, ty = tid >> 4;
    int lrow = tid >> 1, lkg = (tid & 1) << 3;
    int ar = r0 + lrow;
    bool va = ar < nrows;
    int ga = ar;
    if (GATHER) ga = va ? pair_tok[r0 + lrow] : 0;
    const float* ap = A + (size_t)(va ? ga : 0)*H + lkg;
    // B pointers
    const float* wpT = W + (size_t)(c0 + lrow)*H + lkg;                     // BT=1
    int kr0 = tid >> 5, cg = (tid & 31) << 2;                               // BT=0
    const float* wpN0 = W + (size_t)kr0*H + c0 + cg;
    const float* wpN1 = wpN0 + (size_t)8*H;
    float acc[8][8] = {};
    for (int kk = 0; kk < H; kk += 16) {
        float4 av0 = make_float4(0.f,0.f,0.f,0.f), av1 = av0;
        if (va) { av0 = *(const float4*)(ap + kk); av1 = *(const float4*)(ap + kk + 4); }
        float4 wv0, wv1;
        if (BT) {
            wv0 = *(const float4*)(wpT + kk);
            wv1 = *(const float4*)(wpT + kk + 4);
        } else {
            wv0 = *(const float4*)(wpN0 + (size_t)kk*H);
            wv1 = *(const float4*)(wpN1 + (size_t)kk*H);
        }
        __syncthreads();   // prev compute done reading LDS
        As[lkg+0][lrow]=av0.x; As[lkg+1][lrow]=av0.y; As[lkg+2][lrow]=av0.z; As[lkg+3][lrow]=av0.w;
        As[lkg+4][lrow]=av1.x; As[lkg+5][lrow]=av1.y; As[lkg+6][lrow]=av1.z; As[lkg+7][lrow]=av1.w;
        if (BT) {
            Ws[lkg+0][lrow]=wv0.x; Ws[lkg+1][lrow]=wv0.y; Ws[lkg+2][lrow]=wv0.z; Ws[lkg+3][lrow]=wv0.w;
            Ws[lkg+4][lrow]=wv1.x; Ws[lkg+5][lrow]=wv1.y; Ws[lkg+6][lrow]=wv1.z; Ws[lkg+7][lrow]=wv1.w;
        } else {
            *(float4*)&Ws[kr0][cg]     = wv0;
            *(float4*)&Ws[kr0 + 8][cg] = wv1;
        }
        __syncthreads();
        #pragma unroll
        for (int k = 0; k < 16; ++k) {
            float4 a0 = *(const float4*)&As[k][ty<<2];
            float4 a1 = *(const float4*)&As[k][64 + (ty<<2)];
            float4 b0 = *(const float4*)&Ws[k][tx<<2];
            float4 b1 = *(const float4*)&Ws[k][64 + (tx<<2)];
            float aa[8] = {a0.x,a0.y,a0.z,a0.w,a1.x,a1.y,a1.z,a1.w};
            float bb[8] = {b0.x,b0.y,b0.z,b0.w,b1.x,b1.y,b1.z,b1.w};
            #pragma unroll
            for (int ii = 0; ii < 8; ++ii)
                #pragma unroll
                for (int jj = 0; jj < 8; ++jj)
                    acc[ii][jj] += aa[ii] * bb[jj];
        }
    }
    #pragma unroll
    for (int hr = 0; hr < 2; ++hr)
        #pragma unroll
        for (int ii = 0; ii < 4; ++ii) {
            int row = r0 + 64*hr + (ty<<2) + ii;
            if (row < nrows) {
                #pragma unroll
                for (int hc = 0; hc < 2; ++hc) {
                    int col = c0 + 64*hc + (tx<<2);
                    #pragma unroll
                    for (int jj = 0; jj < 4; ++jj) {
                        float o = acc[4*hr+ii][4*hc+jj] + bias[col+jj];
                        if (RELU) o = fmaxf(o, 0.f);
                        out[(size_t)row*H + col + jj] = o;
                    }
                }
            }
        }
}

__global__ __launch_bounds__(256) void gemm_nt128(
    const float* __restrict__ A, const float* __restrict__ W,
    const float* __restrict__ bias, float* __restrict__ out, int nrows)
{
    gemm128_body<0,0,1>(A, W, bias, out, nrows, nullptr);
}

__global__ __launch_bounds__(256) void moe1_128(
    const float* __restrict__ X, const float* __restrict__ W1base,
    const float* __restrict__ b1base, const int* __restrict__ pair_tok,
    const int* __restrict__ offsets, const int* __restrict__ counts,
    float* __restrict__ hbuf)
{
    int e = blockIdx.z;
    int cnt = counts[e], off = offsets[e];
    gemm128_body<1,1,0>(X, W1base + (size_t)e*H*H, b1base + (size_t)e*H,
                        hbuf + (size_t)off*H, cnt, pair_tok + off);
}

__global__ __launch_bounds__(256) void moe2_128(
    const float* __restrict__ Hbuf, const float* __restrict__ W2base,
    const float* __restrict__ b2base, const int* __restrict__ offsets,
    const int* __restrict__ counts, float* __restrict__ ybuf)
{
    int e = blockIdx.z;
    int cnt = counts[e], off = offsets[e];
    gemm128_body<0,0,0>(Hbuf + (size_t)off*H, W2base + (size_t)e*H*H, b2base + (size_t)e*H,
                        ybuf + (size_t)off*H, cnt, nullptr);
}

// ---------------- flash attention, fp32 — EXACT R7 kernel (proven) ----------------
__global__ __launch_bounds__(256) void attn_kernel(
    const float* __restrict__ qbuf, const float* __restrict__ kbuf,
    const float* __restrict__ vbuf, float* __restrict__ ctx, int nq)
{
    __shared__ float Ks[KT][HD+4];
    __shared__ float VsT[HD][KT+4];
    __shared__ float qs[QT][HD+4];
    __shared__ float ps[QT][KT+4];
    int b = blockIdx.x, h = blockIdx.y, z = blockIdx.z;
    int qbase = z * QT;
    int nqt = nq - qbase;
    if (nqt <= 0) return;
    if (nqt > QT) nqt = QT;
    int tid = threadIdx.x, w = tid >> 6, lane = tid & 63;
    int off = SEQL - nq;
    for (int i = tid; i < QT*(HD/4); i += 256) {
        int row = i >> 4, c4 = (i & 15) << 2;
        float4 qv = make_float4(0.f,0.f,0.f,0.f);
        if (row < nqt) qv = *(const float4*)(qbuf + (size_t)(b*nq + qbase + row)*H + h*HD + c4);
        *(float4*)&qs[row][c4] = qv;
    }
    float m[QW], l[QW], acc[QW];
    #pragma unroll
    for (int i = 0; i < QW; ++i) { m[i] = -3e30f; l[i] = 0.f; acc[i] = 0.f; }
    int wq0 = w * QW;
    int wqn = nqt - wq0; if (wqn > QW) wqn = QW;
    int wmaxpos = qbase + wq0 + (wqn > 0 ? wqn - 1 : 0) + off;
    int ntiles = (qbase + nqt - 1 + off) / KT + 1;
    int q_sub = lane >> 3, kq = lane & 7;
    for (int t = 0; t < ntiles; ++t) {
        int kbase = t * KT;
        __syncthreads();
        for (int i = tid; i < KT*(HD/4); i += 256) {
            int row = i >> 4, c4 = (i & 15) << 2;
            int key = kbase + row;
            float4 kv = make_float4(0.f,0.f,0.f,0.f);
            if (key < SEQL) kv = *(const float4*)(kbuf + (size_t)(b*SEQL + key)*H + h*HD + c4);
            *(float4*)&Ks[row][c4] = kv;
        }
        {
            int key = kbase + lane;
            bool kval = key < SEQL;
            const float* vp = vbuf + (size_t)(b*SEQL + (kval ? key : 0))*H + h*HD;
            #pragma unroll
            for (int it = 0; it < 4; ++it) {
                int c4 = ((it << 2) + w) << 2;
                float4 vv = make_float4(0.f,0.f,0.f,0.f);
                if (kval) vv = *(const float4*)(vp + c4);
                VsT[c4+0][lane] = vv.x; VsT[c4+1][lane] = vv.y;
                VsT[c4+2][lane] = vv.z; VsT[c4+3][lane] = vv.w;
            }
        }
        __syncthreads();
        if (wqn > 0 && kbase <= wmaxpos) {
            float s[QW];
            #pragma unroll
            for (int qi = 0; qi < QW; ++qi) s[qi] = 0.f;
            #pragma unroll 4
            for (int d4 = 0; d4 < HD; d4 += 4) {
                float4 k4 = *(const float4*)&Ks[lane][d4];
                #pragma unroll
                for (int qi = 0; qi < QW; ++qi) {
                    float4 q4 = *(const float4*)&qs[wq0+qi][d4];
                    s[qi] += k4.x*q4.x + k4.y*q4.y + k4.z*q4.z + k4.w*q4.w;
                }
            }
            #pragma unroll
            for (int qi = 0; qi < QW; ++qi) {
                if (qi < wqn) {
                    int qpos = qbase + wq0 + qi + off;
                    bool valid = (kbase + lane) <= qpos;
                    ps[wq0+qi][lane] = valid ? s[qi]*0.125f : -3e30f;
                }
            }
            float mq = m[0];
            #pragma unroll
            for (int i = 1; i < QW; ++i) if (q_sub == i) mq = m[i];
            const float2* pr = (const float2*)&ps[wq0+q_sub][kq*8];
            float2 a0 = pr[0], a1 = pr[1], a2 = pr[2], a3 = pr[3];
            float mloc = fmaxf(fmaxf(fmaxf(a0.x,a0.y), fmaxf(a1.x,a1.y)),
                               fmaxf(fmaxf(a2.x,a2.y), fmaxf(a3.x,a3.y)));
            float tm = mloc;
            #pragma unroll
            for (int o = 1; o < 8; o <<= 1) tm = fmaxf(tm, __shfl_xor(tm, o, 64));
            float mn = fmaxf(mq, tm);
            float p0 = expf(a0.x-mn), p1 = expf(a0.y-mn), p2 = expf(a1.x-mn), p3 = expf(a1.y-mn);
            float p4 = expf(a2.x-mn), p5 = expf(a2.y-mn), p6 = expf(a3.x-mn), p7 = expf(a3.y-mn);
            float psum = ((p0+p1)+(p2+p3)) + ((p4+p5)+(p6+p7));
            #pragma unroll
            for (int o = 1; o < 8; o <<= 1) psum += __shfl_xor(psum, o, 64);
            float2* pw = (float2*)&ps[wq0+q_sub][kq*8];
            pw[0] = make_float2(p0,p1); pw[1] = make_float2(p2,p3);
            pw[2] = make_float2(p4,p5); pw[3] = make_float2(p6,p7);
            #pragma unroll
            for (int qi = 0; qi < QW; ++qi) {
                float tmv = __shfl(tm, qi*8, 64);
                float psv = __shfl(psum, qi*8, 64);
                if (qi < wqn) {
                    float mn2 = fmaxf(m[qi], tmv);
                    float scl = expf(m[qi] - mn2);
                    l[qi] = l[qi]*scl + psv;
                    acc[qi] *= scl;
                    m[qi] = mn2;
                }
            }
            #pragma unroll 4
            for (int k4 = 0; k4 < KT; k4 += 4) {
                float4 v4 = *(const float4*)&VsT[lane][k4];
                #pragma unroll
                for (int qi = 0; qi < QW; ++qi) {
                    if (qi < wqn) {
                        float4 p4v = *(const float4*)&ps[wq0+qi][k4];
                        acc[qi] += p4v.x*v4.x + p4v.y*v4.y + p4v.z*v4.z + p4v.w*v4.w;
                    }
                }
            }
        }
    }
    #pragma unroll
    for (int qi = 0; qi < QW; ++qi) {
        if (qi < wqn) {
            ctx[(size_t)(b*nq + qbase + wq0 + qi)*H + h*HD + lane] = acc[qi] / l[qi];
        }
    }
}

// ---------------- gate: logits + top-2 (no global atomics) ----------------
__global__ __launch_bounds__(256) void gate_kernel(
    const float* __restrict__ X, const float* __restrict__ gw, const float* __restrict__ gb,
    int* __restrict__ top_idx, float* __restrict__ top_w, int nrows)
{
    __shared__ float gl[NEXP];
    int n = blockIdx.x;
    int tid = threadIdx.x;
    int wv = tid >> 6, lane = tid & 63;
    float xv[4];
    #pragma unroll
    for (int c = 0; c < 4; ++c) xv[c] = X[(size_t)n*H + lane + (c<<6)];
    #pragma unroll
    for (int s = 0; s < 2; ++s) {
        int e = wv*2 + s;
        float acc = 0.f;
        #pragma unroll
        for (int c = 0; c < 4; ++c) acc += xv[c] * gw[(size_t)e*H + lane + (c<<6)];
        #pragma unroll
        for (int o = 32; o > 0; o >>= 1) acc += __shfl_xor(acc, o, 64);
        if (lane == 0) gl[e] = acc + gb[e];
    }
    __syncthreads();
    if (tid == 0) {
        int i0 = 0;
        for (int e = 1; e < NEXP; ++e) if (gl[e] > gl[i0]) i0 = e;
        int i1 = -1;
        for (int e = 0; e < NEXP; ++e) { if (e == i0) continue; if (i1 < 0 || gl[e] > gl[i1]) i1 = e; }
        float e1 = expf(gl[i1] - gl[i0]);
        float w0 = 1.f / (1.f + e1);
        top_idx[n*2+0] = i0; top_idx[n*2+1] = i1;
        top_w[n*2+0] = w0;  top_w[n*2+1] = 1.f - w0;
    }
}

// ---------------- count: LDS histogram ----------------
__global__ __launch_bounds__(256) void count_kernel(
    const int* __restrict__ top_idx, int* __restrict__ counts, int nrows)
{
    __shared__ int hist[NEXP];
    int tid = threadIdx.x;
    if (tid < NEXP) hist[tid] = 0;
    __syncthreads();
    int n = blockIdx.x * 256 + tid;
    if (n < nrows) {
        atomicAdd(&hist[top_idx[n*2+0]], 1);
        atomicAdd(&hist[top_idx[n*2+1]], 1);
    }
    __syncthreads();
    if (tid < NEXP && hist[tid] > 0) atomicAdd(&counts[tid], hist[tid]);
}

__global__ void scan_kernel(const int* __restrict__ counts, int* __restrict__ offsets,
                            int* __restrict__ cursor)
{
    int s = 0;
    for (int e = 0; e < NEXP; ++e) { offsets[e] = s; cursor[e] = s; s += counts[e]; }
}

// ---------------- block-aggregated scatter (+ inverse map tok_pair) ----------------
__global__ __launch_bounds__(256) void scatter_kernel(
    const int* __restrict__ top_idx,
    int* __restrict__ cursor, int* __restrict__ pair_tok, int* __restrict__ tok_pair, int nrows)
{
    __shared__ int lcnt[NEXP];
    __shared__ int lbase[NEXP];
    int tid = threadIdx.x;
    if (tid < NEXP) lcnt[tid] = 0;
    __syncthreads();
    int n = blockIdx.x * 256 + tid;
    int e0 = 0, e1 = 0, p0 = 0, p1 = 0;
    bool act = n < nrows;
    if (act) {
        e0 = top_idx[n*2+0]; e1 = top_idx[n*2+1];
        p0 = atomicAdd(&lcnt[e0], 1);
        p1 = atomicAdd(&lcnt[e1], 1);
    }
    __syncthreads();
    if (tid < NEXP) lbase[tid] = (lcnt[tid] > 0) ? atomicAdd(&cursor[tid], lcnt[tid]) : 0;
    __syncthreads();
    if (act) {
        int q0 = lbase[e0] + p0, q1 = lbase[e1] + p1;
        pair_tok[q0] = n; pair_tok[q1] = n;
        tok_pair[n*2+0] = q0; tok_pair[n*2+1] = q1;
    }
}

// ---------------- small MoE GEMMs (64-tile, proven) for block-1 sized problems ----------
__global__ __launch_bounds__(256) void moe_gemm1(
    const float* __restrict__ X, const float* __restrict__ W1base,
    const float* __restrict__ b1base, const int* __restrict__ pair_tok,
    const int* __restrict__ offsets, const int* __restrict__ counts,
    float* __restrict__ hbuf)
{
    int e = blockIdx.z;
    int cnt = counts[e];
    int r0 = blockIdx.x * 64;
    if (r0 >= cnt) return;
    int off = offsets[e];
    int c0 = blockIdx.y * 64;
    const float* W = W1base + (size_t)e * H * H;
    const float* bias = b1base + (size_t)e * H;
    __shared__ float As[16][68];
    __shared__ float Bs[16][68];
    int tid = threadIdx.x, tx = tid & 15, ty = tid >> 4;
    int lrow = tid >> 2, lkg = (tid & 3) << 2;
    float acc[4][4] = {};
    for (int kk = 0; kk < H; kk += 16) {
        float4 av = make_float4(0.f,0.f,0.f,0.f);
        int pr = r0 + lrow;
        if (pr < cnt) {
            int tok = pair_tok[off + pr];
            av = *(const float4*)(X + (size_t)tok*H + kk + lkg);
        }
        As[lkg+0][lrow]=av.x; As[lkg+1][lrow]=av.y; As[lkg+2][lrow]=av.z; As[lkg+3][lrow]=av.w;
        float4 wv = *(const float4*)(W + (size_t)(kk+ty)*H + c0 + (tx<<2));
        *(float4*)&Bs[ty][tx<<2] = wv;
        __syncthreads();
        #pragma unroll
        for (int k = 0; k < 16; ++k) {
            float4 a = *(const float4*)&As[k][ty<<2];
            float4 bv = *(const float4*)&Bs[k][tx<<2];
            float aa[4] = {a.x,a.y,a.z,a.w};
            float bb[4] = {bv.x,bv.y,bv.z,bv.w};
            #pragma unroll
            for (int ii = 0; ii < 4; ++ii)
                #pragma unroll
                for (int jj = 0; jj < 4; ++jj)
                    acc[ii][jj] += aa[ii] * bb[jj];
        }
        __syncthreads();
    }
    #pragma unroll
    for (int ii = 0; ii < 4; ++ii) {
        int pr = r0 + (ty<<2) + ii;
        if (pr < cnt) {
            #pragma unroll
            for (int jj = 0; jj < 4; ++jj) {
                int gc = c0 + (tx<<2) + jj;
                hbuf[(size_t)(off+pr)*H + gc] = fmaxf(acc[ii][jj] + bias[gc], 0.f);
            }
        }
    }
}

__global__ __launch_bounds__(256) void moe_gemm2(
    const float* __restrict__ Hbuf, const float* __restrict__ W2base,
    const float* __restrict__ b2base, const int* __restrict__ offsets,
    const int* __restrict__ counts, float* __restrict__ ybuf)
{
    int e = blockIdx.z;
    int cnt = counts[e];
    int r0 = blockIdx.x * 64;
    if (r0 >= cnt) return;
    int off = offsets[e];
    int c0 = blockIdx.y * 64;
    const float* W = W2base + (size_t)e * H * H;
    const float* bias = b2base + (size_t)e * H;
    __shared__ float As[16][68];
    __shared__ float Bs[16][68];
    int tid = threadIdx.x, tx = tid & 15, ty = tid >> 4;
    int lrow = tid >> 2, lkg = (tid & 3) << 2;
    float acc[4][4] = {};
    for (int kk = 0; kk < H; kk += 16) {
        float4 av = make_float4(0.f,0.f,0.f,0.f);
        int pr = r0 + lrow;
        if (pr < cnt) av = *(const float4*)(Hbuf + (size_t)(off+pr)*H + kk + lkg);
        As[lkg+0][lrow]=av.x; As[lkg+1][lrow]=av.y; As[lkg+2][lrow]=av.z; As[lkg+3][lrow]=av.w;
        float4 wv = *(const float4*)(W + (size_t)(kk+ty)*H + c0 + (tx<<2));
        *(float4*)&Bs[ty][tx<<2] = wv;
        __syncthreads();
        #pragma unroll
        for (int k = 0; k < 16; ++k) {
            float4 a = *(const float4*)&As[k][ty<<2];
            float4 bv = *(const float4*)&Bs[k][tx<<2];
            float aa[4] = {a.x,a.y,a.z,a.w};
            float bb[4] = {bv.x,bv.y,bv.z,bv.w};
            #pragma unroll
            for (int ii = 0; ii < 4; ++ii)
                #pragma unroll
                for (int jj = 0; jj < 4; ++jj)
                    acc[ii][jj] += aa[ii] * bb[jj];
        }
        __syncthreads();
    }
    #pragma unroll
    for (int ii = 0; ii < 4; ++ii) {
        int pr = r0 + (ty<<2) + ii;
        if (pr < cnt) {
            #pragma unroll
            for (int jj = 0; jj < 4; ++jj) {
                int gc = c0 + (tx<<2) + jj;
                ybuf[(size_t)(off+pr)*H + gc] = acc[ii][jj] + bias[gc];
            }
        }
    }
}

__global__ void zero_kernel(float* __restrict__ p, int n) {
    int i = blockIdx.x * 256 + threadIdx.x;
    if (i < n) p[i] = 0.f;
}

// ---------------- final: LN + user emb + dot(item emb) ----------------
__global__ __launch_bounds__(256) void final_kernel(
    const float* __restrict__ xf, const float* __restrict__ lnw, const float* __restrict__ lnb,
    const float* __restrict__ user_emb, const float* __restrict__ item_emb,
    const int* __restrict__ user_ids, const int* __restrict__ item_ids, float* __restrict__ out)
{
    __shared__ float s4[4];
    int bb = blockIdx.x, t = threadIdx.x;
    float v = xf[(size_t)bb*H + t];
    float mean = blk_sum256(v, s4) * (1.f/H);
    float d = v - mean;
    float var = blk_sum256(d*d, s4) * (1.f/H);
    float lnv = d * rsqrtf(var + 1e-8f) * lnw[t] + lnb[t];
    float fin = lnv + user_emb[(size_t)user_ids[bb]*H + t];
    float prod = fin * item_emb[(size_t)item_ids[bb]*H + t];
    float tot = blk_sum256(prod, s4);
    if (t == 0) out[bb] = tot;
}

// ---------------- launch ----------------
extern "C" void kernel_launch(void* const* d_in, const int* in_sizes, int n_in,
                              void* d_out, int out_size, void* d_ws, size_t ws_size,
                              hipStream_t stream)
{
    (void)in_sizes; (void)n_in; (void)out_size; (void)ws_size;
    const int*   user_ids  = (const int*)d_in[0];
    const int*   log_seqs  = (const int*)d_in[1];
    const int*   item_ids  = (const int*)d_in[2];
    const float* item_emb  = (const float*)d_in[3];
    const float* pos_emb   = (const float*)d_in[4];
    const float* user_emb  = (const float*)d_in[5];
    const float* ln1_w     = (const float*)d_in[6];
    const float* ln1_b     = (const float*)d_in[7];
    const float* inproj_w  = (const float*)d_in[8];
    const float* inproj_b  = (const float*)d_in[9];
    const float* outproj_w = (const float*)d_in[10];
    const float* outproj_b = (const float*)d_in[11];
    const float* ln2_w     = (const float*)d_in[12];
    const float* ln2_b     = (const float*)d_in[13];
    const float* gate_w    = (const float*)d_in[14];
    const float* gate_b    = (const float*)d_in[15];
    const float* e_w1      = (const float*)d_in[16];
    const float* e_b1      = (const float*)d_in[17];
    const float* e_w2      = (const float*)d_in[18];
    const float* e_b2      = (const float*)d_in[19];
    const float* moeln_w   = (const float*)d_in[20];
    const float* moeln_b   = (const float*)d_in[21];
    const float* lastln_w  = (const float*)d_in[22];
    const float* lastln_b  = (const float*)d_in[23];

    float* ws = (float*)d_ws;
    const size_t NFH = (size_t)NF * H;
    float* buf0 = ws;
    float* buf1 = buf0 + NFH;   // buf1+buf2 contiguous -> ybuf region (2*NF rows)
    float* buf2 = buf1 + NFH;
    float* buf3 = buf2 + NFH;   // buf3+buf4 contiguous -> MoE h region (2*NF rows)
    float* buf4 = buf3 + NFH;
    float* s0   = buf4 + NFH;
    float* s1   = s0 + (size_t)BATCH*H;
    float* s2   = s1 + (size_t)BATCH*H;
    float* s3   = s2 + (size_t)BATCH*H;
    float* s6   = s3 + (size_t)BATCH*H;
    float* s4   = s6 + (size_t)BATCH*H;            // 2*BATCH rows (h)
    float* s5   = s4 + (size_t)2*BATCH*H;          // 2*BATCH rows (y)
    float* top_w   = s5 + (size_t)2*BATCH*H;
    int*   top_idx = (int*)(top_w + (size_t)NF*2);
    int*   pair_tok= top_idx + (size_t)NF*2;
    int*   tok_pair= pair_tok + (size_t)NF*2;
    int*   counts  = tok_pair + (size_t)NF*2;
    int*   offsets = counts + NEXP;
    int*   cursor  = offsets + NEXP;

    dim3 blk(256);
    dim3 g128((NF+127)/128, H/128);
    dim3 gsmall((BATCH+63)/64, H/64);
    dim3 m128((NF+127)/128, H/128, NEXP);
    dim3 msmall((BATCH+63)/64, H/64, NEXP);

    embed_kernel<<<NF, blk, 0, stream>>>(log_seqs, item_emb, pos_emb, buf0);

    // ================= block 0 : full sequence =================
    {
        const int i = 0;
        const float* Wq = inproj_w + (size_t)i*3*H*H;
        const float* Wk = Wq + (size_t)H*H;
        const float* Wv = Wk + (size_t)H*H;
        const float* bq = inproj_b + (size_t)i*3*H;
        ln_kernel<<<NF, blk, 0, stream>>>(buf0, nullptr, buf1, ln1_w + i*H, ln1_b + i*H, 1e-8f, 0, 1);
        gemm_nt128<<<g128, blk, 0, stream>>>(buf1, Wq, bq,       buf2, NF);   // q
        gemm_nt128<<<g128, blk, 0, stream>>>(buf0, Wk, bq + H,   buf3, NF);   // k
        gemm_nt128<<<g128, blk, 0, stream>>>(buf0, Wv, bq + 2*H, buf4, NF);   // v
        attn_kernel<<<dim3(BATCH, NHEAD, (SEQL+QT-1)/QT), blk, 0, stream>>>(buf2, buf3, buf4, buf2, SEQL);
        gemm_nt128<<<g128, blk, 0, stream>>>(buf2, outproj_w + (size_t)i*H*H, outproj_b + i*H, buf3, NF);
        ln_kernel<<<NF, blk, 0, stream>>>(buf1, buf3, buf0, ln2_w + i*H, ln2_b + i*H, 1e-8f, 0, 1);
        zero_kernel<<<1, 32, 0, stream>>>((float*)counts, NEXP);
        gate_kernel<<<NF, blk, 0, stream>>>(buf0, gate_w + (size_t)i*NEXP*H, gate_b + i*NEXP,
                                            top_idx, top_w, NF);
        count_kernel<<<(NF+255)/256, blk, 0, stream>>>(top_idx, counts, NF);
        scan_kernel<<<1, 1, 0, stream>>>(counts, offsets, cursor);
        scatter_kernel<<<(NF+255)/256, blk, 0, stream>>>(top_idx, cursor, pair_tok, tok_pair, NF);
        moe1_128<<<m128, blk, 0, stream>>>(buf0, e_w1 + (size_t)i*NEXP*H*H, e_b1 + (size_t)i*NEXP*H,
                                           pair_tok, offsets, counts, buf3);
        moe2_128<<<m128, blk, 0, stream>>>(buf3, e_w2 + (size_t)i*NEXP*H*H, e_b2 + (size_t)i*NEXP*H,
                                           offsets, counts, buf1);
        moe_ln_kernel<<<NF, blk, 0, stream>>>(buf0, buf1, tok_pair, top_w, buf3,
                                              moeln_w + i*H, moeln_b + i*H, 1e-5f);
    }

    // ================= block 1 : only last position matters downstream =================
    {
        const int i = 1;
        const float* Wq = inproj_w + (size_t)i*3*H*H;
        const float* Wk = Wq + (size_t)H*H;
        const float* Wv = Wk + (size_t)H*H;
        const float* bq = inproj_b + (size_t)i*3*H;
        float* X = buf3;
        ln_kernel<<<BATCH, blk, 0, stream>>>(X, nullptr, s0, ln1_w + i*H, ln1_b + i*H, 1e-8f, SEQL-1, SEQL);
        gemm_nt<<<gsmall, blk, 0, stream>>>(s0, Wq, bq, s1, BATCH);            // q (last rows only)
        gemm_nt128<<<g128, blk, 0, stream>>>(X, Wk, bq + H,   buf0, NF);       // k (full)
        gemm_nt128<<<g128, blk, 0, stream>>>(X, Wv, bq + 2*H, buf1, NF);       // v (full)
        attn_kernel<<<dim3(BATCH, NHEAD, 1), blk, 0, stream>>>(s1, buf0, buf1, s2, 1);
        gemm_nt<<<gsmall, blk, 0, stream>>>(s2, outproj_w + (size_t)i*H*H, outproj_b + i*H, s3, BATCH);
        ln_kernel<<<BATCH, blk, 0, stream>>>(s0, s3, s2, ln2_w + i*H, ln2_b + i*H, 1e-8f, 0, 1);
        zero_kernel<<<1, 32, 0, stream>>>((float*)counts, NEXP);
        gate_kernel<<<BATCH, blk, 0, stream>>>(s2, gate_w + (size_t)i*NEXP*H, gate_b + i*NEXP,
                                               top_idx, top_w, BATCH);
        count_kernel<<<1, blk, 0, stream>>>(top_idx, counts, BATCH);
        scan_kernel<<<1, 1, 0, stream>>>(counts, offsets, cursor);
        scatter_kernel<<<1, blk, 0, stream>>>(top_idx, cursor, pair_tok, tok_pair, BATCH);
        moe_gemm1<<<msmall, blk, 0, stream>>>(s2, e_w1 + (size_t)i*NEXP*H*H, e_b1 + (size_t)i*NEXP*H,
                                              pair_tok, offsets, counts, s4);
        moe_gemm2<<<msmall, blk, 0, stream>>>(s4, e_w2 + (size_t)i*NEXP*H*H, e_b2 + (size_t)i*NEXP*H,
                                              offsets, counts, s5);
        moe_ln_kernel<<<BATCH, blk, 0, stream>>>(s2, s5, tok_pair, top_w, s6,
                                                 moeln_w + i*H, moeln_b + i*H, 1e-5f);
    }

    final_kernel<<<BATCH, blk, 0, stream>>>(s6, lastln_w, lastln_b, user_emb, item_emb,
                                            user_ids, item_ids, (float*)d_out);
}

// Round 12
// 885.749 us; speedup vs baseline: 2.1548x; 1.0189x over previous
//
#include <hip/hip_runtime.h>
#include <math.h>

#define H 256
#define NHEAD 4
#define HD 64
#define NEXP 8
#define SEQL 200
#define BATCH 128
#define NF (BATCH*SEQL)
#define KT 64
#define QT 64
#define QW 8   // queries per wave (8 waves x 8 q = QT)

// ---------------- helpers ----------------
__device__ __forceinline__ float blk_sum256(float v, float* s4) {
    #pragma unroll
    for (int o = 32; o > 0; o >>= 1) v += __shfl_xor(v, o, 64);
    __syncthreads();
    if ((threadIdx.x & 63) == 0) s4[threadIdx.x >> 6] = v;
    __syncthreads();
    return s4[0] + s4[1] + s4[2] + s4[3];
}

// ---------------- embedding ----------------
__global__ __launch_bounds__(256) void embed_kernel(
    const int* __restrict__ seqs, const float* __restrict__ item_emb,
    const float* __restrict__ pos_emb, float* __restrict__ x)
{
    int n = blockIdx.x, t = threadIdx.x;
    int id = seqs[n];
    int pos = (id != 0) ? (n % SEQL) + 1 : 0;
    x[(size_t)n*H + t] = item_emb[(size_t)id*H + t] * 16.0f + pos_emb[(size_t)pos*H + t];
}

// ---------------- layernorm (gather + optional residual) ----------------
__global__ __launch_bounds__(256) void ln_kernel(
    const float* __restrict__ in, const float* __restrict__ res,
    float* __restrict__ out, const float* __restrict__ w, const float* __restrict__ b,
    float eps, int base, int step)
{
    __shared__ float s4[4];
    int r = blockIdx.x, t = threadIdx.x;
    float v = in[(size_t)(base + r*step)*H + t];
    if (res) v += res[(size_t)r*H + t];
    float mean = blk_sum256(v, s4) * (1.f/H);
    float d = v - mean;
    float var = blk_sum256(d*d, s4) * (1.f/H);
    out[(size_t)r*H + t] = d * rsqrtf(var + eps) * w[t] + b[t];
}

// ---------------- fused moe combine + layernorm ----------------
__global__ __launch_bounds__(256) void moe_ln_kernel(
    const float* __restrict__ x, const float* __restrict__ ybuf,
    const int* __restrict__ tok_pair, const float* __restrict__ top_w,
    float* __restrict__ out, const float* __restrict__ w, const float* __restrict__ b,
    float eps)
{
    __shared__ float s4[4];
    int r = blockIdx.x, t = threadIdx.x;
    int p0 = tok_pair[r*2], p1 = tok_pair[r*2+1];
    float v = x[(size_t)r*H + t]
            + top_w[r*2+0] * ybuf[(size_t)p0*H + t]
            + top_w[r*2+1] * ybuf[(size_t)p1*H + t];
    float mean = blk_sum256(v, s4) * (1.f/H);
    float d = v - mean;
    float var = blk_sum256(d*d, s4) * (1.f/H);
    out[(size_t)r*H + t] = d * rsqrtf(var + eps) * w[t] + b[t];
}

// ---------------- GEMM (64x64 tile) — proven bit-path ----------------
__global__ __launch_bounds__(256) void gemm_nt(
    const float* __restrict__ A, const float* __restrict__ W,
    const float* __restrict__ bias, float* __restrict__ out, int nrows)
{
    __shared__ float As[16][68];
    __shared__ float Ws[16][68];
    int r0 = blockIdx.x * 64;
    if (r0 >= nrows) return;
    int c0 = blockIdx.y * 64;
    int tid = threadIdx.x;
    int tx = tid & 15, ty = tid >> 4;
    int lrow = tid >> 2, lkg = (tid & 3) << 2;
    float acc[4][4] = {};
    for (int kk = 0; kk < H; kk += 16) {
        float4 av = make_float4(0.f,0.f,0.f,0.f);
        int gr = r0 + lrow;
        if (gr < nrows) av = *(const float4*)(A + (size_t)gr*H + kk + lkg);
        As[lkg+0][lrow]=av.x; As[lkg+1][lrow]=av.y; As[lkg+2][lrow]=av.z; As[lkg+3][lrow]=av.w;
        float4 wv = *(const float4*)(W + (size_t)(c0+lrow)*H + kk + lkg);
        Ws[lkg+0][lrow]=wv.x; Ws[lkg+1][lrow]=wv.y; Ws[lkg+2][lrow]=wv.z; Ws[lkg+3][lrow]=wv.w;
        __syncthreads();
        #pragma unroll
        for (int k = 0; k < 16; ++k) {
            float4 a = *(const float4*)&As[k][ty<<2];
            float4 bv = *(const float4*)&Ws[k][tx<<2];
            float aa[4] = {a.x,a.y,a.z,a.w};
            float bb[4] = {bv.x,bv.y,bv.z,bv.w};
            #pragma unroll
            for (int ii = 0; ii < 4; ++ii)
                #pragma unroll
                for (int jj = 0; jj < 4; ++jj)
                    acc[ii][jj] += aa[ii] * bb[jj];
        }
        __syncthreads();
    }
    #pragma unroll
    for (int ii = 0; ii < 4; ++ii) {
        int gr = r0 + (ty<<2) + ii;
        if (gr < nrows) {
            #pragma unroll
            for (int jj = 0; jj < 4; ++jj) {
                int gc = c0 + (tx<<2) + jj;
                out[(size_t)gr*H + gc] = acc[ii][jj] + bias[gc];
            }
        }
    }
}

// ---------------- 128x128 GEMM body (proven R11) ----------------
template<int GATHER, int RELU, int BT>
__device__ __forceinline__ void gemm128_body(
    const float* __restrict__ A, const float* __restrict__ W,
    const float* __restrict__ bias, float* __restrict__ out, int nrows,
    const int* __restrict__ pair_tok)
{
    __shared__ float As[16][132];
    __shared__ float Ws[16][132];
    int r0 = blockIdx.x * 128;
    if (r0 >= nrows) return;
    int c0 = blockIdx.y * 128;
    int tid = threadIdx.x;
    int tx = tid & 15, ty = tid >> 4;
    int lrow = tid >> 1, lkg = (tid & 1) << 3;
    int ar = r0 + lrow;
    bool va = ar < nrows;
    int ga = ar;
    if (GATHER) ga = va ? pair_tok[r0 + lrow] : 0;
    const float* ap = A + (size_t)(va ? ga : 0)*H + lkg;
    const float* wpT = W + (size_t)(c0 + lrow)*H + lkg;
    int kr0 = tid >> 5, cg = (tid & 31) << 2;
    const float* wpN0 = W + (size_t)kr0*H + c0 + cg;
    const float* wpN1 = wpN0 + (size_t)8*H;
    float acc[8][8] = {};
    for (int kk = 0; kk < H; kk += 16) {
        float4 av0 = make_float4(0.f,0.f,0.f,0.f), av1 = av0;
        if (va) { av0 = *(const float4*)(ap + kk); av1 = *(const float4*)(ap + kk + 4); }
        float4 wv0, wv1;
        if (BT) {
            wv0 = *(const float4*)(wpT + kk);
            wv1 = *(const float4*)(wpT + kk + 4);
        } else {
            wv0 = *(const float4*)(wpN0 + (size_t)kk*H);
            wv1 = *(const float4*)(wpN1 + (size_t)kk*H);
        }
        __syncthreads();
        As[lkg+0][lrow]=av0.x; As[lkg+1][lrow]=av0.y; As[lkg+2][lrow]=av0.z; As[lkg+3][lrow]=av0.w;
        As[lkg+4][lrow]=av1.x; As[lkg+5][lrow]=av1.y; As[lkg+6][lrow]=av1.z; As[lkg+7][lrow]=av1.w;
        if (BT) {
            Ws[lkg+0][lrow]=wv0.x; Ws[lkg+1][lrow]=wv0.y; Ws[lkg+2][lrow]=wv0.z; Ws[lkg+3][lrow]=wv0.w;
            Ws[lkg+4][lrow]=wv1.x; Ws[lkg+5][lrow]=wv1.y; Ws[lkg+6][lrow]=wv1.z; Ws[lkg+7][lrow]=wv1.w;
        } else {
            *(float4*)&Ws[kr0][cg]     = wv0;
            *(float4*)&Ws[kr0 + 8][cg] = wv1;
        }
        __syncthreads();
        #pragma unroll
        for (int k = 0; k < 16; ++k) {
            float4 a0 = *(const float4*)&As[k][ty<<2];
            float4 a1 = *(const float4*)&As[k][64 + (ty<<2)];
            float4 b0 = *(const float4*)&Ws[k][tx<<2];
            float4 b1 = *(const float4*)&Ws[k][64 + (tx<<2)];
            float aa[8] = {a0.x,a0.y,a0.z,a0.w,a1.x,a1.y,a1.z,a1.w};
            float bb[8] = {b0.x,b0.y,b0.z,b0.w,b1.x,b1.y,b1.z,b1.w};
            #pragma unroll
            for (int ii = 0; ii < 8; ++ii)
                #pragma unroll
                for (int jj = 0; jj < 8; ++jj)
                    acc[ii][jj] += aa[ii] * bb[jj];
        }
    }
    #pragma unroll
    for (int hr = 0; hr < 2; ++hr)
        #pragma unroll
        for (int ii = 0; ii < 4; ++ii) {
            int row = r0 + 64*hr + (ty<<2) + ii;
            if (row < nrows) {
                #pragma unroll
                for (int hc = 0; hc < 2; ++hc) {
                    int col = c0 + 64*hc + (tx<<2);
                    #pragma unroll
                    for (int jj = 0; jj < 4; ++jj) {
                        float o = acc[4*hr+ii][4*hc+jj] + bias[col+jj];
                        if (RELU) o = fmaxf(o, 0.f);
                        out[(size_t)row*H + col + jj] = o;
                    }
                }
            }
        }
}

__global__ __launch_bounds__(256) void gemm_nt128(
    const float* __restrict__ A, const float* __restrict__ W,
    const float* __restrict__ bias, float* __restrict__ out, int nrows)
{
    gemm128_body<0,0,1>(A, W, bias, out, nrows, nullptr);
}

__global__ __launch_bounds__(256) void moe1_128(
    const float* __restrict__ X, const float* __restrict__ W1base,
    const float* __restrict__ b1base, const int* __restrict__ pair_tok,
    const int* __restrict__ offsets, const int* __restrict__ counts,
    float* __restrict__ hbuf)
{
    int e = blockIdx.z;
    int cnt = counts[e], off = offsets[e];
    gemm128_body<1,1,0>(X, W1base + (size_t)e*H*H, b1base + (size_t)e*H,
                        hbuf + (size_t)off*H, cnt, pair_tok + off);
}

__global__ __launch_bounds__(256) void moe2_128(
    const float* __restrict__ Hbuf, const float* __restrict__ W2base,
    const float* __restrict__ b2base, const int* __restrict__ offsets,
    const int* __restrict__ counts, float* __restrict__ ybuf)
{
    int e = blockIdx.z;
    int cnt = counts[e], off = offsets[e];
    gemm128_body<0,0,0>(Hbuf + (size_t)off*H, W2base + (size_t)e*H*H, b2base + (size_t)e*H,
                        ybuf + (size_t)off*H, cnt, nullptr);
}

// ---------------- flash attention, fp32: QT=64, 8 waves, K/V time-shared LDS ----------
// Per-query arithmetic identical to R7/R11 (same tile order, same reductions).
__global__ __launch_bounds__(512) void attn_kernel(
    const float* __restrict__ qbuf, const float* __restrict__ kbuf,
    const float* __restrict__ vbuf, float* __restrict__ ctx, int nq)
{
    __shared__ float kv[KT*(HD+4)];     // K: kv[row*68+d] ; V^T: kv[d*68+key]
    __shared__ float qs[QT][HD+4];
    __shared__ float ps[QT][KT+4];
    int b = blockIdx.x, h = blockIdx.y, z = blockIdx.z;
    int qbase = z * QT;
    int nqt = nq - qbase;
    if (nqt <= 0) return;
    if (nqt > QT) nqt = QT;
    int tid = threadIdx.x, w = tid >> 6, lane = tid & 63;   // w in 0..7
    int off = SEQL - nq;
    for (int i = tid; i < QT*(HD/4); i += 512) {
        int row = i >> 4, c4 = (i & 15) << 2;
        float4 qv = make_float4(0.f,0.f,0.f,0.f);
        if (row < nqt) qv = *(const float4*)(qbuf + (size_t)(b*nq + qbase + row)*H + h*HD + c4);
        *(float4*)&qs[row][c4] = qv;
    }
    float m[QW], l[QW], acc[QW];
    #pragma unroll
    for (int i = 0; i < QW; ++i) { m[i] = -3e30f; l[i] = 0.f; acc[i] = 0.f; }
    int wq0 = w * QW;
    int wqn = nqt - wq0; if (wqn > QW) wqn = QW;    // may be <= 0 (idle wave)
    int wmaxpos = qbase + wq0 + (wqn > 0 ? wqn - 1 : 0) + off;
    int ntiles = (qbase + nqt - 1 + off) / KT + 1;
    int q_sub = lane >> 3, kq = lane & 7;
    for (int t = 0; t < ntiles; ++t) {
        int kbase = t * KT;
        bool active = (wqn > 0) && (kbase <= wmaxpos);
        __syncthreads();                 // prev PV (and qs stage at t=0) complete
        // ---- stage K rows ----
        for (int i = tid; i < KT*(HD/4); i += 512) {
            int row = i >> 4, c4 = (i & 15) << 2;
            int key = kbase + row;
            float4 kvv = make_float4(0.f,0.f,0.f,0.f);
            if (key < SEQL) kvv = *(const float4*)(kbuf + (size_t)(b*SEQL + key)*H + h*HD + c4);
            *(float4*)&kv[row*(HD+4) + c4] = kvv;
        }
        __syncthreads();
        // ---- phase 1: scores, lane = key ----
        if (active) {
            float s[QW];
            #pragma unroll
            for (int qi = 0; qi < QW; ++qi) s[qi] = 0.f;
            #pragma unroll 4
            for (int d4 = 0; d4 < HD; d4 += 4) {
                float4 k4 = *(const float4*)&kv[lane*(HD+4) + d4];
                #pragma unroll
                for (int qi = 0; qi < QW; ++qi) {
                    float4 q4 = *(const float4*)&qs[wq0+qi][d4];
                    s[qi] += k4.x*q4.x + k4.y*q4.y + k4.z*q4.z + k4.w*q4.w;
                }
            }
            #pragma unroll
            for (int qi = 0; qi < QW; ++qi) {
                if (qi < wqn) {
                    int qpos = qbase + wq0 + qi + off;
                    bool valid = (kbase + lane) <= qpos;
                    ps[wq0+qi][lane] = valid ? s[qi]*0.125f : -3e30f;
                }
            }
        }
        __syncthreads();                 // scores done reading K from kv
        // ---- stage V transposed into same buffer ----
        {
            int key = kbase + lane;
            bool kval = key < SEQL;
            const float* vp = vbuf + (size_t)(b*SEQL + (kval ? key : 0))*H + h*HD;
            #pragma unroll
            for (int it = 0; it < 2; ++it) {
                int c4 = ((it << 3) + w) << 2;
                float4 vv = make_float4(0.f,0.f,0.f,0.f);
                if (kval) vv = *(const float4*)(vp + c4);
                kv[(c4+0)*(KT+4) + lane] = vv.x;
                kv[(c4+1)*(KT+4) + lane] = vv.y;
                kv[(c4+2)*(KT+4) + lane] = vv.z;
                kv[(c4+3)*(KT+4) + lane] = vv.w;
            }
        }
        __syncthreads();
        if (active) {
            // ---- phase 2: transposed softmax ----
            float mq = m[0];
            #pragma unroll
            for (int i = 1; i < QW; ++i) if (q_sub == i) mq = m[i];
            const float2* pr = (const float2*)&ps[wq0+q_sub][kq*8];
            float2 a0 = pr[0], a1 = pr[1], a2 = pr[2], a3 = pr[3];
            float mloc = fmaxf(fmaxf(fmaxf(a0.x,a0.y), fmaxf(a1.x,a1.y)),
                               fmaxf(fmaxf(a2.x,a2.y), fmaxf(a3.x,a3.y)));
            float tm = mloc;
            #pragma unroll
            for (int o = 1; o < 8; o <<= 1) tm = fmaxf(tm, __shfl_xor(tm, o, 64));
            float mn = fmaxf(mq, tm);
            float p0 = expf(a0.x-mn), p1 = expf(a0.y-mn), p2 = expf(a1.x-mn), p3 = expf(a1.y-mn);
            float p4 = expf(a2.x-mn), p5 = expf(a2.y-mn), p6 = expf(a3.x-mn), p7 = expf(a3.y-mn);
            float psum = ((p0+p1)+(p2+p3)) + ((p4+p5)+(p6+p7));
            #pragma unroll
            for (int o = 1; o < 8; o <<= 1) psum += __shfl_xor(psum, o, 64);
            float2* pw = (float2*)&ps[wq0+q_sub][kq*8];
            pw[0] = make_float2(p0,p1); pw[1] = make_float2(p2,p3);
            pw[2] = make_float2(p4,p5); pw[3] = make_float2(p6,p7);
            #pragma unroll
            for (int qi = 0; qi < QW; ++qi) {
                float tmv = __shfl(tm, qi*8, 64);
                float psv = __shfl(psum, qi*8, 64);
                if (qi < wqn) {
                    float mn2 = fmaxf(m[qi], tmv);
                    float scl = expf(m[qi] - mn2);
                    l[qi] = l[qi]*scl + psv;
                    acc[qi] *= scl;
                    m[qi] = mn2;
                }
            }
            // ---- phase 3: PV, lane = dim ----
            #pragma unroll 4
            for (int k4 = 0; k4 < KT; k4 += 4) {
                float4 v4 = *(const float4*)&kv[lane*(KT+4) + k4];
                #pragma unroll
                for (int qi = 0; qi < QW; ++qi) {
                    if (qi < wqn) {
                        float4 p4v = *(const float4*)&ps[wq0+qi][k4];
                        acc[qi] += p4v.x*v4.x + p4v.y*v4.y + p4v.z*v4.z + p4v.w*v4.w;
                    }
                }
            }
        }
    }
    #pragma unroll
    for (int qi = 0; qi < QW; ++qi) {
        if (qi < wqn) {
            ctx[(size_t)(b*nq + qbase + wq0 + qi)*H + h*HD + lane] = acc[qi] / l[qi];
        }
    }
}

// ---------------- gate: logits + top-2 (no global atomics) ----------------
__global__ __launch_bounds__(256) void gate_kernel(
    const float* __restrict__ X, const float* __restrict__ gw, const float* __restrict__ gb,
    int* __restrict__ top_idx, float* __restrict__ top_w, int nrows)
{
    __shared__ float gl[NEXP];
    int n = blockIdx.x;
    int tid = threadIdx.x;
    int wv = tid >> 6, lane = tid & 63;
    float xv[4];
    #pragma unroll
    for (int c = 0; c < 4; ++c) xv[c] = X[(size_t)n*H + lane + (c<<6)];
    #pragma unroll
    for (int s = 0; s < 2; ++s) {
        int e = wv*2 + s;
        float acc = 0.f;
        #pragma unroll
        for (int c = 0; c < 4; ++c) acc += xv[c] * gw[(size_t)e*H + lane + (c<<6)];
        #pragma unroll
        for (int o = 32; o > 0; o >>= 1) acc += __shfl_xor(acc, o, 64);
        if (lane == 0) gl[e] = acc + gb[e];
    }
    __syncthreads();
    if (tid == 0) {
        int i0 = 0;
        for (int e = 1; e < NEXP; ++e) if (gl[e] > gl[i0]) i0 = e;
        int i1 = -1;
        for (int e = 0; e < NEXP; ++e) { if (e == i0) continue; if (i1 < 0 || gl[e] > gl[i1]) i1 = e; }
        float e1 = expf(gl[i1] - gl[i0]);
        float w0 = 1.f / (1.f + e1);
        top_idx[n*2+0] = i0; top_idx[n*2+1] = i1;
        top_w[n*2+0] = w0;  top_w[n*2+1] = 1.f - w0;
    }
}

// ---------------- count: LDS histogram ----------------
__global__ __launch_bounds__(256) void count_kernel(
    const int* __restrict__ top_idx, int* __restrict__ counts, int nrows)
{
    __shared__ int hist[NEXP];
    int tid = threadIdx.x;
    if (tid < NEXP) hist[tid] = 0;
    __syncthreads();
    int n = blockIdx.x * 256 + tid;
    if (n < nrows) {
        atomicAdd(&hist[top_idx[n*2+0]], 1);
        atomicAdd(&hist[top_idx[n*2+1]], 1);
    }
    __syncthreads();
    if (tid < NEXP && hist[tid] > 0) atomicAdd(&counts[tid], hist[tid]);
}

__global__ void scan_kernel(const int* __restrict__ counts, int* __restrict__ offsets,
                            int* __restrict__ cursor)
{
    int s = 0;
    for (int e = 0; e < NEXP; ++e) { offsets[e] = s; cursor[e] = s; s += counts[e]; }
}

// ---------------- block-aggregated scatter (+ inverse map tok_pair) ----------------
__global__ __launch_bounds__(256) void scatter_kernel(
    const int* __restrict__ top_idx,
    int* __restrict__ cursor, int* __restrict__ pair_tok, int* __restrict__ tok_pair, int nrows)
{
    __shared__ int lcnt[NEXP];
    __shared__ int lbase[NEXP];
    int tid = threadIdx.x;
    if (tid < NEXP) lcnt[tid] = 0;
    __syncthreads();
    int n = blockIdx.x * 256 + tid;
    int e0 = 0, e1 = 0, p0 = 0, p1 = 0;
    bool act = n < nrows;
    if (act) {
        e0 = top_idx[n*2+0]; e1 = top_idx[n*2+1];
        p0 = atomicAdd(&lcnt[e0], 1);
        p1 = atomicAdd(&lcnt[e1], 1);
    }
    __syncthreads();
    if (tid < NEXP) lbase[tid] = (lcnt[tid] > 0) ? atomicAdd(&cursor[tid], lcnt[tid]) : 0;
    __syncthreads();
    if (act) {
        int q0 = lbase[e0] + p0, q1 = lbase[e1] + p1;
        pair_tok[q0] = n; pair_tok[q1] = n;
        tok_pair[n*2+0] = q0; tok_pair[n*2+1] = q1;
    }
}

// ---------------- small MoE GEMMs (64-tile, proven) for block-1 sized problems ----------
__global__ __launch_bounds__(256) void moe_gemm1(
    const float* __restrict__ X, const float* __restrict__ W1base,
    const float* __restrict__ b1base, const int* __restrict__ pair_tok,
    const int* __restrict__ offsets, const int* __restrict__ counts,
    float* __restrict__ hbuf)
{
    int e = blockIdx.z;
    int cnt = counts[e];
    int r0 = blockIdx.x * 64;
    if (r0 >= cnt) return;
    int off = offsets[e];
    int c0 = blockIdx.y * 64;
    const float* W = W1base + (size_t)e * H * H;
    const float* bias = b1base + (size_t)e * H;
    __shared__ float As[16][68];
    __shared__ float Bs[16][68];
    int tid = threadIdx.x, tx = tid & 15, ty = tid >> 4;
    int lrow = tid >> 2, lkg = (tid & 3) << 2;
    float acc[4][4] = {};
    for (int kk = 0; kk < H; kk += 16) {
        float4 av = make_float4(0.f,0.f,0.f,0.f);
        int pr = r0 + lrow;
        if (pr < cnt) {
            int tok = pair_tok[off + pr];
            av = *(const float4*)(X + (size_t)tok*H + kk + lkg);
        }
        As[lkg+0][lrow]=av.x; As[lkg+1][lrow]=av.y; As[lkg+2][lrow]=av.z; As[lkg+3][lrow]=av.w;
        float4 wv = *(const float4*)(W + (size_t)(kk+ty)*H + c0 + (tx<<2));
        *(float4*)&Bs[ty][tx<<2] = wv;
        __syncthreads();
        #pragma unroll
        for (int k = 0; k < 16; ++k) {
            float4 a = *(const float4*)&As[k][ty<<2];
            float4 bv = *(const float4*)&Bs[k][tx<<2];
            float aa[4] = {a.x,a.y,a.z,a.w};
            float bb[4] = {bv.x,bv.y,bv.z,bv.w};
            #pragma unroll
            for (int ii = 0; ii < 4; ++ii)
                #pragma unroll
                for (int jj = 0; jj < 4; ++jj)
                    acc[ii][jj] += aa[ii] * bb[jj];
        }
        __syncthreads();
    }
    #pragma unroll
    for (int ii = 0; ii < 4; ++ii) {
        int pr = r0 + (ty<<2) + ii;
        if (pr < cnt) {
            #pragma unroll
            for (int jj = 0; jj < 4; ++jj) {
                int gc = c0 + (tx<<2) + jj;
                hbuf[(size_t)(off+pr)*H + gc] = fmaxf(acc[ii][jj] + bias[gc], 0.f);
            }
        }
    }
}

__global__ __launch_bounds__(256) void moe_gemm2(
    const float* __restrict__ Hbuf, const float* __restrict__ W2base,
    const float* __restrict__ b2base, const int* __restrict__ offsets,
    const int* __restrict__ counts, float* __restrict__ ybuf)
{
    int e = blockIdx.z;
    int cnt = counts[e];
    int r0 = blockIdx.x * 64;
    if (r0 >= cnt) return;
    int off = offsets[e];
    int c0 = blockIdx.y * 64;
    const float* W = W2base + (size_t)e * H * H;
    const float* bias = b2base + (size_t)e * H;
    __shared__ float As[16][68];
    __shared__ float Bs[16][68];
    int tid = threadIdx.x, tx = tid & 15, ty = tid >> 4;
    int lrow = tid >> 2, lkg = (tid & 3) << 2;
    float acc[4][4] = {};
    for (int kk = 0; kk < H; kk += 16) {
        float4 av = make_float4(0.f,0.f,0.f,0.f);
        int pr = r0 + lrow;
        if (pr < cnt) av = *(const float4*)(Hbuf + (size_t)(off+pr)*H + kk + lkg);
        As[lkg+0][lrow]=av.x; As[lkg+1][lrow]=av.y; As[lkg+2][lrow]=av.z; As[lkg+3][lrow]=av.w;
        float4 wv = *(const float4*)(W + (size_t)(kk+ty)*H + c0 + (tx<<2));
        *(float4*)&Bs[ty][tx<<2] = wv;
        __syncthreads();
        #pragma unroll
        for (int k = 0; k < 16; ++k) {
            float4 a = *(const float4*)&As[k][ty<<2];
            float4 bv = *(const float4*)&Bs[k][tx<<2];
            float aa[4] = {a.x,a.y,a.z,a.w};
            float bb[4] = {bv.x,bv.y,bv.z,bv.w};
            #pragma unroll
            for (int ii = 0; ii < 4; ++ii)
                #pragma unroll
                for (int jj = 0; jj < 4; ++jj)
                    acc[ii][jj] += aa[ii] * bb[jj];
        }
        __syncthreads();
    }
    #pragma unroll
    for (int ii = 0; ii < 4; ++ii) {
        int pr = r0 + (ty<<2) + ii;
        if (pr < cnt) {
            #pragma unroll
            for (int jj = 0; jj < 4; ++jj) {
                int gc = c0 + (tx<<2) + jj;
                ybuf[(size_t)(off+pr)*H + gc] = acc[ii][jj] + bias[gc];
            }
        }
    }
}

__global__ void zero_kernel(float* __restrict__ p, int n) {
    int i = blockIdx.x * 256 + threadIdx.x;
    if (i < n) p[i] = 0.f;
}

// ---------------- final: LN + user emb + dot(item emb) ----------------
__global__ __launch_bounds__(256) void final_kernel(
    const float* __restrict__ xf, const float* __restrict__ lnw, const float* __restrict__ lnb,
    const float* __restrict__ user_emb, const float* __restrict__ item_emb,
    const int* __restrict__ user_ids, const int* __restrict__ item_ids, float* __restrict__ out)
{
    __shared__ float s4[4];
    int bb = blockIdx.x, t = threadIdx.x;
    float v = xf[(size_t)bb*H + t];
    float mean = blk_sum256(v, s4) * (1.f/H);
    float d = v - mean;
    float var = blk_sum256(d*d, s4) * (1.f/H);
    float lnv = d * rsqrtf(var + 1e-8f) * lnw[t] + lnb[t];
    float fin = lnv + user_emb[(size_t)user_ids[bb]*H + t];
    float prod = fin * item_emb[(size_t)item_ids[bb]*H + t];
    float tot = blk_sum256(prod, s4);
    if (t == 0) out[bb] = tot;
}

// ---------------- launch ----------------
extern "C" void kernel_launch(void* const* d_in, const int* in_sizes, int n_in,
                              void* d_out, int out_size, void* d_ws, size_t ws_size,
                              hipStream_t stream)
{
    (void)in_sizes; (void)n_in; (void)out_size; (void)ws_size;
    const int*   user_ids  = (const int*)d_in[0];
    const int*   log_seqs  = (const int*)d_in[1];
    const int*   item_ids  = (const int*)d_in[2];
    const float* item_emb  = (const float*)d_in[3];
    const float* pos_emb   = (const float*)d_in[4];
    const float* user_emb  = (const float*)d_in[5];
    const float* ln1_w     = (const float*)d_in[6];
    const float* ln1_b     = (const float*)d_in[7];
    const float* inproj_w  = (const float*)d_in[8];
    const float* inproj_b  = (const float*)d_in[9];
    const float* outproj_w = (const float*)d_in[10];
    const float* outproj_b = (const float*)d_in[11];
    const float* ln2_w     = (const float*)d_in[12];
    const float* ln2_b     = (const float*)d_in[13];
    const float* gate_w    = (const float*)d_in[14];
    const float* gate_b    = (const float*)d_in[15];
    const float* e_w1      = (const float*)d_in[16];
    const float* e_b1      = (const float*)d_in[17];
    const float* e_w2      = (const float*)d_in[18];
    const float* e_b2      = (const float*)d_in[19];
    const float* moeln_w   = (const float*)d_in[20];
    const float* moeln_b   = (const float*)d_in[21];
    const float* lastln_w  = (const float*)d_in[22];
    const float* lastln_b  = (const float*)d_in[23];

    float* ws = (float*)d_ws;
    const size_t NFH = (size_t)NF * H;
    float* buf0 = ws;
    float* buf1 = buf0 + NFH;   // buf1+buf2 contiguous -> ybuf region (2*NF rows)
    float* buf2 = buf1 + NFH;
    float* buf3 = buf2 + NFH;   // buf3+buf4 contiguous -> MoE h region (2*NF rows)
    float* buf4 = buf3 + NFH;
    float* s0   = buf4 + NFH;
    float* s1   = s0 + (size_t)BATCH*H;
    float* s2   = s1 + (size_t)BATCH*H;
    float* s3   = s2 + (size_t)BATCH*H;
    float* s6   = s3 + (size_t)BATCH*H;
    float* s4   = s6 + (size_t)BATCH*H;            // 2*BATCH rows (h)
    float* s5   = s4 + (size_t)2*BATCH*H;          // 2*BATCH rows (y)
    float* top_w   = s5 + (size_t)2*BATCH*H;
    int*   top_idx = (int*)(top_w + (size_t)NF*2);
    int*   pair_tok= top_idx + (size_t)NF*2;
    int*   tok_pair= pair_tok + (size_t)NF*2;
    int*   counts  = tok_pair + (size_t)NF*2;
    int*   offsets = counts + NEXP;
    int*   cursor  = offsets + NEXP;

    dim3 blk(256);
    dim3 ablk(512);
    dim3 g128((NF+127)/128, H/128);
    dim3 gsmall((BATCH+63)/64, H/64);
    dim3 m128((NF+127)/128, H/128, NEXP);
    dim3 msmall((BATCH+63)/64, H/64, NEXP);

    embed_kernel<<<NF, blk, 0, stream>>>(log_seqs, item_emb, pos_emb, buf0);

    // ================= block 0 : full sequence =================
    {
        const int i = 0;
        const float* Wq = inproj_w + (size_t)i*3*H*H;
        const float* Wk = Wq + (size_t)H*H;
        const float* Wv = Wk + (size_t)H*H;
        const float* bq = inproj_b + (size_t)i*3*H;
        ln_kernel<<<NF, blk, 0, stream>>>(buf0, nullptr, buf1, ln1_w + i*H, ln1_b + i*H, 1e-8f, 0, 1);
        gemm_nt128<<<g128, blk, 0, stream>>>(buf1, Wq, bq,       buf2, NF);   // q
        gemm_nt128<<<g128, blk, 0, stream>>>(buf0, Wk, bq + H,   buf3, NF);   // k
        gemm_nt128<<<g128, blk, 0, stream>>>(buf0, Wv, bq + 2*H, buf4, NF);   // v
        attn_kernel<<<dim3(BATCH, NHEAD, (SEQL+QT-1)/QT), ablk, 0, stream>>>(buf2, buf3, buf4, buf2, SEQL);
        gemm_nt128<<<g128, blk, 0, stream>>>(buf2, outproj_w + (size_t)i*H*H, outproj_b + i*H, buf3, NF);
        ln_kernel<<<NF, blk, 0, stream>>>(buf1, buf3, buf0, ln2_w + i*H, ln2_b + i*H, 1e-8f, 0, 1);
        zero_kernel<<<1, 32, 0, stream>>>((float*)counts, NEXP);
        gate_kernel<<<NF, blk, 0, stream>>>(buf0, gate_w + (size_t)i*NEXP*H, gate_b + i*NEXP,
                                            top_idx, top_w, NF);
        count_kernel<<<(NF+255)/256, blk, 0, stream>>>(top_idx, counts, NF);
        scan_kernel<<<1, 1, 0, stream>>>(counts, offsets, cursor);
        scatter_kernel<<<(NF+255)/256, blk, 0, stream>>>(top_idx, cursor, pair_tok, tok_pair, NF);
        moe1_128<<<m128, blk, 0, stream>>>(buf0, e_w1 + (size_t)i*NEXP*H*H, e_b1 + (size_t)i*NEXP*H,
                                           pair_tok, offsets, counts, buf3);
        moe2_128<<<m128, blk, 0, stream>>>(buf3, e_w2 + (size_t)i*NEXP*H*H, e_b2 + (size_t)i*NEXP*H,
                                           offsets, counts, buf1);
        moe_ln_kernel<<<NF, blk, 0, stream>>>(buf0, buf1, tok_pair, top_w, buf3,
                                              moeln_w + i*H, moeln_b + i*H, 1e-5f);
    }

    // ================= block 1 : only last position matters downstream =================
    {
        const int i = 1;
        const float* Wq = inproj_w + (size_t)i*3*H*H;
        const float* Wk = Wq + (size_t)H*H;
        const float* Wv = Wk + (size_t)H*H;
        const float* bq = inproj_b + (size_t)i*3*H;
        float* X = buf3;
        ln_kernel<<<BATCH, blk, 0, stream>>>(X, nullptr, s0, ln1_w + i*H, ln1_b + i*H, 1e-8f, SEQL-1, SEQL);
        gemm_nt<<<gsmall, blk, 0, stream>>>(s0, Wq, bq, s1, BATCH);            // q (last rows only)
        gemm_nt128<<<g128, blk, 0, stream>>>(X, Wk, bq + H,   buf0, NF);       // k (full)
        gemm_nt128<<<g128, blk, 0, stream>>>(X, Wv, bq + 2*H, buf1, NF);       // v (full)
        attn_kernel<<<dim3(BATCH, NHEAD, 1), ablk, 0, stream>>>(s1, buf0, buf1, s2, 1);
        gemm_nt<<<gsmall, blk, 0, stream>>>(s2, outproj_w + (size_t)i*H*H, outproj_b + i*H, s3, BATCH);
        ln_kernel<<<BATCH, blk, 0, stream>>>(s0, s3, s2, ln2_w + i*H, ln2_b + i*H, 1e-8f, 0, 1);
        zero_kernel<<<1, 32, 0, stream>>>((float*)counts, NEXP);
        gate_kernel<<<BATCH, blk, 0, stream>>>(s2, gate_w + (size_t)i*NEXP*H, gate_b + i*NEXP,
                                               top_idx, top_w, BATCH);
        count_kernel<<<1, blk, 0, stream>>>(top_idx, counts, BATCH);
        scan_kernel<<<1, 1, 0, stream>>>(counts, offsets, cursor);
        scatter_kernel<<<1, blk, 0, stream>>>(top_idx, cursor, pair_tok, tok_pair, BATCH);
        moe_gemm1<<<msmall, blk, 0, stream>>>(s2, e_w1 + (size_t)i*NEXP*H*H, e_b1 + (size_t)i*NEXP*H,
                                              pair_tok, offsets, counts, s4);
        moe_gemm2<<<msmall, blk, 0, stream>>>(s4, e_w2 + (size_t)i*NEXP*H*H, e_b2 + (size_t)i*NEXP*H,
                                              offsets, counts, s5);
        moe_ln_kernel<<<BATCH, blk, 0, stream>>>(s2, s5, tok_pair, top_w, s6,
                                                 moeln_w + i*H, moeln_b + i*H, 1e-5f);
    }

    final_kernel<<<BATCH, blk, 0, stream>>>(s6, lastln_w, lastln_b, user_emb, item_emb,
                                            user_ids, item_ids, (float*)d_out);
}